// Round 3
// baseline (3043.625 us; speedup 1.0000x reference)
//
#include <hip/hip_runtime.h>
#include <math.h>

// Sinkhorn-divergence triplet loss (geomloss-style), MI355X.
// R2: register-tiled 8x8-microtile fp32 cost GEMM (64-thread blocks, XOR-swizzled
// LDS, b128 reads/writes). Sinkhorn kernels unchanged from R1 (reg-resident C,
// defer-max single-pass LSE).

namespace {
constexpr int NB = 128, NL = 128, ND = 300, NK = 10, NR = 50, NITER = 20;
constexpr float LOG2E   = 1.4426950408889634f;
constexpr float EPS     = 0.0025f;                  // blur^p = 0.05^2
constexpr float CSCALE  = 0.5f * LOG2E / EPS;       // squared-dist -> log2-domain cost
constexpr float VSCALE  = EPS * 0.6931471805599453f; // log2-potential -> nat (eps*ln2)
constexpr float LOG2_50 = 5.6438561897747395f;      // log2(50)
constexpr float NEGL2   = -1.442695e9f;             // -1e9 * log2e
constexpr float D_HI    = 30.f, D_LO = -80.f;       // defer-max redo window
}

// ---------------------------------------------------------------- prep
__global__ void prep_kernel(const float* __restrict__ anchor,
                            const float* __restrict__ weight,
                            const float* __restrict__ t0,
                            const int* __restrict__ len,
                            float* __restrict__ na, float* __restrict__ nt,
                            float* __restrict__ lw2) {
  int wid  = (blockIdx.x * blockDim.x + threadIdx.x) >> 6;
  int lane = threadIdx.x & 63;
  const int nA = NB * NL;
  const int total = nA + NK * NR;
  if (wid >= total) return;
  const float* src = (wid < nA) ? (anchor + (size_t)wid * ND)
                                : (t0 + (size_t)(wid - nA) * ND);
  float s = 0.f;
  for (int d = lane; d < ND; d += 64) { float v = src[d]; s += v * v; }
  #pragma unroll
  for (int off = 32; off; off >>= 1) s += __shfl_xor(s, off);
  if (lane == 0) { if (wid < nA) na[wid] = s; else nt[wid - nA] = s; }
  if (wid < nA && lane == 1) {
    int b = wid >> 7, l = wid & 127;
    float w = weight[wid];
    lw2[wid] = (l < len[b]) ? log2f(fmaxf(w, 1e-12f)) : NEGL2;
  }
}

// ---------------------------------------------------------------- cost GEMM
// 64 threads (1 wave), 64x64 tile, 8x8 microtile, KC=16 staged in LDS.
// LDS layout: [row][16 k] pitch 16 floats, quad-swizzled: quad' = quad ^ ((row>>3)&3).
// mode 0: ab (p = b*NK+k), n=NL m=NR; mode 1: aa (p=b), n=m=NL; mode 2: tt, n=m=NR.
__global__ __launch_bounds__(64, 4)
void cost_gemm(const float* __restrict__ X, const float* __restrict__ Y,
               const float* __restrict__ NX, const float* __restrict__ NY,
               float* __restrict__ C, int n, int m, int mode) {
  constexpr int KC = 16;
  __shared__ float As[64 * KC];
  __shared__ float Bs[64 * KC];

  int p = blockIdx.x;
  int i0 = blockIdx.y * 64, j0 = blockIdx.z * 64;
  int xr0, yr0;
  if (mode == 0)      { xr0 = (p / NK) * NL; yr0 = (p % NK) * NR; }
  else if (mode == 1) { xr0 = p * NL;        yr0 = xr0;           }
  else                { xr0 = (p / NK) * NR; yr0 = (p % NK) * NR; }
  size_t cbase = (size_t)p * n * m;

  const int t  = threadIdx.x;
  const int tx = t & 7, ty = t >> 3;          // 8x8 thread layout
  const int tysw = ty & 3, txsw = tx & 3;     // per-thread read swizzle keys

  float acc[8][8];
  #pragma unroll
  for (int i = 0; i < 8; ++i)
    #pragma unroll
    for (int j = 0; j < 8; ++j) acc[i][j] = 0.f;

  for (int d0 = 0; d0 < ND; d0 += KC) {
    // ---- stage A and B tiles: 64 rows x 16 k each; 4 float4 per thread per tile
    #pragma unroll
    for (int q = 0; q < 4; ++q) {
      int f4id = q * 64 + t;
      int row = f4id >> 2, kq = f4id & 3;
      int d = d0 + kq * 4;
      int sw = kq ^ ((row >> 3) & 3);
      float4 va = make_float4(0.f, 0.f, 0.f, 0.f);
      float4 vb = make_float4(0.f, 0.f, 0.f, 0.f);
      if (d < ND) {
        if (i0 + row < n) va = *(const float4*)(X + (size_t)(xr0 + i0 + row) * ND + d);
        if (j0 + row < m) vb = *(const float4*)(Y + (size_t)(yr0 + j0 + row) * ND + d);
      }
      *(float4*)(As + row * KC + sw * 4) = va;
      *(float4*)(Bs + row * KC + sw * 4) = vb;
    }
    __syncthreads();

    // ---- 8x8 outer product over 16 k (4-k steps, b128 fragment reads)
    const float* ap = As + (ty * 8) * KC;
    const float* bp = Bs + (tx * 8) * KC;
    #pragma unroll
    for (int kk = 0; kk < KC; kk += 4) {
      int qa = ((kk >> 2) ^ tysw) * 4;
      int qb = ((kk >> 2) ^ txsw) * 4;
      float4 av[8];
      #pragma unroll
      for (int i = 0; i < 8; ++i) av[i] = *(const float4*)(ap + i * KC + qa);
      #pragma unroll
      for (int j = 0; j < 8; ++j) {
        float4 b = *(const float4*)(bp + j * KC + qb);
        #pragma unroll
        for (int i = 0; i < 8; ++i) {
          acc[i][j] += av[i].x * b.x + av[i].y * b.y + av[i].z * b.z + av[i].w * b.w;
        }
      }
    }
    __syncthreads();
  }

  // ---- epilogue: C = max(|x|^2 + |y|^2 - 2 x.y, 0) * CSCALE
  #pragma unroll
  for (int i = 0; i < 8; ++i) {
    int gi = i0 + ty * 8 + i;
    if (gi >= n) continue;
    float nx = NX[xr0 + gi];
    float* crow = C + cbase + (size_t)gi * m;
    #pragma unroll
    for (int j = 0; j < 8; ++j) {
      int gj = j0 + tx * 8 + j;
      if (gj < m) {
        float sq = nx + NY[yr0 + gj] - 2.f * acc[i][j];
        crow[gj] = fmaxf(sq, 0.f) * CSCALE;
      }
    }
  }
}

// ---------------------------------------------------------------- sinkhorn ab
__global__ __launch_bounds__(256)
void sinkhorn_ab(const float* __restrict__ Cg, const float* __restrict__ lw2,
                 const float* __restrict__ weight, float* __restrict__ ot) {
  __shared__ float Cs[NL * 51];
  __shared__ float g2[NR];
  __shared__ float f2[NL];
  __shared__ float potf2[NL];
  __shared__ float la2s[NL];
  __shared__ float red[4];
  int p = blockIdx.x, b = p / NK, t = threadIdx.x;
  const float* Cp = Cg + (size_t)p * (NL * NR);
  for (int i = t; i < NL * NR; i += 256) {
    int r = i / NR, c = i - r * NR;
    Cs[r * 51 + c] = Cp[i];
  }
  if (t < NL) la2s[t] = lw2[b * NL + t];
  if (t < NR) g2[t] = 0.f;
  __syncthreads();

  const int rf = t >> 1, sf = t & 1;
  float Crow[25];
  {
    const float* rp = &Cs[rf * 51 + sf * 25];
    #pragma unroll
    for (int j = 0; j < 25; ++j) Crow[j] = rp[j];
  }
  const int cc = t >> 2, sc = t & 3;
  float Ccol[32];
  if (t < 200) {
    #pragma unroll
    for (int i = 0; i < 32; ++i) Ccol[i] = Cs[(sc * 32 + i) * 51 + cc];
  }

  float mEf = 0.f, mEg = 0.f;
  const float* gbase = g2 + sf * 25;
  const float* fbase = potf2 + sc * 32;

  for (int it = 0; it < NITER; ++it) {
    {
      float mx = -3.0e38f, s = 0.f;
      #pragma unroll
      for (int j = 0; j < 25; ++j) {
        float x = gbase[j] - Crow[j];
        mx = fmaxf(mx, x);
        s += exp2f(x - mEf);
      }
      mx = fmaxf(mx, __shfl_xor(mx, 1));
      s += __shfl_xor(s, 1);
      float mU = mEf, d = mx - mEf;
      if (d > D_HI || d < D_LO) {
        mU = mx; s = 0.f;
        #pragma unroll
        for (int j = 0; j < 25; ++j) s += exp2f(gbase[j] - Crow[j] - mx);
        s += __shfl_xor(s, 1);
      }
      mEf = mx;
      if (sf == 0) {
        float fv = LOG2_50 - (mU + log2f(s));
        f2[rf] = fv; potf2[rf] = la2s[rf] + fv;
      }
    }
    __syncthreads();
    if (t < 200) {
      float mx = -3.0e38f, s = 0.f;
      #pragma unroll
      for (int i = 0; i < 32; ++i) {
        float x = fbase[i] - Ccol[i];
        mx = fmaxf(mx, x);
        s += exp2f(x - mEg);
      }
      mx = fmaxf(mx, __shfl_xor(mx, 1));
      mx = fmaxf(mx, __shfl_xor(mx, 2));
      s += __shfl_xor(s, 1);
      s += __shfl_xor(s, 2);
      float mU = mEg, d = mx - mEg;
      if (d > D_HI || d < D_LO) {
        mU = mx; s = 0.f;
        #pragma unroll
        for (int i = 0; i < 32; ++i) s += exp2f(fbase[i] - Ccol[i] - mx);
        s += __shfl_xor(s, 1);
        s += __shfl_xor(s, 2);
      }
      mEg = mx;
      if (sc == 0) g2[cc] = -(mU + log2f(s));
    }
    __syncthreads();
  }

  float acc = 0.f;
  if (t < NL) acc = weight[b * NL + t] * f2[t];
  else if (t < NL + NR) acc = g2[t - NL] * (1.0f / NR);
  #pragma unroll
  for (int off = 32; off; off >>= 1) acc += __shfl_xor(acc, off);
  if ((t & 63) == 0) red[t >> 6] = acc;
  __syncthreads();
  if (t == 0) ot[p] = VSCALE * (red[0] + red[1] + red[2] + red[3]);
}

// ---------------------------------------------------------------- sinkhorn aa
__global__ __launch_bounds__(512)
void sinkhorn_aa(const float* __restrict__ Cg, const float* __restrict__ lw2,
                 const float* __restrict__ weight, float* __restrict__ ot) {
  __shared__ float pF[NL];
  __shared__ float pG[NL];
  __shared__ float red[8];
  int b = blockIdx.x, t = threadIdx.x;
  int r = t >> 2, sub = t & 3;
  const float* Cp = Cg + (size_t)b * (NL * NL) + (size_t)r * NL + sub * 32;
  const float* lp = lw2 + b * NL + sub * 32;
  float Cr[32];
  #pragma unroll
  for (int i = 0; i < 32; i += 4) {
    float4 cv = *(const float4*)(Cp + i);
    float4 lv = *(const float4*)(lp + i);
    Cr[i]     = lv.x - cv.x; Cr[i + 1] = lv.y - cv.y;
    Cr[i + 2] = lv.z - cv.z; Cr[i + 3] = lv.w - cv.w;
  }
  if (t < NL) pG[t] = 0.f;
  __syncthreads();

  float mE = 0.f;
  for (int app = 0; app < 2 * NITER; ++app) {
    const float* src = (app & 1) ? pF : pG;
    float* dst       = (app & 1) ? pG : pF;
    const float* sp = src + sub * 32;
    float mx = -3.0e38f, s = 0.f;
    #pragma unroll
    for (int i = 0; i < 32; ++i) {
      float x = sp[i] + Cr[i];
      mx = fmaxf(mx, x);
      s += exp2f(x - mE);
    }
    mx = fmaxf(mx, __shfl_xor(mx, 1));
    mx = fmaxf(mx, __shfl_xor(mx, 2));
    s += __shfl_xor(s, 1);
    s += __shfl_xor(s, 2);
    float mU = mE, d = mx - mE;
    if (d > D_HI || d < D_LO) {
      mU = mx; s = 0.f;
      #pragma unroll
      for (int i = 0; i < 32; ++i) s += exp2f(sp[i] + Cr[i] - mx);
      s += __shfl_xor(s, 1);
      s += __shfl_xor(s, 2);
    }
    mE = mx;
    if (sub == 0) dst[r] = -(mU + log2f(s));
    __syncthreads();
  }

  float acc = 0.f;
  if (t < NL) acc = weight[b * NL + t] * (pF[t] + pG[t]);
  #pragma unroll
  for (int off = 32; off; off >>= 1) acc += __shfl_xor(acc, off);
  if ((t & 63) == 0) red[t >> 6] = acc;
  __syncthreads();
  if (t == 0) {
    float v = 0.f;
    #pragma unroll
    for (int i = 0; i < 8; ++i) v += red[i];
    ot[b] = VSCALE * v;
  }
}

// ---------------------------------------------------------------- sinkhorn tt
__global__ __launch_bounds__(256)
void sinkhorn_tt(const float* __restrict__ Cg, float* __restrict__ ot) {
  __shared__ float Cs[NR * 51];
  __shared__ float f2[NR], g2[NR];
  __shared__ float red[4];
  int p = blockIdx.x, t = threadIdx.x;
  const float* Cp = Cg + (size_t)p * (NR * NR);
  for (int i = t; i < NR * NR; i += 256) {
    int r = i / NR, c = i - r * NR;
    Cs[r * 51 + c] = Cp[i];
  }
  if (t < NR) g2[t] = 0.f;
  __syncthreads();

  int r = t >> 2, sub = t & 3;
  for (int it = 0; it < NITER; ++it) {
    if (r < NR) {
      const float* row = &Cs[r * 51];
      float mx = -INFINITY;
      for (int mm = sub; mm < NR; mm += 4) mx = fmaxf(mx, g2[mm] - row[mm]);
      mx = fmaxf(mx, __shfl_xor(mx, 1));
      mx = fmaxf(mx, __shfl_xor(mx, 2));
      float s = 0.f;
      for (int mm = sub; mm < NR; mm += 4) s += exp2f(g2[mm] - row[mm] - mx);
      s += __shfl_xor(s, 1);
      s += __shfl_xor(s, 2);
      if (sub == 0) f2[r] = LOG2_50 - mx - log2f(s);
    }
    __syncthreads();
    if (r < NR) {
      float mx = -INFINITY;
      for (int nn = sub; nn < NR; nn += 4) mx = fmaxf(mx, f2[nn] - Cs[nn * 51 + r]);
      mx = fmaxf(mx, __shfl_xor(mx, 1));
      mx = fmaxf(mx, __shfl_xor(mx, 2));
      float s = 0.f;
      for (int nn = sub; nn < NR; nn += 4) s += exp2f(f2[nn] - Cs[nn * 51 + r] - mx);
      s += __shfl_xor(s, 1);
      s += __shfl_xor(s, 2);
      if (sub == 0) g2[r] = LOG2_50 - mx - log2f(s);
    }
    __syncthreads();
  }

  float acc = 0.f;
  if (t < NR) acc = f2[t] + g2[t];
  #pragma unroll
  for (int off = 32; off; off >>= 1) acc += __shfl_xor(acc, off);
  if ((t & 63) == 0) red[t >> 6] = acc;
  __syncthreads();
  if (t == 0) ot[p] = VSCALE * (1.0f / NR) * (red[0] + red[1] + red[2] + red[3]);
}

// ---------------------------------------------------------------- finalize
__global__ void finalize_kernel(const float* __restrict__ oab, const float* __restrict__ oaa,
                                const float* __restrict__ ott, const int* __restrict__ grade,
                                float* __restrict__ out) {
  __shared__ float selft[NK];
  __shared__ float redL[4], redD[4];
  int t = threadIdx.x;
  if (t < NK) selft[t] = ott[t * NK + t];
  __syncthreads();
  float dpart = (t < NK * NK) ? ott[t] : 0.f;
  float lpart = 0.f;
  if (t < NB) {
    int g = grade[t];
    float oa = oaa[t];
    float dpos = oab[t * NK + g] - 0.5f * (oa + selft[g]);
    float s = 0.f;
    #pragma unroll
    for (int k = 0; k < NK; ++k) {
      float dk = oab[t * NK + k] - 0.5f * (oa + selft[k]);
      s += fmaxf(dpos - dk + 10.0f, 0.0f);
    }
    lpart = s - 10.0f;
  }
  #pragma unroll
  for (int off = 32; off; off >>= 1) {
    dpart += __shfl_xor(dpart, off);
    lpart += __shfl_xor(lpart, off);
  }
  if ((t & 63) == 0) { redD[t >> 6] = dpart; redL[t >> 6] = lpart; }
  __syncthreads();
  if (t == 0) {
    float ds = 0.f, ls = 0.f;
    #pragma unroll
    for (int i = 0; i < 4; ++i) { ds += redD[i]; ls += redL[i]; }
    float ss = 0.f;
    #pragma unroll
    for (int k = 0; k < NK; ++k) ss += selft[k];
    float dis = ds - (float)NK * ss;
    out[0] = ls / (float)NB - dis * 0.01f;
  }
}

// ---------------------------------------------------------------- launch
extern "C" void kernel_launch(void* const* d_in, const int* in_sizes, int n_in,
                              void* d_out, int out_size, void* d_ws, size_t ws_size,
                              hipStream_t stream) {
  (void)in_sizes; (void)n_in; (void)out_size; (void)ws_size;
  const float* anchor = (const float*)d_in[0];
  const float* weight = (const float*)d_in[1];
  const float* t0     = (const float*)d_in[2];
  const int*   len    = (const int*)d_in[3];
  const int*   grade  = (const int*)d_in[4];
  float* out = (float*)d_out;

  float* ws  = (float*)d_ws;
  float* Cab = ws;                                    // 819200
  float* Caa = Cab + (size_t)NB * NK * NL * NR;       // 2097152
  float* Ctt = Caa + (size_t)NB * NL * NL;            // 250000
  float* na  = Ctt + (size_t)NK * NK * NR * NR;       // 16384
  float* nt  = na + NB * NL;                          // 500
  float* lw2 = nt + NK * NR;                          // 16384
  float* oab = lw2 + NB * NL;                         // 1280
  float* oaa = oab + NB * NK;                         // 128
  float* ott = oaa + NB;                              // 100

  prep_kernel<<<(NB * NL + NK * NR) / 4, 256, 0, stream>>>(anchor, weight, t0, len, na, nt, lw2);
  cost_gemm<<<dim3(NB * NK, 2, 1), 64, 0, stream>>>(anchor, t0, na, nt, Cab, NL, NR, 0);
  cost_gemm<<<dim3(NB, 2, 2),      64, 0, stream>>>(anchor, anchor, na, na, Caa, NL, NL, 1);
  cost_gemm<<<dim3(NK * NK, 1, 1), 64, 0, stream>>>(t0, t0, nt, nt, Ctt, NR, NR, 2);
  sinkhorn_ab<<<NB * NK, 256, 0, stream>>>(Cab, lw2, weight, oab);
  sinkhorn_aa<<<NB, 512, 0, stream>>>(Caa, lw2, weight, oaa);
  sinkhorn_tt<<<NK * NK, 256, 0, stream>>>(Ctt, ott);
  finalize_kernel<<<1, 256, 0, stream>>>(oab, oaa, ott, grade, out);
}

// Round 4
// 1137.413 us; speedup vs baseline: 2.6759x; 2.6759x over previous
//
#include <hip/hip_runtime.h>
#include <math.h>

// Sinkhorn-divergence triplet loss (geomloss-style), MI355X.
// R4: cost GEMM = 128 threads (2 waves), 128x64 tile, 8x8 microtile,
// XOR-quad-swizzled LDS (pitch 20), b128 reads, __launch_bounds__(128,2)
// so the allocator has 256 VGPRs (R3 failed by capping at 64 -> spills).
// Sinkhorn kernels unchanged from R2 (reg-resident C, defer-max LSE).

namespace {
constexpr int NB = 128, NL = 128, ND = 300, NK = 10, NR = 50, NITER = 20;
constexpr float LOG2E   = 1.4426950408889634f;
constexpr float EPS     = 0.0025f;                  // blur^p = 0.05^2
constexpr float CSCALE  = 0.5f * LOG2E / EPS;       // squared-dist -> log2-domain cost
constexpr float VSCALE  = EPS * 0.6931471805599453f; // log2-potential -> nat (eps*ln2)
constexpr float LOG2_50 = 5.6438561897747395f;      // log2(50)
constexpr float NEGL2   = -1.442695e9f;             // -1e9 * log2e
constexpr float D_HI    = 30.f, D_LO = -80.f;       // defer-max redo window
}

// ---------------------------------------------------------------- prep
__global__ void prep_kernel(const float* __restrict__ anchor,
                            const float* __restrict__ weight,
                            const float* __restrict__ t0,
                            const int* __restrict__ len,
                            float* __restrict__ na, float* __restrict__ nt,
                            float* __restrict__ lw2) {
  int wid  = (blockIdx.x * blockDim.x + threadIdx.x) >> 6;
  int lane = threadIdx.x & 63;
  const int nA = NB * NL;
  const int total = nA + NK * NR;
  if (wid >= total) return;
  const float* src = (wid < nA) ? (anchor + (size_t)wid * ND)
                                : (t0 + (size_t)(wid - nA) * ND);
  float s = 0.f;
  for (int d = lane; d < ND; d += 64) { float v = src[d]; s += v * v; }
  #pragma unroll
  for (int off = 32; off; off >>= 1) s += __shfl_xor(s, off);
  if (lane == 0) { if (wid < nA) na[wid] = s; else nt[wid - nA] = s; }
  if (wid < nA && lane == 1) {
    int b = wid >> 7, l = wid & 127;
    float w = weight[wid];
    lw2[wid] = (l < len[b]) ? log2f(fmaxf(w, 1e-12f)) : NEGL2;
  }
}

// ---------------------------------------------------------------- cost GEMM
// 128 threads, tile 128 rows x 64 cols, 8x8 microtile (ty=t>>3 in [0,16),
// tx=t&7 in [0,8)). KC=16 staged in LDS, pitch 20 floats, k-quad swizzled:
// stored quad = kq ^ ((row>>3)&3). Fragment reads are ds_read_b128 hitting
// 4 distinct bank-quads x 2-way (free).
// mode 0: ab (p=b*NK+k) n=NL m=NR; mode 1: aa (p=b) n=m=NL; mode 2: tt n=m=NR.
__global__ __launch_bounds__(128, 2)
void cost_gemm(const float* __restrict__ X, const float* __restrict__ Y,
               const float* __restrict__ NX, const float* __restrict__ NY,
               float* __restrict__ C, int n, int m, int mode) {
  constexpr int KC = 16, PITCH = 20;
  __shared__ float As[128 * PITCH];   // 10.0 KB
  __shared__ float Bs[64 * PITCH];    // 5.0 KB

  int p = blockIdx.x;
  int i0 = blockIdx.y * 128, j0 = blockIdx.z * 64;
  int xr0, yr0;
  if (mode == 0)      { xr0 = (p / NK) * NL; yr0 = (p % NK) * NR; }
  else if (mode == 1) { xr0 = p * NL;        yr0 = xr0;           }
  else                { xr0 = (p / NK) * NR; yr0 = (p % NK) * NR; }
  size_t cbase = (size_t)p * n * m;

  const int t  = threadIdx.x;
  const int ty = t >> 3, tx = t & 7;

  float acc[8][8];
  #pragma unroll
  for (int i = 0; i < 8; ++i)
    #pragma unroll
    for (int j = 0; j < 8; ++j) acc[i][j] = 0.f;

  for (int d0 = 0; d0 < ND; d0 += KC) {
    // ---- stage A: 128 rows x 16 k = 512 float4, 4 per thread
    #pragma unroll
    for (int q = 0; q < 4; ++q) {
      int f4id = q * 128 + t;
      int row = f4id >> 2, kq = f4id & 3;
      int d = d0 + kq * 4;
      int sw = kq ^ ((row >> 3) & 3);
      float4 v = make_float4(0.f, 0.f, 0.f, 0.f);
      if (d < ND - 3 && i0 + row < n)
        v = *(const float4*)(X + (size_t)(xr0 + i0 + row) * ND + d);
      *(float4*)(As + row * PITCH + sw * 4) = v;
    }
    // ---- stage B: 64 rows x 16 k = 256 float4, 2 per thread
    #pragma unroll
    for (int q = 0; q < 2; ++q) {
      int f4id = q * 128 + t;
      int row = f4id >> 2, kq = f4id & 3;
      int d = d0 + kq * 4;
      int sw = kq ^ ((row >> 3) & 3);
      float4 v = make_float4(0.f, 0.f, 0.f, 0.f);
      if (d < ND - 3 && j0 + row < m)
        v = *(const float4*)(Y + (size_t)(yr0 + j0 + row) * ND + d);
      *(float4*)(Bs + row * PITCH + sw * 4) = v;
    }
    __syncthreads();

    // ---- 8x8 outer product, 4-k steps
    #pragma unroll
    for (int kk = 0; kk < KC; kk += 4) {
      int qa = ((kk >> 2) ^ (ty & 3)) * 4;
      int qb = ((kk >> 2) ^ (tx & 3)) * 4;
      float4 av[8];
      #pragma unroll
      for (int i = 0; i < 8; ++i)
        av[i] = *(const float4*)(As + (ty * 8 + i) * PITCH + qa);
      #pragma unroll
      for (int j = 0; j < 8; ++j) {
        float4 bv = *(const float4*)(Bs + (tx * 8 + j) * PITCH + qb);
        #pragma unroll
        for (int i = 0; i < 8; ++i) {
          acc[i][j] += av[i].x * bv.x + av[i].y * bv.y
                     + av[i].z * bv.z + av[i].w * bv.w;
        }
      }
    }
    __syncthreads();
  }

  // ---- epilogue: C = max(|x|^2 + |y|^2 - 2 x.y, 0) * CSCALE
  #pragma unroll
  for (int i = 0; i < 8; ++i) {
    int gi = i0 + ty * 8 + i;
    if (gi >= n) continue;
    float nx = NX[xr0 + gi];
    float* crow = C + cbase + (size_t)gi * m;
    #pragma unroll
    for (int j = 0; j < 8; ++j) {
      int gj = j0 + tx * 8 + j;
      if (gj < m) {
        float sq = nx + NY[yr0 + gj] - 2.f * acc[i][j];
        crow[gj] = fmaxf(sq, 0.f) * CSCALE;
      }
    }
  }
}

// ---------------------------------------------------------------- sinkhorn ab
__global__ __launch_bounds__(256)
void sinkhorn_ab(const float* __restrict__ Cg, const float* __restrict__ lw2,
                 const float* __restrict__ weight, float* __restrict__ ot) {
  __shared__ float Cs[NL * 51];
  __shared__ float g2[NR];
  __shared__ float f2[NL];
  __shared__ float potf2[NL];
  __shared__ float la2s[NL];
  __shared__ float red[4];
  int p = blockIdx.x, b = p / NK, t = threadIdx.x;
  const float* Cp = Cg + (size_t)p * (NL * NR);
  for (int i = t; i < NL * NR; i += 256) {
    int r = i / NR, c = i - r * NR;
    Cs[r * 51 + c] = Cp[i];
  }
  if (t < NL) la2s[t] = lw2[b * NL + t];
  if (t < NR) g2[t] = 0.f;
  __syncthreads();

  const int rf = t >> 1, sf = t & 1;
  float Crow[25];
  {
    const float* rp = &Cs[rf * 51 + sf * 25];
    #pragma unroll
    for (int j = 0; j < 25; ++j) Crow[j] = rp[j];
  }
  const int cc = t >> 2, sc = t & 3;
  float Ccol[32];
  if (t < 200) {
    #pragma unroll
    for (int i = 0; i < 32; ++i) Ccol[i] = Cs[(sc * 32 + i) * 51 + cc];
  }

  float mEf = 0.f, mEg = 0.f;
  const float* gbase = g2 + sf * 25;
  const float* fbase = potf2 + sc * 32;

  for (int it = 0; it < NITER; ++it) {
    {
      float mx = -3.0e38f, s = 0.f;
      #pragma unroll
      for (int j = 0; j < 25; ++j) {
        float x = gbase[j] - Crow[j];
        mx = fmaxf(mx, x);
        s += exp2f(x - mEf);
      }
      mx = fmaxf(mx, __shfl_xor(mx, 1));
      s += __shfl_xor(s, 1);
      float mU = mEf, d = mx - mEf;
      if (d > D_HI || d < D_LO) {
        mU = mx; s = 0.f;
        #pragma unroll
        for (int j = 0; j < 25; ++j) s += exp2f(gbase[j] - Crow[j] - mx);
        s += __shfl_xor(s, 1);
      }
      mEf = mx;
      if (sf == 0) {
        float fv = LOG2_50 - (mU + log2f(s));
        f2[rf] = fv; potf2[rf] = la2s[rf] + fv;
      }
    }
    __syncthreads();
    if (t < 200) {
      float mx = -3.0e38f, s = 0.f;
      #pragma unroll
      for (int i = 0; i < 32; ++i) {
        float x = fbase[i] - Ccol[i];
        mx = fmaxf(mx, x);
        s += exp2f(x - mEg);
      }
      mx = fmaxf(mx, __shfl_xor(mx, 1));
      mx = fmaxf(mx, __shfl_xor(mx, 2));
      s += __shfl_xor(s, 1);
      s += __shfl_xor(s, 2);
      float mU = mEg, d = mx - mEg;
      if (d > D_HI || d < D_LO) {
        mU = mx; s = 0.f;
        #pragma unroll
        for (int i = 0; i < 32; ++i) s += exp2f(fbase[i] - Ccol[i] - mx);
        s += __shfl_xor(s, 1);
        s += __shfl_xor(s, 2);
      }
      mEg = mx;
      if (sc == 0) g2[cc] = -(mU + log2f(s));
    }
    __syncthreads();
  }

  float acc = 0.f;
  if (t < NL) acc = weight[b * NL + t] * f2[t];
  else if (t < NL + NR) acc = g2[t - NL] * (1.0f / NR);
  #pragma unroll
  for (int off = 32; off; off >>= 1) acc += __shfl_xor(acc, off);
  if ((t & 63) == 0) red[t >> 6] = acc;
  __syncthreads();
  if (t == 0) ot[p] = VSCALE * (red[0] + red[1] + red[2] + red[3]);
}

// ---------------------------------------------------------------- sinkhorn aa
__global__ __launch_bounds__(512)
void sinkhorn_aa(const float* __restrict__ Cg, const float* __restrict__ lw2,
                 const float* __restrict__ weight, float* __restrict__ ot) {
  __shared__ float pF[NL];
  __shared__ float pG[NL];
  __shared__ float red[8];
  int b = blockIdx.x, t = threadIdx.x;
  int r = t >> 2, sub = t & 3;
  const float* Cp = Cg + (size_t)b * (NL * NL) + (size_t)r * NL + sub * 32;
  const float* lp = lw2 + b * NL + sub * 32;
  float Cr[32];
  #pragma unroll
  for (int i = 0; i < 32; i += 4) {
    float4 cv = *(const float4*)(Cp + i);
    float4 lv = *(const float4*)(lp + i);
    Cr[i]     = lv.x - cv.x; Cr[i + 1] = lv.y - cv.y;
    Cr[i + 2] = lv.z - cv.z; Cr[i + 3] = lv.w - cv.w;
  }
  if (t < NL) pG[t] = 0.f;
  __syncthreads();

  float mE = 0.f;
  for (int app = 0; app < 2 * NITER; ++app) {
    const float* src = (app & 1) ? pF : pG;
    float* dst       = (app & 1) ? pG : pF;
    const float* sp = src + sub * 32;
    float mx = -3.0e38f, s = 0.f;
    #pragma unroll
    for (int i = 0; i < 32; ++i) {
      float x = sp[i] + Cr[i];
      mx = fmaxf(mx, x);
      s += exp2f(x - mE);
    }
    mx = fmaxf(mx, __shfl_xor(mx, 1));
    mx = fmaxf(mx, __shfl_xor(mx, 2));
    s += __shfl_xor(s, 1);
    s += __shfl_xor(s, 2);
    float mU = mE, d = mx - mE;
    if (d > D_HI || d < D_LO) {
      mU = mx; s = 0.f;
      #pragma unroll
      for (int i = 0; i < 32; ++i) s += exp2f(sp[i] + Cr[i] - mx);
      s += __shfl_xor(s, 1);
      s += __shfl_xor(s, 2);
    }
    mE = mx;
    if (sub == 0) dst[r] = -(mU + log2f(s));
    __syncthreads();
  }

  float acc = 0.f;
  if (t < NL) acc = weight[b * NL + t] * (pF[t] + pG[t]);
  #pragma unroll
  for (int off = 32; off; off >>= 1) acc += __shfl_xor(acc, off);
  if ((t & 63) == 0) red[t >> 6] = acc;
  __syncthreads();
  if (t == 0) {
    float v = 0.f;
    #pragma unroll
    for (int i = 0; i < 8; ++i) v += red[i];
    ot[b] = VSCALE * v;
  }
}

// ---------------------------------------------------------------- sinkhorn tt
__global__ __launch_bounds__(256)
void sinkhorn_tt(const float* __restrict__ Cg, float* __restrict__ ot) {
  __shared__ float Cs[NR * 51];
  __shared__ float f2[NR], g2[NR];
  __shared__ float red[4];
  int p = blockIdx.x, t = threadIdx.x;
  const float* Cp = Cg + (size_t)p * (NR * NR);
  for (int i = t; i < NR * NR; i += 256) {
    int r = i / NR, c = i - r * NR;
    Cs[r * 51 + c] = Cp[i];
  }
  if (t < NR) g2[t] = 0.f;
  __syncthreads();

  int r = t >> 2, sub = t & 3;
  for (int it = 0; it < NITER; ++it) {
    if (r < NR) {
      const float* row = &Cs[r * 51];
      float mx = -INFINITY;
      for (int mm = sub; mm < NR; mm += 4) mx = fmaxf(mx, g2[mm] - row[mm]);
      mx = fmaxf(mx, __shfl_xor(mx, 1));
      mx = fmaxf(mx, __shfl_xor(mx, 2));
      float s = 0.f;
      for (int mm = sub; mm < NR; mm += 4) s += exp2f(g2[mm] - row[mm] - mx);
      s += __shfl_xor(s, 1);
      s += __shfl_xor(s, 2);
      if (sub == 0) f2[r] = LOG2_50 - mx - log2f(s);
    }
    __syncthreads();
    if (r < NR) {
      float mx = -INFINITY;
      for (int nn = sub; nn < NR; nn += 4) mx = fmaxf(mx, f2[nn] - Cs[nn * 51 + r]);
      mx = fmaxf(mx, __shfl_xor(mx, 1));
      mx = fmaxf(mx, __shfl_xor(mx, 2));
      float s = 0.f;
      for (int nn = sub; nn < NR; nn += 4) s += exp2f(f2[nn] - Cs[nn * 51 + r] - mx);
      s += __shfl_xor(s, 1);
      s += __shfl_xor(s, 2);
      if (sub == 0) g2[r] = LOG2_50 - mx - log2f(s);
    }
    __syncthreads();
  }

  float acc = 0.f;
  if (t < NR) acc = f2[t] + g2[t];
  #pragma unroll
  for (int off = 32; off; off >>= 1) acc += __shfl_xor(acc, off);
  if ((t & 63) == 0) red[t >> 6] = acc;
  __syncthreads();
  if (t == 0) ot[p] = VSCALE * (1.0f / NR) * (red[0] + red[1] + red[2] + red[3]);
}

// ---------------------------------------------------------------- finalize
__global__ void finalize_kernel(const float* __restrict__ oab, const float* __restrict__ oaa,
                                const float* __restrict__ ott, const int* __restrict__ grade,
                                float* __restrict__ out) {
  __shared__ float selft[NK];
  __shared__ float redL[4], redD[4];
  int t = threadIdx.x;
  if (t < NK) selft[t] = ott[t * NK + t];
  __syncthreads();
  float dpart = (t < NK * NK) ? ott[t] : 0.f;
  float lpart = 0.f;
  if (t < NB) {
    int g = grade[t];
    float oa = oaa[t];
    float dpos = oab[t * NK + g] - 0.5f * (oa + selft[g]);
    float s = 0.f;
    #pragma unroll
    for (int k = 0; k < NK; ++k) {
      float dk = oab[t * NK + k] - 0.5f * (oa + selft[k]);
      s += fmaxf(dpos - dk + 10.0f, 0.0f);
    }
    lpart = s - 10.0f;
  }
  #pragma unroll
  for (int off = 32; off; off >>= 1) {
    dpart += __shfl_xor(dpart, off);
    lpart += __shfl_xor(lpart, off);
  }
  if ((t & 63) == 0) { redD[t >> 6] = dpart; redL[t >> 6] = lpart; }
  __syncthreads();
  if (t == 0) {
    float ds = 0.f, ls = 0.f;
    #pragma unroll
    for (int i = 0; i < 4; ++i) { ds += redD[i]; ls += redL[i]; }
    float ss = 0.f;
    #pragma unroll
    for (int k = 0; k < NK; ++k) ss += selft[k];
    float dis = ds - (float)NK * ss;
    out[0] = ls / (float)NB - dis * 0.01f;
  }
}

// ---------------------------------------------------------------- launch
extern "C" void kernel_launch(void* const* d_in, const int* in_sizes, int n_in,
                              void* d_out, int out_size, void* d_ws, size_t ws_size,
                              hipStream_t stream) {
  (void)in_sizes; (void)n_in; (void)out_size; (void)ws_size;
  const float* anchor = (const float*)d_in[0];
  const float* weight = (const float*)d_in[1];
  const float* t0     = (const float*)d_in[2];
  const int*   len    = (const int*)d_in[3];
  const int*   grade  = (const int*)d_in[4];
  float* out = (float*)d_out;

  float* ws  = (float*)d_ws;
  float* Cab = ws;                                    // 819200
  float* Caa = Cab + (size_t)NB * NK * NL * NR;       // 2097152
  float* Ctt = Caa + (size_t)NB * NL * NL;            // 250000
  float* na  = Ctt + (size_t)NK * NK * NR * NR;       // 16384
  float* nt  = na + NB * NL;                          // 500
  float* lw2 = nt + NK * NR;                          // 16384
  float* oab = lw2 + NB * NL;                         // 1280
  float* oaa = oab + NB * NK;                         // 128
  float* ott = oaa + NB;                              // 100

  prep_kernel<<<(NB * NL + NK * NR) / 4, 256, 0, stream>>>(anchor, weight, t0, len, na, nt, lw2);
  cost_gemm<<<dim3(NB * NK, 1, 1), 128, 0, stream>>>(anchor, t0, na, nt, Cab, NL, NR, 0);
  cost_gemm<<<dim3(NB, 1, 2),      128, 0, stream>>>(anchor, anchor, na, na, Caa, NL, NL, 1);
  cost_gemm<<<dim3(NK * NK, 1, 1), 128, 0, stream>>>(t0, t0, nt, nt, Ctt, NR, NR, 2);
  sinkhorn_ab<<<NB * NK, 256, 0, stream>>>(Cab, lw2, weight, oab);
  sinkhorn_aa<<<NB, 512, 0, stream>>>(Caa, lw2, weight, oaa);
  sinkhorn_tt<<<NK * NK, 256, 0, stream>>>(Ctt, ott);
  finalize_kernel<<<1, 256, 0, stream>>>(oab, oaa, ott, grade, out);
}

// Round 5
// 712.492 us; speedup vs baseline: 4.2718x; 1.5964x over previous
//
#include <hip/hip_runtime.h>
#include <math.h>

// Sinkhorn-divergence triplet loss (geomloss-style), MI355X.
// R5: cost GEMM identical to R4 EXCEPT __launch_bounds__(128) with NO
// min-waves argument. Empirical law from R3/R4: VGPR cap = 512/(2*arg2)
// (arg2=4 -> 64 regs, arg2=2 -> 128 regs) -> the 8x8 microtile (needs ~150)
// spilled ~5KB/thread to scratch. No arg -> allocator free (~256), no spill.
// Sinkhorn kernels unchanged from R2 (reg-resident C, defer-max LSE).

namespace {
constexpr int NB = 128, NL = 128, ND = 300, NK = 10, NR = 50, NITER = 20;
constexpr float LOG2E   = 1.4426950408889634f;
constexpr float EPS     = 0.0025f;                  // blur^p = 0.05^2
constexpr float CSCALE  = 0.5f * LOG2E / EPS;       // squared-dist -> log2-domain cost
constexpr float VSCALE  = EPS * 0.6931471805599453f; // log2-potential -> nat (eps*ln2)
constexpr float LOG2_50 = 5.6438561897747395f;      // log2(50)
constexpr float NEGL2   = -1.442695e9f;             // -1e9 * log2e
constexpr float D_HI    = 30.f, D_LO = -80.f;       // defer-max redo window
}

// ---------------------------------------------------------------- prep
__global__ void prep_kernel(const float* __restrict__ anchor,
                            const float* __restrict__ weight,
                            const float* __restrict__ t0,
                            const int* __restrict__ len,
                            float* __restrict__ na, float* __restrict__ nt,
                            float* __restrict__ lw2) {
  int wid  = (blockIdx.x * blockDim.x + threadIdx.x) >> 6;
  int lane = threadIdx.x & 63;
  const int nA = NB * NL;
  const int total = nA + NK * NR;
  if (wid >= total) return;
  const float* src = (wid < nA) ? (anchor + (size_t)wid * ND)
                                : (t0 + (size_t)(wid - nA) * ND);
  float s = 0.f;
  for (int d = lane; d < ND; d += 64) { float v = src[d]; s += v * v; }
  #pragma unroll
  for (int off = 32; off; off >>= 1) s += __shfl_xor(s, off);
  if (lane == 0) { if (wid < nA) na[wid] = s; else nt[wid - nA] = s; }
  if (wid < nA && lane == 1) {
    int b = wid >> 7, l = wid & 127;
    float w = weight[wid];
    lw2[wid] = (l < len[b]) ? log2f(fmaxf(w, 1e-12f)) : NEGL2;
  }
}

// ---------------------------------------------------------------- cost GEMM
// 128 threads, tile 128 rows x 64 cols, 8x8 microtile (ty=t>>3 in [0,16),
// tx=t&7 in [0,8)). KC=16 staged in LDS, pitch 20 floats, k-quad swizzled:
// stored quad = kq ^ ((row>>3)&3). Fragment reads are ds_read_b128.
// mode 0: ab (p=b*NK+k) n=NL m=NR; mode 1: aa (p=b) n=m=NL; mode 2: tt n=m=NR.
__global__ __launch_bounds__(128)
void cost_gemm(const float* __restrict__ X, const float* __restrict__ Y,
               const float* __restrict__ NX, const float* __restrict__ NY,
               float* __restrict__ C, int n, int m, int mode) {
  constexpr int KC = 16, PITCH = 20;
  __shared__ float As[128 * PITCH];   // 10.0 KB
  __shared__ float Bs[64 * PITCH];    // 5.0 KB

  int p = blockIdx.x;
  int i0 = blockIdx.y * 128, j0 = blockIdx.z * 64;
  int xr0, yr0;
  if (mode == 0)      { xr0 = (p / NK) * NL; yr0 = (p % NK) * NR; }
  else if (mode == 1) { xr0 = p * NL;        yr0 = xr0;           }
  else                { xr0 = (p / NK) * NR; yr0 = (p % NK) * NR; }
  size_t cbase = (size_t)p * n * m;

  const int t  = threadIdx.x;
  const int ty = t >> 3, tx = t & 7;

  float acc[8][8];
  #pragma unroll
  for (int i = 0; i < 8; ++i)
    #pragma unroll
    for (int j = 0; j < 8; ++j) acc[i][j] = 0.f;

  for (int d0 = 0; d0 < ND; d0 += KC) {
    // ---- stage A: 128 rows x 16 k = 512 float4, 4 per thread
    #pragma unroll
    for (int q = 0; q < 4; ++q) {
      int f4id = q * 128 + t;
      int row = f4id >> 2, kq = f4id & 3;
      int d = d0 + kq * 4;
      int sw = kq ^ ((row >> 3) & 3);
      float4 v = make_float4(0.f, 0.f, 0.f, 0.f);
      if (d < ND - 3 && i0 + row < n)
        v = *(const float4*)(X + (size_t)(xr0 + i0 + row) * ND + d);
      *(float4*)(As + row * PITCH + sw * 4) = v;
    }
    // ---- stage B: 64 rows x 16 k = 256 float4, 2 per thread
    #pragma unroll
    for (int q = 0; q < 2; ++q) {
      int f4id = q * 128 + t;
      int row = f4id >> 2, kq = f4id & 3;
      int d = d0 + kq * 4;
      int sw = kq ^ ((row >> 3) & 3);
      float4 v = make_float4(0.f, 0.f, 0.f, 0.f);
      if (d < ND - 3 && j0 + row < m)
        v = *(const float4*)(Y + (size_t)(yr0 + j0 + row) * ND + d);
      *(float4*)(Bs + row * PITCH + sw * 4) = v;
    }
    __syncthreads();

    // ---- 8x8 outer product, 4-k steps
    #pragma unroll
    for (int kk = 0; kk < KC; kk += 4) {
      int qa = ((kk >> 2) ^ (ty & 3)) * 4;
      int qb = ((kk >> 2) ^ (tx & 3)) * 4;
      float4 av[8];
      #pragma unroll
      for (int i = 0; i < 8; ++i)
        av[i] = *(const float4*)(As + (ty * 8 + i) * PITCH + qa);
      #pragma unroll
      for (int j = 0; j < 8; ++j) {
        float4 bv = *(const float4*)(Bs + (tx * 8 + j) * PITCH + qb);
        #pragma unroll
        for (int i = 0; i < 8; ++i) {
          acc[i][j] += av[i].x * bv.x + av[i].y * bv.y
                     + av[i].z * bv.z + av[i].w * bv.w;
        }
      }
    }
    __syncthreads();
  }

  // ---- epilogue: C = max(|x|^2 + |y|^2 - 2 x.y, 0) * CSCALE
  #pragma unroll
  for (int i = 0; i < 8; ++i) {
    int gi = i0 + ty * 8 + i;
    if (gi >= n) continue;
    float nx = NX[xr0 + gi];
    float* crow = C + cbase + (size_t)gi * m;
    #pragma unroll
    for (int j = 0; j < 8; ++j) {
      int gj = j0 + tx * 8 + j;
      if (gj < m) {
        float sq = nx + NY[yr0 + gj] - 2.f * acc[i][j];
        crow[gj] = fmaxf(sq, 0.f) * CSCALE;
      }
    }
  }
}

// ---------------------------------------------------------------- sinkhorn ab
__global__ __launch_bounds__(256)
void sinkhorn_ab(const float* __restrict__ Cg, const float* __restrict__ lw2,
                 const float* __restrict__ weight, float* __restrict__ ot) {
  __shared__ float Cs[NL * 51];
  __shared__ float g2[NR];
  __shared__ float f2[NL];
  __shared__ float potf2[NL];
  __shared__ float la2s[NL];
  __shared__ float red[4];
  int p = blockIdx.x, b = p / NK, t = threadIdx.x;
  const float* Cp = Cg + (size_t)p * (NL * NR);
  for (int i = t; i < NL * NR; i += 256) {
    int r = i / NR, c = i - r * NR;
    Cs[r * 51 + c] = Cp[i];
  }
  if (t < NL) la2s[t] = lw2[b * NL + t];
  if (t < NR) g2[t] = 0.f;
  __syncthreads();

  const int rf = t >> 1, sf = t & 1;
  float Crow[25];
  {
    const float* rp = &Cs[rf * 51 + sf * 25];
    #pragma unroll
    for (int j = 0; j < 25; ++j) Crow[j] = rp[j];
  }
  const int cc = t >> 2, sc = t & 3;
  float Ccol[32];
  if (t < 200) {
    #pragma unroll
    for (int i = 0; i < 32; ++i) Ccol[i] = Cs[(sc * 32 + i) * 51 + cc];
  }

  float mEf = 0.f, mEg = 0.f;
  const float* gbase = g2 + sf * 25;
  const float* fbase = potf2 + sc * 32;

  for (int it = 0; it < NITER; ++it) {
    {
      float mx = -3.0e38f, s = 0.f;
      #pragma unroll
      for (int j = 0; j < 25; ++j) {
        float x = gbase[j] - Crow[j];
        mx = fmaxf(mx, x);
        s += exp2f(x - mEf);
      }
      mx = fmaxf(mx, __shfl_xor(mx, 1));
      s += __shfl_xor(s, 1);
      float mU = mEf, d = mx - mEf;
      if (d > D_HI || d < D_LO) {
        mU = mx; s = 0.f;
        #pragma unroll
        for (int j = 0; j < 25; ++j) s += exp2f(gbase[j] - Crow[j] - mx);
        s += __shfl_xor(s, 1);
      }
      mEf = mx;
      if (sf == 0) {
        float fv = LOG2_50 - (mU + log2f(s));
        f2[rf] = fv; potf2[rf] = la2s[rf] + fv;
      }
    }
    __syncthreads();
    if (t < 200) {
      float mx = -3.0e38f, s = 0.f;
      #pragma unroll
      for (int i = 0; i < 32; ++i) {
        float x = fbase[i] - Ccol[i];
        mx = fmaxf(mx, x);
        s += exp2f(x - mEg);
      }
      mx = fmaxf(mx, __shfl_xor(mx, 1));
      mx = fmaxf(mx, __shfl_xor(mx, 2));
      s += __shfl_xor(s, 1);
      s += __shfl_xor(s, 2);
      float mU = mEg, d = mx - mEg;
      if (d > D_HI || d < D_LO) {
        mU = mx; s = 0.f;
        #pragma unroll
        for (int i = 0; i < 32; ++i) s += exp2f(fbase[i] - Ccol[i] - mx);
        s += __shfl_xor(s, 1);
        s += __shfl_xor(s, 2);
      }
      mEg = mx;
      if (sc == 0) g2[cc] = -(mU + log2f(s));
    }
    __syncthreads();
  }

  float acc = 0.f;
  if (t < NL) acc = weight[b * NL + t] * f2[t];
  else if (t < NL + NR) acc = g2[t - NL] * (1.0f / NR);
  #pragma unroll
  for (int off = 32; off; off >>= 1) acc += __shfl_xor(acc, off);
  if ((t & 63) == 0) red[t >> 6] = acc;
  __syncthreads();
  if (t == 0) ot[p] = VSCALE * (red[0] + red[1] + red[2] + red[3]);
}

// ---------------------------------------------------------------- sinkhorn aa
__global__ __launch_bounds__(512)
void sinkhorn_aa(const float* __restrict__ Cg, const float* __restrict__ lw2,
                 const float* __restrict__ weight, float* __restrict__ ot) {
  __shared__ float pF[NL];
  __shared__ float pG[NL];
  __shared__ float red[8];
  int b = blockIdx.x, t = threadIdx.x;
  int r = t >> 2, sub = t & 3;
  const float* Cp = Cg + (size_t)b * (NL * NL) + (size_t)r * NL + sub * 32;
  const float* lp = lw2 + b * NL + sub * 32;
  float Cr[32];
  #pragma unroll
  for (int i = 0; i < 32; i += 4) {
    float4 cv = *(const float4*)(Cp + i);
    float4 lv = *(const float4*)(lp + i);
    Cr[i]     = lv.x - cv.x; Cr[i + 1] = lv.y - cv.y;
    Cr[i + 2] = lv.z - cv.z; Cr[i + 3] = lv.w - cv.w;
  }
  if (t < NL) pG[t] = 0.f;
  __syncthreads();

  float mE = 0.f;
  for (int app = 0; app < 2 * NITER; ++app) {
    const float* src = (app & 1) ? pF : pG;
    float* dst       = (app & 1) ? pG : pF;
    const float* sp = src + sub * 32;
    float mx = -3.0e38f, s = 0.f;
    #pragma unroll
    for (int i = 0; i < 32; ++i) {
      float x = sp[i] + Cr[i];
      mx = fmaxf(mx, x);
      s += exp2f(x - mE);
    }
    mx = fmaxf(mx, __shfl_xor(mx, 1));
    mx = fmaxf(mx, __shfl_xor(mx, 2));
    s += __shfl_xor(s, 1);
    s += __shfl_xor(s, 2);
    float mU = mE, d = mx - mE;
    if (d > D_HI || d < D_LO) {
      mU = mx; s = 0.f;
      #pragma unroll
      for (int i = 0; i < 32; ++i) s += exp2f(sp[i] + Cr[i] - mx);
      s += __shfl_xor(s, 1);
      s += __shfl_xor(s, 2);
    }
    mE = mx;
    if (sub == 0) dst[r] = -(mU + log2f(s));
    __syncthreads();
  }

  float acc = 0.f;
  if (t < NL) acc = weight[b * NL + t] * (pF[t] + pG[t]);
  #pragma unroll
  for (int off = 32; off; off >>= 1) acc += __shfl_xor(acc, off);
  if ((t & 63) == 0) red[t >> 6] = acc;
  __syncthreads();
  if (t == 0) {
    float v = 0.f;
    #pragma unroll
    for (int i = 0; i < 8; ++i) v += red[i];
    ot[b] = VSCALE * v;
  }
}

// ---------------------------------------------------------------- sinkhorn tt
__global__ __launch_bounds__(256)
void sinkhorn_tt(const float* __restrict__ Cg, float* __restrict__ ot) {
  __shared__ float Cs[NR * 51];
  __shared__ float f2[NR], g2[NR];
  __shared__ float red[4];
  int p = blockIdx.x, t = threadIdx.x;
  const float* Cp = Cg + (size_t)p * (NR * NR);
  for (int i = t; i < NR * NR; i += 256) {
    int r = i / NR, c = i - r * NR;
    Cs[r * 51 + c] = Cp[i];
  }
  if (t < NR) g2[t] = 0.f;
  __syncthreads();

  int r = t >> 2, sub = t & 3;
  for (int it = 0; it < NITER; ++it) {
    if (r < NR) {
      const float* row = &Cs[r * 51];
      float mx = -INFINITY;
      for (int mm = sub; mm < NR; mm += 4) mx = fmaxf(mx, g2[mm] - row[mm]);
      mx = fmaxf(mx, __shfl_xor(mx, 1));
      mx = fmaxf(mx, __shfl_xor(mx, 2));
      float s = 0.f;
      for (int mm = sub; mm < NR; mm += 4) s += exp2f(g2[mm] - row[mm] - mx);
      s += __shfl_xor(s, 1);
      s += __shfl_xor(s, 2);
      if (sub == 0) f2[r] = LOG2_50 - mx - log2f(s);
    }
    __syncthreads();
    if (r < NR) {
      float mx = -INFINITY;
      for (int nn = sub; nn < NR; nn += 4) mx = fmaxf(mx, f2[nn] - Cs[nn * 51 + r]);
      mx = fmaxf(mx, __shfl_xor(mx, 1));
      mx = fmaxf(mx, __shfl_xor(mx, 2));
      float s = 0.f;
      for (int nn = sub; nn < NR; nn += 4) s += exp2f(f2[nn] - Cs[nn * 51 + r] - mx);
      s += __shfl_xor(s, 1);
      s += __shfl_xor(s, 2);
      if (sub == 0) g2[r] = LOG2_50 - mx - log2f(s);
    }
    __syncthreads();
  }

  float acc = 0.f;
  if (t < NR) acc = f2[t] + g2[t];
  #pragma unroll
  for (int off = 32; off; off >>= 1) acc += __shfl_xor(acc, off);
  if ((t & 63) == 0) red[t >> 6] = acc;
  __syncthreads();
  if (t == 0) ot[p] = VSCALE * (1.0f / NR) * (red[0] + red[1] + red[2] + red[3]);
}

// ---------------------------------------------------------------- finalize
__global__ void finalize_kernel(const float* __restrict__ oab, const float* __restrict__ oaa,
                                const float* __restrict__ ott, const int* __restrict__ grade,
                                float* __restrict__ out) {
  __shared__ float selft[NK];
  __shared__ float redL[4], redD[4];
  int t = threadIdx.x;
  if (t < NK) selft[t] = ott[t * NK + t];
  __syncthreads();
  float dpart = (t < NK * NK) ? ott[t] : 0.f;
  float lpart = 0.f;
  if (t < NB) {
    int g = grade[t];
    float oa = oaa[t];
    float dpos = oab[t * NK + g] - 0.5f * (oa + selft[g]);
    float s = 0.f;
    #pragma unroll
    for (int k = 0; k < NK; ++k) {
      float dk = oab[t * NK + k] - 0.5f * (oa + selft[k]);
      s += fmaxf(dpos - dk + 10.0f, 0.0f);
    }
    lpart = s - 10.0f;
  }
  #pragma unroll
  for (int off = 32; off; off >>= 1) {
    dpart += __shfl_xor(dpart, off);
    lpart += __shfl_xor(lpart, off);
  }
  if ((t & 63) == 0) { redD[t >> 6] = dpart; redL[t >> 6] = lpart; }
  __syncthreads();
  if (t == 0) {
    float ds = 0.f, ls = 0.f;
    #pragma unroll
    for (int i = 0; i < 4; ++i) { ds += redD[i]; ls += redL[i]; }
    float ss = 0.f;
    #pragma unroll
    for (int k = 0; k < NK; ++k) ss += selft[k];
    float dis = ds - (float)NK * ss;
    out[0] = ls / (float)NB - dis * 0.01f;
  }
}

// ---------------------------------------------------------------- launch
extern "C" void kernel_launch(void* const* d_in, const int* in_sizes, int n_in,
                              void* d_out, int out_size, void* d_ws, size_t ws_size,
                              hipStream_t stream) {
  (void)in_sizes; (void)n_in; (void)out_size; (void)ws_size;
  const float* anchor = (const float*)d_in[0];
  const float* weight = (const float*)d_in[1];
  const float* t0     = (const float*)d_in[2];
  const int*   len    = (const int*)d_in[3];
  const int*   grade  = (const int*)d_in[4];
  float* out = (float*)d_out;

  float* ws  = (float*)d_ws;
  float* Cab = ws;                                    // 819200
  float* Caa = Cab + (size_t)NB * NK * NL * NR;       // 2097152
  float* Ctt = Caa + (size_t)NB * NL * NL;            // 250000
  float* na  = Ctt + (size_t)NK * NK * NR * NR;       // 16384
  float* nt  = na + NB * NL;                          // 500
  float* lw2 = nt + NK * NR;                          // 16384
  float* oab = lw2 + NB * NL;                         // 1280
  float* oaa = oab + NB * NK;                         // 128
  float* ott = oaa + NB;                              // 100

  prep_kernel<<<(NB * NL + NK * NR) / 4, 256, 0, stream>>>(anchor, weight, t0, len, na, nt, lw2);
  cost_gemm<<<dim3(NB * NK, 1, 1), 128, 0, stream>>>(anchor, t0, na, nt, Cab, NL, NR, 0);
  cost_gemm<<<dim3(NB, 1, 2),      128, 0, stream>>>(anchor, anchor, na, na, Caa, NL, NL, 1);
  cost_gemm<<<dim3(NK * NK, 1, 1), 128, 0, stream>>>(t0, t0, nt, nt, Ctt, NR, NR, 2);
  sinkhorn_ab<<<NB * NK, 256, 0, stream>>>(Cab, lw2, weight, oab);
  sinkhorn_aa<<<NB, 512, 0, stream>>>(Caa, lw2, weight, oaa);
  sinkhorn_tt<<<NK * NK, 256, 0, stream>>>(Ctt, ott);
  finalize_kernel<<<1, 256, 0, stream>>>(oab, oaa, ott, grade, out);
}

// Round 6
// 675.682 us; speedup vs baseline: 4.5045x; 1.0545x over previous
//
#include <hip/hip_runtime.h>
#include <math.h>

// Sinkhorn-divergence triplet loss (geomloss-style), MI355X.
// R6: cost GEMM gets double-buffered LDS + async-stage split (T14):
// issue next chunk's global loads into regs BEFORE compute, ds_write after,
// ONE barrier per chunk (write target buffer is not read this chunk).
// R5 post-mortem: 2 waves/SIMD (VGPR 176) + drain-at-barrier => 73% idle.
// Launch-bounds law (measured R3/R4): VGPR cap = 256/arg2 -> never pass arg2.
// Sinkhorn kernels unchanged from R2 (reg-resident C, defer-max LSE).

namespace {
constexpr int NB = 128, NL = 128, ND = 300, NK = 10, NR = 50, NITER = 20;
constexpr float LOG2E   = 1.4426950408889634f;
constexpr float EPS     = 0.0025f;                  // blur^p = 0.05^2
constexpr float CSCALE  = 0.5f * LOG2E / EPS;       // squared-dist -> log2-domain cost
constexpr float VSCALE  = EPS * 0.6931471805599453f; // log2-potential -> nat (eps*ln2)
constexpr float LOG2_50 = 5.6438561897747395f;      // log2(50)
constexpr float NEGL2   = -1.442695e9f;             // -1e9 * log2e
constexpr float D_HI    = 30.f, D_LO = -80.f;       // defer-max redo window
}

// ---------------------------------------------------------------- prep
__global__ void prep_kernel(const float* __restrict__ anchor,
                            const float* __restrict__ weight,
                            const float* __restrict__ t0,
                            const int* __restrict__ len,
                            float* __restrict__ na, float* __restrict__ nt,
                            float* __restrict__ lw2) {
  int wid  = (blockIdx.x * blockDim.x + threadIdx.x) >> 6;
  int lane = threadIdx.x & 63;
  const int nA = NB * NL;
  const int total = nA + NK * NR;
  if (wid >= total) return;
  const float* src = (wid < nA) ? (anchor + (size_t)wid * ND)
                                : (t0 + (size_t)(wid - nA) * ND);
  float s = 0.f;
  for (int d = lane; d < ND; d += 64) { float v = src[d]; s += v * v; }
  #pragma unroll
  for (int off = 32; off; off >>= 1) s += __shfl_xor(s, off);
  if (lane == 0) { if (wid < nA) na[wid] = s; else nt[wid - nA] = s; }
  if (wid < nA && lane == 1) {
    int b = wid >> 7, l = wid & 127;
    float w = weight[wid];
    lw2[wid] = (l < len[b]) ? log2f(fmaxf(w, 1e-12f)) : NEGL2;
  }
}

// ---------------------------------------------------------------- cost GEMM
// 128 threads, tile 128 rows x 64 cols, 8x8 microtile. KC=16, double-buffered
// LDS (pitch 20, k-quad XOR swizzle). Per chunk: load next chunk -> regs,
// compute current from LDS, ds_write regs -> other buffer, one barrier.
__global__ __launch_bounds__(128)
void cost_gemm(const float* __restrict__ X, const float* __restrict__ Y,
               const float* __restrict__ NX, const float* __restrict__ NY,
               float* __restrict__ C, int n, int m, int mode) {
  constexpr int KC = 16, PITCH = 20;
  constexpr int NCH = (ND + KC - 1) / KC;   // 19
  __shared__ float As[2][128 * PITCH];      // 2 x 10.0 KB
  __shared__ float Bs[2][64 * PITCH];       // 2 x 5.0 KB

  int p = blockIdx.x;
  int i0 = blockIdx.y * 128, j0 = blockIdx.z * 64;
  int xr0, yr0;
  if (mode == 0)      { xr0 = (p / NK) * NL; yr0 = (p % NK) * NR; }
  else if (mode == 1) { xr0 = p * NL;        yr0 = xr0;           }
  else                { xr0 = (p / NK) * NR; yr0 = (p % NK) * NR; }
  size_t cbase = (size_t)p * n * m;

  const int t  = threadIdx.x;
  const int ty = t >> 3, tx = t & 7;

  // ---- per-thread staging geometry (constant across chunks)
  int arow[4], aoff[4]; const float* aptr[4]; bool aval[4];
  #pragma unroll
  for (int q = 0; q < 4; ++q) {
    int f4id = q * 128 + t;
    int row = f4id >> 2, kq = f4id & 3;
    int sw  = kq ^ ((row >> 3) & 3);
    arow[q] = row;
    aoff[q] = row * PITCH + sw * 4;
    aval[q] = (i0 + row < n);
    aptr[q] = X + (size_t)(xr0 + i0 + row) * ND + kq * 4;
  }
  int boff[2]; const float* bptr[2]; bool bval[2]; int bkq[2];
  #pragma unroll
  for (int q = 0; q < 2; ++q) {
    int f4id = q * 128 + t;
    int row = f4id >> 2, kq = f4id & 3;
    int sw  = kq ^ ((row >> 3) & 3);
    boff[q] = row * PITCH + sw * 4;
    bval[q] = (j0 + row < m);
    bptr[q] = Y + (size_t)(yr0 + j0 + row) * ND + kq * 4;
    bkq[q]  = kq;
  }
  const int akq0 = t & 3;  // kq for A loads of q (same pattern: (q*128+t)&3 = t&3)

  float4 ra[4], rb[2];
  const float4 z4 = make_float4(0.f, 0.f, 0.f, 0.f);

  // ---- load chunk c into regs
  auto loadchunk = [&](int c) {
    int d0 = c * KC;
    #pragma unroll
    for (int q = 0; q < 4; ++q) {
      int d = d0 + akq0 * 4;
      ra[q] = (aval[q] && d < ND - 3) ? *(const float4*)(aptr[q] + d0) : z4;
    }
    #pragma unroll
    for (int q = 0; q < 2; ++q) {
      int d = d0 + bkq[q] * 4;
      rb[q] = (bval[q] && d < ND - 3) ? *(const float4*)(bptr[q] + d0) : z4;
    }
  };
  auto writebuf = [&](int buf) {
    #pragma unroll
    for (int q = 0; q < 4; ++q) *(float4*)(&As[buf][aoff[q]]) = ra[q];
    #pragma unroll
    for (int q = 0; q < 2; ++q) *(float4*)(&Bs[buf][boff[q]]) = rb[q];
  };

  float acc[8][8];
  #pragma unroll
  for (int i = 0; i < 8; ++i)
    #pragma unroll
    for (int j = 0; j < 8; ++j) acc[i][j] = 0.f;

  loadchunk(0);
  writebuf(0);
  __syncthreads();

  int cur = 0;
  for (int c = 0; c < NCH; ++c) {
    if (c + 1 < NCH) loadchunk(c + 1);        // async: loads in flight over compute

    const float* as = As[cur];
    const float* bs = Bs[cur];
    #pragma unroll
    for (int kk = 0; kk < KC; kk += 4) {
      int qa = ((kk >> 2) ^ (ty & 3)) * 4;
      int qb = ((kk >> 2) ^ (tx & 3)) * 4;
      float4 av[8];
      #pragma unroll
      for (int i = 0; i < 8; ++i)
        av[i] = *(const float4*)(as + (ty * 8 + i) * PITCH + qa);
      #pragma unroll
      for (int j = 0; j < 8; ++j) {
        float4 bv = *(const float4*)(bs + (tx * 8 + j) * PITCH + qb);
        #pragma unroll
        for (int i = 0; i < 8; ++i) {
          acc[i][j] += av[i].x * bv.x + av[i].y * bv.y
                     + av[i].z * bv.z + av[i].w * bv.w;
        }
      }
    }

    if (c + 1 < NCH) writebuf(cur ^ 1);       // other buffer: no reader this chunk
    __syncthreads();                          // ONE barrier per chunk
    cur ^= 1;
  }

  // ---- epilogue: C = max(|x|^2 + |y|^2 - 2 x.y, 0) * CSCALE
  #pragma unroll
  for (int i = 0; i < 8; ++i) {
    int gi = i0 + ty * 8 + i;
    if (gi >= n) continue;
    float nx = NX[xr0 + gi];
    float* crow = C + cbase + (size_t)gi * m;
    #pragma unroll
    for (int j = 0; j < 8; ++j) {
      int gj = j0 + tx * 8 + j;
      if (gj < m) {
        float sq = nx + NY[yr0 + gj] - 2.f * acc[i][j];
        crow[gj] = fmaxf(sq, 0.f) * CSCALE;
      }
    }
  }
}

// ---------------------------------------------------------------- sinkhorn ab
__global__ __launch_bounds__(256)
void sinkhorn_ab(const float* __restrict__ Cg, const float* __restrict__ lw2,
                 const float* __restrict__ weight, float* __restrict__ ot) {
  __shared__ float Cs[NL * 51];
  __shared__ float g2[NR];
  __shared__ float f2[NL];
  __shared__ float potf2[NL];
  __shared__ float la2s[NL];
  __shared__ float red[4];
  int p = blockIdx.x, b = p / NK, t = threadIdx.x;
  const float* Cp = Cg + (size_t)p * (NL * NR);
  for (int i = t; i < NL * NR; i += 256) {
    int r = i / NR, c = i - r * NR;
    Cs[r * 51 + c] = Cp[i];
  }
  if (t < NL) la2s[t] = lw2[b * NL + t];
  if (t < NR) g2[t] = 0.f;
  __syncthreads();

  const int rf = t >> 1, sf = t & 1;
  float Crow[25];
  {
    const float* rp = &Cs[rf * 51 + sf * 25];
    #pragma unroll
    for (int j = 0; j < 25; ++j) Crow[j] = rp[j];
  }
  const int cc = t >> 2, sc = t & 3;
  float Ccol[32];
  if (t < 200) {
    #pragma unroll
    for (int i = 0; i < 32; ++i) Ccol[i] = Cs[(sc * 32 + i) * 51 + cc];
  }

  float mEf = 0.f, mEg = 0.f;
  const float* gbase = g2 + sf * 25;
  const float* fbase = potf2 + sc * 32;

  for (int it = 0; it < NITER; ++it) {
    {
      float mx = -3.0e38f, s = 0.f;
      #pragma unroll
      for (int j = 0; j < 25; ++j) {
        float x = gbase[j] - Crow[j];
        mx = fmaxf(mx, x);
        s += exp2f(x - mEf);
      }
      mx = fmaxf(mx, __shfl_xor(mx, 1));
      s += __shfl_xor(s, 1);
      float mU = mEf, d = mx - mEf;
      if (d > D_HI || d < D_LO) {
        mU = mx; s = 0.f;
        #pragma unroll
        for (int j = 0; j < 25; ++j) s += exp2f(gbase[j] - Crow[j] - mx);
        s += __shfl_xor(s, 1);
      }
      mEf = mx;
      if (sf == 0) {
        float fv = LOG2_50 - (mU + log2f(s));
        f2[rf] = fv; potf2[rf] = la2s[rf] + fv;
      }
    }
    __syncthreads();
    if (t < 200) {
      float mx = -3.0e38f, s = 0.f;
      #pragma unroll
      for (int i = 0; i < 32; ++i) {
        float x = fbase[i] - Ccol[i];
        mx = fmaxf(mx, x);
        s += exp2f(x - mEg);
      }
      mx = fmaxf(mx, __shfl_xor(mx, 1));
      mx = fmaxf(mx, __shfl_xor(mx, 2));
      s += __shfl_xor(s, 1);
      s += __shfl_xor(s, 2);
      float mU = mEg, d = mx - mEg;
      if (d > D_HI || d < D_LO) {
        mU = mx; s = 0.f;
        #pragma unroll
        for (int i = 0; i < 32; ++i) s += exp2f(fbase[i] - Ccol[i] - mx);
        s += __shfl_xor(s, 1);
        s += __shfl_xor(s, 2);
      }
      mEg = mx;
      if (sc == 0) g2[cc] = -(mU + log2f(s));
    }
    __syncthreads();
  }

  float acc = 0.f;
  if (t < NL) acc = weight[b * NL + t] * f2[t];
  else if (t < NL + NR) acc = g2[t - NL] * (1.0f / NR);
  #pragma unroll
  for (int off = 32; off; off >>= 1) acc += __shfl_xor(acc, off);
  if ((t & 63) == 0) red[t >> 6] = acc;
  __syncthreads();
  if (t == 0) ot[p] = VSCALE * (red[0] + red[1] + red[2] + red[3]);
}

// ---------------------------------------------------------------- sinkhorn aa
__global__ __launch_bounds__(512)
void sinkhorn_aa(const float* __restrict__ Cg, const float* __restrict__ lw2,
                 const float* __restrict__ weight, float* __restrict__ ot) {
  __shared__ float pF[NL];
  __shared__ float pG[NL];
  __shared__ float red[8];
  int b = blockIdx.x, t = threadIdx.x;
  int r = t >> 2, sub = t & 3;
  const float* Cp = Cg + (size_t)b * (NL * NL) + (size_t)r * NL + sub * 32;
  const float* lp = lw2 + b * NL + sub * 32;
  float Cr[32];
  #pragma unroll
  for (int i = 0; i < 32; i += 4) {
    float4 cv = *(const float4*)(Cp + i);
    float4 lv = *(const float4*)(lp + i);
    Cr[i]     = lv.x - cv.x; Cr[i + 1] = lv.y - cv.y;
    Cr[i + 2] = lv.z - cv.z; Cr[i + 3] = lv.w - cv.w;
  }
  if (t < NL) pG[t] = 0.f;
  __syncthreads();

  float mE = 0.f;
  for (int app = 0; app < 2 * NITER; ++app) {
    const float* src = (app & 1) ? pF : pG;
    float* dst       = (app & 1) ? pG : pF;
    const float* sp = src + sub * 32;
    float mx = -3.0e38f, s = 0.f;
    #pragma unroll
    for (int i = 0; i < 32; ++i) {
      float x = sp[i] + Cr[i];
      mx = fmaxf(mx, x);
      s += exp2f(x - mE);
    }
    mx = fmaxf(mx, __shfl_xor(mx, 1));
    mx = fmaxf(mx, __shfl_xor(mx, 2));
    s += __shfl_xor(s, 1);
    s += __shfl_xor(s, 2);
    float mU = mE, d = mx - mE;
    if (d > D_HI || d < D_LO) {
      mU = mx; s = 0.f;
      #pragma unroll
      for (int i = 0; i < 32; ++i) s += exp2f(sp[i] + Cr[i] - mx);
      s += __shfl_xor(s, 1);
      s += __shfl_xor(s, 2);
    }
    mE = mx;
    if (sub == 0) dst[r] = -(mU + log2f(s));
    __syncthreads();
  }

  float acc = 0.f;
  if (t < NL) acc = weight[b * NL + t] * (pF[t] + pG[t]);
  #pragma unroll
  for (int off = 32; off; off >>= 1) acc += __shfl_xor(acc, off);
  if ((t & 63) == 0) red[t >> 6] = acc;
  __syncthreads();
  if (t == 0) {
    float v = 0.f;
    #pragma unroll
    for (int i = 0; i < 8; ++i) v += red[i];
    ot[b] = VSCALE * v;
  }
}

// ---------------------------------------------------------------- sinkhorn tt
__global__ __launch_bounds__(256)
void sinkhorn_tt(const float* __restrict__ Cg, float* __restrict__ ot) {
  __shared__ float Cs[NR * 51];
  __shared__ float f2[NR], g2[NR];
  __shared__ float red[4];
  int p = blockIdx.x, t = threadIdx.x;
  const float* Cp = Cg + (size_t)p * (NR * NR);
  for (int i = t; i < NR * NR; i += 256) {
    int r = i / NR, c = i - r * NR;
    Cs[r * 51 + c] = Cp[i];
  }
  if (t < NR) g2[t] = 0.f;
  __syncthreads();

  int r = t >> 2, sub = t & 3;
  for (int it = 0; it < NITER; ++it) {
    if (r < NR) {
      const float* row = &Cs[r * 51];
      float mx = -INFINITY;
      for (int mm = sub; mm < NR; mm += 4) mx = fmaxf(mx, g2[mm] - row[mm]);
      mx = fmaxf(mx, __shfl_xor(mx, 1));
      mx = fmaxf(mx, __shfl_xor(mx, 2));
      float s = 0.f;
      for (int mm = sub; mm < NR; mm += 4) s += exp2f(g2[mm] - row[mm] - mx);
      s += __shfl_xor(s, 1);
      s += __shfl_xor(s, 2);
      if (sub == 0) f2[r] = LOG2_50 - mx - log2f(s);
    }
    __syncthreads();
    if (r < NR) {
      float mx = -INFINITY;
      for (int nn = sub; nn < NR; nn += 4) mx = fmaxf(mx, f2[nn] - Cs[nn * 51 + r]);
      mx = fmaxf(mx, __shfl_xor(mx, 1));
      mx = fmaxf(mx, __shfl_xor(mx, 2));
      float s = 0.f;
      for (int nn = sub; nn < NR; nn += 4) s += exp2f(f2[nn] - Cs[nn * 51 + r] - mx);
      s += __shfl_xor(s, 1);
      s += __shfl_xor(s, 2);
      if (sub == 0) g2[r] = LOG2_50 - mx - log2f(s);
    }
    __syncthreads();
  }

  float acc = 0.f;
  if (t < NR) acc = f2[t] + g2[t];
  #pragma unroll
  for (int off = 32; off; off >>= 1) acc += __shfl_xor(acc, off);
  if ((t & 63) == 0) red[t >> 6] = acc;
  __syncthreads();
  if (t == 0) ot[p] = VSCALE * (1.0f / NR) * (red[0] + red[1] + red[2] + red[3]);
}

// ---------------------------------------------------------------- finalize
__global__ void finalize_kernel(const float* __restrict__ oab, const float* __restrict__ oaa,
                                const float* __restrict__ ott, const int* __restrict__ grade,
                                float* __restrict__ out) {
  __shared__ float selft[NK];
  __shared__ float redL[4], redD[4];
  int t = threadIdx.x;
  if (t < NK) selft[t] = ott[t * NK + t];
  __syncthreads();
  float dpart = (t < NK * NK) ? ott[t] : 0.f;
  float lpart = 0.f;
  if (t < NB) {
    int g = grade[t];
    float oa = oaa[t];
    float dpos = oab[t * NK + g] - 0.5f * (oa + selft[g]);
    float s = 0.f;
    #pragma unroll
    for (int k = 0; k < NK; ++k) {
      float dk = oab[t * NK + k] - 0.5f * (oa + selft[k]);
      s += fmaxf(dpos - dk + 10.0f, 0.0f);
    }
    lpart = s - 10.0f;
  }
  #pragma unroll
  for (int off = 32; off; off >>= 1) {
    dpart += __shfl_xor(dpart, off);
    lpart += __shfl_xor(lpart, off);
  }
  if ((t & 63) == 0) { redD[t >> 6] = dpart; redL[t >> 6] = lpart; }
  __syncthreads();
  if (t == 0) {
    float ds = 0.f, ls = 0.f;
    #pragma unroll
    for (int i = 0; i < 4; ++i) { ds += redD[i]; ls += redL[i]; }
    float ss = 0.f;
    #pragma unroll
    for (int k = 0; k < NK; ++k) ss += selft[k];
    float dis = ds - (float)NK * ss;
    out[0] = ls / (float)NB - dis * 0.01f;
  }
}

// ---------------------------------------------------------------- launch
extern "C" void kernel_launch(void* const* d_in, const int* in_sizes, int n_in,
                              void* d_out, int out_size, void* d_ws, size_t ws_size,
                              hipStream_t stream) {
  (void)in_sizes; (void)n_in; (void)out_size; (void)ws_size;
  const float* anchor = (const float*)d_in[0];
  const float* weight = (const float*)d_in[1];
  const float* t0     = (const float*)d_in[2];
  const int*   len    = (const int*)d_in[3];
  const int*   grade  = (const int*)d_in[4];
  float* out = (float*)d_out;

  float* ws  = (float*)d_ws;
  float* Cab = ws;                                    // 819200
  float* Caa = Cab + (size_t)NB * NK * NL * NR;       // 2097152
  float* Ctt = Caa + (size_t)NB * NL * NL;            // 250000
  float* na  = Ctt + (size_t)NK * NK * NR * NR;       // 16384
  float* nt  = na + NB * NL;                          // 500
  float* lw2 = nt + NK * NR;                          // 16384
  float* oab = lw2 + NB * NL;                         // 1280
  float* oaa = oab + NB * NK;                         // 128
  float* ott = oaa + NB;                              // 100

  prep_kernel<<<(NB * NL + NK * NR) / 4, 256, 0, stream>>>(anchor, weight, t0, len, na, nt, lw2);
  cost_gemm<<<dim3(NB * NK, 1, 1), 128, 0, stream>>>(anchor, t0, na, nt, Cab, NL, NR, 0);
  cost_gemm<<<dim3(NB, 1, 2),      128, 0, stream>>>(anchor, anchor, na, na, Caa, NL, NL, 1);
  cost_gemm<<<dim3(NK * NK, 1, 1), 128, 0, stream>>>(t0, t0, nt, nt, Ctt, NR, NR, 2);
  sinkhorn_ab<<<NB * NK, 256, 0, stream>>>(Cab, lw2, weight, oab);
  sinkhorn_aa<<<NB, 512, 0, stream>>>(Caa, lw2, weight, oaa);
  sinkhorn_tt<<<NK * NK, 256, 0, stream>>>(Ctt, ott);
  finalize_kernel<<<1, 256, 0, stream>>>(oab, oaa, ott, grade, out);
}

// Round 7
// 336.472 us; speedup vs baseline: 9.0457x; 2.0081x over previous
//
#include <hip/hip_runtime.h>
#include <math.h>

// Sinkhorn-divergence triplet loss (geomloss-style), MI355X.
// R7: cost matrices via MFMA (bf16 hi/lo split, 3 MFMAs = fp32-ish accuracy).
// ab flattened to one 16384x500 GEMM, tt to one 500x500 GEMM, aa per-b batched
// (A=B shares one LDS stage). fp32->2xbf16 conversion inline during staging.
// Epilogues write the SAME blocked C layouts as R2-R6, so Sinkhorn kernels
// (reg-resident C, defer-max LSE) are unchanged.
// Launch-bounds law (R3/R4): VGPR cap = 256/arg2 -> never pass arg2.

namespace {
constexpr int NB = 128, NL = 128, ND = 300, NK = 10, NR = 50, NITER = 20;
constexpr float LOG2E   = 1.4426950408889634f;
constexpr float EPS     = 0.0025f;                  // blur^p = 0.05^2
constexpr float CSCALE  = 0.5f * LOG2E / EPS;       // squared-dist -> log2-domain cost
constexpr float VSCALE  = EPS * 0.6931471805599453f; // log2-potential -> nat (eps*ln2)
constexpr float LOG2_50 = 5.6438561897747395f;      // log2(50)
constexpr float NEGL2   = -1.442695e9f;             // -1e9 * log2e
constexpr float D_HI    = 30.f, D_LO = -80.f;       // defer-max redo window
constexpr int KCH = 10;                              // K chunks of 32 (300 padded 320)
constexpr int PIT = 40;                              // LDS pitch in shorts (80 B)
}

typedef __attribute__((ext_vector_type(8))) short bf16x8;
typedef __attribute__((ext_vector_type(4))) float f32x4;

__device__ inline unsigned short f2bf_rn(float x) {
  unsigned int u = __float_as_uint(x);
  unsigned int r = (u + 0x7fffu + ((u >> 16) & 1u)) >> 16;
  return (unsigned short)r;
}
__device__ inline float bf2f(unsigned short h) {
  return __uint_as_float((unsigned int)h << 16);
}

// ---------------------------------------------------------------- prep
__global__ void prep_kernel(const float* __restrict__ anchor,
                            const float* __restrict__ weight,
                            const float* __restrict__ t0,
                            const int* __restrict__ len,
                            float* __restrict__ na, float* __restrict__ nt,
                            float* __restrict__ lw2) {
  int wid  = (blockIdx.x * blockDim.x + threadIdx.x) >> 6;
  int lane = threadIdx.x & 63;
  const int nA = NB * NL;
  const int total = nA + NK * NR;
  if (wid >= total) return;
  const float* src = (wid < nA) ? (anchor + (size_t)wid * ND)
                                : (t0 + (size_t)(wid - nA) * ND);
  float s = 0.f;
  for (int d = lane; d < ND; d += 64) { float v = src[d]; s += v * v; }
  #pragma unroll
  for (int off = 32; off; off >>= 1) s += __shfl_xor(s, off);
  if (lane == 0) { if (wid < nA) na[wid] = s; else nt[wid - nA] = s; }
  if (wid < nA && lane == 1) {
    int b = wid >> 7, l = wid & 127;
    float w = weight[wid];
    lw2[wid] = (l < len[b]) ? log2f(fmaxf(w, 1e-12f)) : NEGL2;
  }
}

// ---------------------------------------------------------------- staging helper
// thread t stages 8 consecutive k of one row: row = t>>2, kq = t&3 (k = kq*8).
__device__ inline void stage8(const float* __restrict__ src, bool rowvalid,
                              int kg, short* __restrict__ Hs, short* __restrict__ Ls,
                              int lofs) {
  float xv[8];
  if (rowvalid && kg + 8 <= ND) {
    float4 u = *(const float4*)(src + kg);
    float4 v = *(const float4*)(src + kg + 4);
    xv[0]=u.x; xv[1]=u.y; xv[2]=u.z; xv[3]=u.w;
    xv[4]=v.x; xv[5]=v.y; xv[6]=v.z; xv[7]=v.w;
  } else {
    #pragma unroll
    for (int e = 0; e < 8; ++e)
      xv[e] = (rowvalid && kg + e < ND) ? src[kg + e] : 0.f;
  }
  bf16x8 hv, lv;
  #pragma unroll
  for (int e = 0; e < 8; ++e) {
    unsigned short h = f2bf_rn(xv[e]);
    float hf = bf2f(h);
    unsigned short l = f2bf_rn(xv[e] - hf);
    hv[e] = (short)h; lv[e] = (short)l;
  }
  *(bf16x8*)(Hs + lofs) = hv;
  *(bf16x8*)(Ls + lofs) = lv;
}

// ---------------------------------------------------------------- cost MFMA (ab / tt)
// 512 threads, 8 waves, tile 128 rows x 128 cols. Wave w: rows 16w..16w+16,
// 8 col-tiles of 16. Per 32-k chunk: stage A/B hi+lo in LDS, 3 MFMAs per tile.
// mode 0: ab flat GEMM anchor(16384) x t0(500), C -> blocked [b*10+k][128][50]
// mode 2: tt flat GEMM t0(500) x t0(500),      C -> blocked [ki*10+kj][50][50]
__global__ __launch_bounds__(512)
void cost_mfma(const float* __restrict__ X, const float* __restrict__ Y,
               const float* __restrict__ NX, const float* __restrict__ NY,
               float* __restrict__ C, int nX, int nY, int mode) {
  __shared__ __align__(16) short Ah[128 * PIT], Al[128 * PIT];
  __shared__ __align__(16) short Bh[128 * PIT], Bl[128 * PIT];

  const int t = threadIdx.x;
  const int i0 = blockIdx.x * 128, j0 = blockIdx.y * 128;
  const int srow = t >> 2, skq = t & 3, kloc = skq * 8;
  const int lofs = srow * PIT + kloc;
  const bool avalid = (i0 + srow) < nX;
  const bool bvalid = (j0 + srow) < nY;
  const float* aro = X + (size_t)(i0 + srow) * ND;
  const float* bro = Y + (size_t)(j0 + srow) * ND;

  const int lane = t & 63, w = t >> 6;
  const int fr = lane & 15, fo = (lane >> 4) * 8;   // frag row-in-tile, k-offset
  const int aofs = (w * 16 + fr) * PIT + fo;

  f32x4 acc[8];
  #pragma unroll
  for (int cc = 0; cc < 8; ++cc) acc[cc] = (f32x4){0.f, 0.f, 0.f, 0.f};

  for (int c = 0; c < KCH; ++c) {
    int kg = c * 32 + kloc;
    stage8(aro, avalid, kg, Ah, Al, lofs);
    stage8(bro, bvalid, kg, Bh, Bl, lofs);
    __syncthreads();

    bf16x8 ah = *(const bf16x8*)(Ah + aofs);
    bf16x8 al = *(const bf16x8*)(Al + aofs);
    #pragma unroll
    for (int cc = 0; cc < 8; ++cc) {
      int bofs = (cc * 16 + fr) * PIT + fo;
      bf16x8 bh = *(const bf16x8*)(Bh + bofs);
      bf16x8 bl = *(const bf16x8*)(Bl + bofs);
      acc[cc] = __builtin_amdgcn_mfma_f32_16x16x32_bf16(ah, bh, acc[cc], 0, 0, 0);
      acc[cc] = __builtin_amdgcn_mfma_f32_16x16x32_bf16(ah, bl, acc[cc], 0, 0, 0);
      acc[cc] = __builtin_amdgcn_mfma_f32_16x16x32_bf16(al, bh, acc[cc], 0, 0, 0);
    }
    __syncthreads();
  }

  // epilogue: C layout col=lane&15, row=(lane>>4)*4+reg (m89-verified)
  #pragma unroll
  for (int cc = 0; cc < 8; ++cc) {
    int gj = j0 + cc * 16 + fr;
    if (gj >= nY) continue;
    float ny = NY[gj];
    #pragma unroll
    for (int reg = 0; reg < 4; ++reg) {
      int gi = i0 + w * 16 + (lane >> 4) * 4 + reg;
      if (gi >= nX) continue;
      float sq = NX[gi] + ny - 2.f * acc[cc][reg];
      float cv = fmaxf(sq, 0.f) * CSCALE;
      if (mode == 0) {
        int k = gj / 50, jj = gj - k * 50;
        C[((size_t)((gi >> 7) * NK + k)) * (NL * NR) + (gi & 127) * NR + jj] = cv;
      } else {
        int ki = gi / 50, ii = gi - ki * 50;
        int kj = gj / 50, jj = gj - kj * 50;
        C[((size_t)(ki * NK + kj)) * (NR * NR) + ii * NR + jj] = cv;
      }
    }
  }
}

// ---------------------------------------------------------------- cost MFMA (aa, A=B per block)
__global__ __launch_bounds__(512)
void cost_mfma_aa(const float* __restrict__ X, const float* __restrict__ NX,
                  float* __restrict__ C) {
  __shared__ __align__(16) short Ah[128 * PIT], Al[128 * PIT];

  const int t = threadIdx.x, b = blockIdx.x;
  const int srow = t >> 2, skq = t & 3, kloc = skq * 8;
  const int lofs = srow * PIT + kloc;
  const float* aro = X + (size_t)(b * NL + srow) * ND;

  const int lane = t & 63, w = t >> 6;
  const int fr = lane & 15, fo = (lane >> 4) * 8;
  const int aofs = (w * 16 + fr) * PIT + fo;

  f32x4 acc[8];
  #pragma unroll
  for (int cc = 0; cc < 8; ++cc) acc[cc] = (f32x4){0.f, 0.f, 0.f, 0.f};

  for (int c = 0; c < KCH; ++c) {
    stage8(aro, true, c * 32 + kloc, Ah, Al, lofs);
    __syncthreads();

    bf16x8 ah = *(const bf16x8*)(Ah + aofs);
    bf16x8 al = *(const bf16x8*)(Al + aofs);
    #pragma unroll
    for (int cc = 0; cc < 8; ++cc) {
      int bofs = (cc * 16 + fr) * PIT + fo;
      bf16x8 bh = *(const bf16x8*)(Ah + bofs);
      bf16x8 bl = *(const bf16x8*)(Al + bofs);
      acc[cc] = __builtin_amdgcn_mfma_f32_16x16x32_bf16(ah, bh, acc[cc], 0, 0, 0);
      acc[cc] = __builtin_amdgcn_mfma_f32_16x16x32_bf16(ah, bl, acc[cc], 0, 0, 0);
      acc[cc] = __builtin_amdgcn_mfma_f32_16x16x32_bf16(al, bh, acc[cc], 0, 0, 0);
    }
    __syncthreads();
  }

  const float* nb = NX + b * NL;
  float* Cb = C + (size_t)b * (NL * NL);
  #pragma unroll
  for (int cc = 0; cc < 8; ++cc) {
    int gj = cc * 16 + fr;
    float ny = nb[gj];
    #pragma unroll
    for (int reg = 0; reg < 4; ++reg) {
      int gi = w * 16 + (lane >> 4) * 4 + reg;
      float sq = nb[gi] + ny - 2.f * acc[cc][reg];
      Cb[(size_t)gi * NL + gj] = fmaxf(sq, 0.f) * CSCALE;
    }
  }
}

// ---------------------------------------------------------------- sinkhorn ab
__global__ __launch_bounds__(256)
void sinkhorn_ab(const float* __restrict__ Cg, const float* __restrict__ lw2,
                 const float* __restrict__ weight, float* __restrict__ ot) {
  __shared__ float Cs[NL * 51];
  __shared__ float g2[NR];
  __shared__ float f2[NL];
  __shared__ float potf2[NL];
  __shared__ float la2s[NL];
  __shared__ float red[4];
  int p = blockIdx.x, b = p / NK, t = threadIdx.x;
  const float* Cp = Cg + (size_t)p * (NL * NR);
  for (int i = t; i < NL * NR; i += 256) {
    int r = i / NR, c = i - r * NR;
    Cs[r * 51 + c] = Cp[i];
  }
  if (t < NL) la2s[t] = lw2[b * NL + t];
  if (t < NR) g2[t] = 0.f;
  __syncthreads();

  const int rf = t >> 1, sf = t & 1;
  float Crow[25];
  {
    const float* rp = &Cs[rf * 51 + sf * 25];
    #pragma unroll
    for (int j = 0; j < 25; ++j) Crow[j] = rp[j];
  }
  const int cc = t >> 2, sc = t & 3;
  float Ccol[32];
  if (t < 200) {
    #pragma unroll
    for (int i = 0; i < 32; ++i) Ccol[i] = Cs[(sc * 32 + i) * 51 + cc];
  }

  float mEf = 0.f, mEg = 0.f;
  const float* gbase = g2 + sf * 25;
  const float* fbase = potf2 + sc * 32;

  for (int it = 0; it < NITER; ++it) {
    {
      float mx = -3.0e38f, s = 0.f;
      #pragma unroll
      for (int j = 0; j < 25; ++j) {
        float x = gbase[j] - Crow[j];
        mx = fmaxf(mx, x);
        s += exp2f(x - mEf);
      }
      mx = fmaxf(mx, __shfl_xor(mx, 1));
      s += __shfl_xor(s, 1);
      float mU = mEf, d = mx - mEf;
      if (d > D_HI || d < D_LO) {
        mU = mx; s = 0.f;
        #pragma unroll
        for (int j = 0; j < 25; ++j) s += exp2f(gbase[j] - Crow[j] - mx);
        s += __shfl_xor(s, 1);
      }
      mEf = mx;
      if (sf == 0) {
        float fv = LOG2_50 - (mU + log2f(s));
        f2[rf] = fv; potf2[rf] = la2s[rf] + fv;
      }
    }
    __syncthreads();
    if (t < 200) {
      float mx = -3.0e38f, s = 0.f;
      #pragma unroll
      for (int i = 0; i < 32; ++i) {
        float x = fbase[i] - Ccol[i];
        mx = fmaxf(mx, x);
        s += exp2f(x - mEg);
      }
      mx = fmaxf(mx, __shfl_xor(mx, 1));
      mx = fmaxf(mx, __shfl_xor(mx, 2));
      s += __shfl_xor(s, 1);
      s += __shfl_xor(s, 2);
      float mU = mEg, d = mx - mEg;
      if (d > D_HI || d < D_LO) {
        mU = mx; s = 0.f;
        #pragma unroll
        for (int i = 0; i < 32; ++i) s += exp2f(fbase[i] - Ccol[i] - mx);
        s += __shfl_xor(s, 1);
        s += __shfl_xor(s, 2);
      }
      mEg = mx;
      if (sc == 0) g2[cc] = -(mU + log2f(s));
    }
    __syncthreads();
  }

  float acc = 0.f;
  if (t < NL) acc = weight[b * NL + t] * f2[t];
  else if (t < NL + NR) acc = g2[t - NL] * (1.0f / NR);
  #pragma unroll
  for (int off = 32; off; off >>= 1) acc += __shfl_xor(acc, off);
  if ((t & 63) == 0) red[t >> 6] = acc;
  __syncthreads();
  if (t == 0) ot[p] = VSCALE * (red[0] + red[1] + red[2] + red[3]);
}

// ---------------------------------------------------------------- sinkhorn aa
__global__ __launch_bounds__(512)
void sinkhorn_aa(const float* __restrict__ Cg, const float* __restrict__ lw2,
                 const float* __restrict__ weight, float* __restrict__ ot) {
  __shared__ float pF[NL];
  __shared__ float pG[NL];
  __shared__ float red[8];
  int b = blockIdx.x, t = threadIdx.x;
  int r = t >> 2, sub = t & 3;
  const float* Cp = Cg + (size_t)b * (NL * NL) + (size_t)r * NL + sub * 32;
  const float* lp = lw2 + b * NL + sub * 32;
  float Cr[32];
  #pragma unroll
  for (int i = 0; i < 32; i += 4) {
    float4 cv = *(const float4*)(Cp + i);
    float4 lv = *(const float4*)(lp + i);
    Cr[i]     = lv.x - cv.x; Cr[i + 1] = lv.y - cv.y;
    Cr[i + 2] = lv.z - cv.z; Cr[i + 3] = lv.w - cv.w;
  }
  if (t < NL) pG[t] = 0.f;
  __syncthreads();

  float mE = 0.f;
  for (int app = 0; app < 2 * NITER; ++app) {
    const float* src = (app & 1) ? pF : pG;
    float* dst       = (app & 1) ? pG : pF;
    const float* sp = src + sub * 32;
    float mx = -3.0e38f, s = 0.f;
    #pragma unroll
    for (int i = 0; i < 32; ++i) {
      float x = sp[i] + Cr[i];
      mx = fmaxf(mx, x);
      s += exp2f(x - mE);
    }
    mx = fmaxf(mx, __shfl_xor(mx, 1));
    mx = fmaxf(mx, __shfl_xor(mx, 2));
    s += __shfl_xor(s, 1);
    s += __shfl_xor(s, 2);
    float mU = mE, d = mx - mE;
    if (d > D_HI || d < D_LO) {
      mU = mx; s = 0.f;
      #pragma unroll
      for (int i = 0; i < 32; ++i) s += exp2f(sp[i] + Cr[i] - mx);
      s += __shfl_xor(s, 1);
      s += __shfl_xor(s, 2);
    }
    mE = mx;
    if (sub == 0) dst[r] = -(mU + log2f(s));
    __syncthreads();
  }

  float acc = 0.f;
  if (t < NL) acc = weight[b * NL + t] * (pF[t] + pG[t]);
  #pragma unroll
  for (int off = 32; off; off >>= 1) acc += __shfl_xor(acc, off);
  if ((t & 63) == 0) red[t >> 6] = acc;
  __syncthreads();
  if (t == 0) {
    float v = 0.f;
    #pragma unroll
    for (int i = 0; i < 8; ++i) v += red[i];
    ot[b] = VSCALE * v;
  }
}

// ---------------------------------------------------------------- sinkhorn tt
__global__ __launch_bounds__(256)
void sinkhorn_tt(const float* __restrict__ Cg, float* __restrict__ ot) {
  __shared__ float Cs[NR * 51];
  __shared__ float f2[NR], g2[NR];
  __shared__ float red[4];
  int p = blockIdx.x, t = threadIdx.x;
  const float* Cp = Cg + (size_t)p * (NR * NR);
  for (int i = t; i < NR * NR; i += 256) {
    int r = i / NR, c = i - r * NR;
    Cs[r * 51 + c] = Cp[i];
  }
  if (t < NR) g2[t] = 0.f;
  __syncthreads();

  int r = t >> 2, sub = t & 3;
  for (int it = 0; it < NITER; ++it) {
    if (r < NR) {
      const float* row = &Cs[r * 51];
      float mx = -INFINITY;
      for (int mm = sub; mm < NR; mm += 4) mx = fmaxf(mx, g2[mm] - row[mm]);
      mx = fmaxf(mx, __shfl_xor(mx, 1));
      mx = fmaxf(mx, __shfl_xor(mx, 2));
      float s = 0.f;
      for (int mm = sub; mm < NR; mm += 4) s += exp2f(g2[mm] - row[mm] - mx);
      s += __shfl_xor(s, 1);
      s += __shfl_xor(s, 2);
      if (sub == 0) f2[r] = LOG2_50 - mx - log2f(s);
    }
    __syncthreads();
    if (r < NR) {
      float mx = -INFINITY;
      for (int nn = sub; nn < NR; nn += 4) mx = fmaxf(mx, f2[nn] - Cs[nn * 51 + r]);
      mx = fmaxf(mx, __shfl_xor(mx, 1));
      mx = fmaxf(mx, __shfl_xor(mx, 2));
      float s = 0.f;
      for (int nn = sub; nn < NR; nn += 4) s += exp2f(f2[nn] - Cs[nn * 51 + r] - mx);
      s += __shfl_xor(s, 1);
      s += __shfl_xor(s, 2);
      if (sub == 0) g2[r] = LOG2_50 - mx - log2f(s);
    }
    __syncthreads();
  }

  float acc = 0.f;
  if (t < NR) acc = f2[t] + g2[t];
  #pragma unroll
  for (int off = 32; off; off >>= 1) acc += __shfl_xor(acc, off);
  if ((t & 63) == 0) red[t >> 6] = acc;
  __syncthreads();
  if (t == 0) ot[p] = VSCALE * (1.0f / NR) * (red[0] + red[1] + red[2] + red[3]);
}

// ---------------------------------------------------------------- finalize
__global__ void finalize_kernel(const float* __restrict__ oab, const float* __restrict__ oaa,
                                const float* __restrict__ ott, const int* __restrict__ grade,
                                float* __restrict__ out) {
  __shared__ float selft[NK];
  __shared__ float redL[4], redD[4];
  int t = threadIdx.x;
  if (t < NK) selft[t] = ott[t * NK + t];
  __syncthreads();
  float dpart = (t < NK * NK) ? ott[t] : 0.f;
  float lpart = 0.f;
  if (t < NB) {
    int g = grade[t];
    float oa = oaa[t];
    float dpos = oab[t * NK + g] - 0.5f * (oa + selft[g]);
    float s = 0.f;
    #pragma unroll
    for (int k = 0; k < NK; ++k) {
      float dk = oab[t * NK + k] - 0.5f * (oa + selft[k]);
      s += fmaxf(dpos - dk + 10.0f, 0.0f);
    }
    lpart = s - 10.0f;
  }
  #pragma unroll
  for (int off = 32; off; off >>= 1) {
    dpart += __shfl_xor(dpart, off);
    lpart += __shfl_xor(lpart, off);
  }
  if ((t & 63) == 0) { redD[t >> 6] = dpart; redL[t >> 6] = lpart; }
  __syncthreads();
  if (t == 0) {
    float ds = 0.f, ls = 0.f;
    #pragma unroll
    for (int i = 0; i < 4; ++i) { ds += redD[i]; ls += redL[i]; }
    float ss = 0.f;
    #pragma unroll
    for (int k = 0; k < NK; ++k) ss += selft[k];
    float dis = ds - (float)NK * ss;
    out[0] = ls / (float)NB - dis * 0.01f;
  }
}

// ---------------------------------------------------------------- launch
extern "C" void kernel_launch(void* const* d_in, const int* in_sizes, int n_in,
                              void* d_out, int out_size, void* d_ws, size_t ws_size,
                              hipStream_t stream) {
  (void)in_sizes; (void)n_in; (void)out_size; (void)ws_size;
  const float* anchor = (const float*)d_in[0];
  const float* weight = (const float*)d_in[1];
  const float* t0     = (const float*)d_in[2];
  const int*   len    = (const int*)d_in[3];
  const int*   grade  = (const int*)d_in[4];
  float* out = (float*)d_out;

  float* ws  = (float*)d_ws;
  float* Cab = ws;                                    // 819200
  float* Caa = Cab + (size_t)NB * NK * NL * NR;       // 2097152
  float* Ctt = Caa + (size_t)NB * NL * NL;            // 250000
  float* na  = Ctt + (size_t)NK * NK * NR * NR;       // 16384
  float* nt  = na + NB * NL;                          // 500
  float* lw2 = nt + NK * NR;                          // 16384
  float* oab = lw2 + NB * NL;                         // 1280
  float* oaa = oab + NB * NK;                         // 128
  float* ott = oaa + NB;                              // 100

  prep_kernel<<<(NB * NL + NK * NR) / 4, 256, 0, stream>>>(anchor, weight, t0, len, na, nt, lw2);
  // ab: flat 16384 x 500 GEMM (tiles 128x128 -> grid 128 x 4)
  cost_mfma<<<dim3(128, 4), 512, 0, stream>>>(anchor, t0, na, nt, Cab,
                                              NB * NL, NK * NR, 0);
  // tt: flat 500 x 500 GEMM (grid 4 x 4)
  cost_mfma<<<dim3(4, 4), 512, 0, stream>>>(t0, t0, nt, nt, Ctt,
                                            NK * NR, NK * NR, 2);
  // aa: per-b 128 x 128, A = B
  cost_mfma_aa<<<NB, 512, 0, stream>>>(anchor, na, Caa);

  sinkhorn_ab<<<NB * NK, 256, 0, stream>>>(Cab, lw2, weight, oab);
  sinkhorn_aa<<<NB, 512, 0, stream>>>(Caa, lw2, weight, oaa);
  sinkhorn_tt<<<NK * NK, 256, 0, stream>>>(Ctt, ott);
  finalize_kernel<<<1, 256, 0, stream>>>(oab, oaa, ott, grade, out);
}

// Round 8
// 293.862 us; speedup vs baseline: 10.3573x; 1.1450x over previous
//
#include <hip/hip_runtime.h>
#include <math.h>

// Sinkhorn-divergence triplet loss (geomloss-style), MI355X.
// R8: Sinkhorn inner loops reduced to {add, exp2, add} per element by folding
// the log-domain stabilizer into the register-resident cost (Crowb = -C - B)
// and guarding on the SUM range instead of tracking the max. Redo path
// (recompute max, re-bias) triggers only at iter 1 / large potential moves.
// sinkhorn_tt fused into the sinkhorn_ab launch (same 256-thread shape).
// Cost matrices via MFMA (R7, split-bf16 3-MFMA). Launch-bounds law: never
// pass arg2 (VGPR cap = 256/arg2, measured R3/R4).

namespace {
constexpr int NB = 128, NL = 128, ND = 300, NK = 10, NR = 50, NITER = 20;
constexpr float LOG2E   = 1.4426950408889634f;
constexpr float EPS     = 0.0025f;                  // blur^p = 0.05^2
constexpr float CSCALE  = 0.5f * LOG2E / EPS;       // squared-dist -> log2-domain cost
constexpr float VSCALE  = EPS * 0.6931471805599453f; // log2-potential -> nat (eps*ln2)
constexpr float LOG2_50 = 5.6438561897747395f;      // log2(50)
constexpr float NEGL2   = -1.442695e9f;             // -1e9 * log2e
constexpr float S_LO    = 1e-30f, S_HI = 1e30f;     // sum guard window
constexpr int KCH = 10;                              // K chunks of 32
constexpr int PIT = 40;                              // LDS pitch in shorts
}

typedef __attribute__((ext_vector_type(8))) short bf16x8;
typedef __attribute__((ext_vector_type(4))) float f32x4;

__device__ inline unsigned short f2bf_rn(float x) {
  unsigned int u = __float_as_uint(x);
  unsigned int r = (u + 0x7fffu + ((u >> 16) & 1u)) >> 16;
  return (unsigned short)r;
}
__device__ inline float bf2f(unsigned short h) {
  return __uint_as_float((unsigned int)h << 16);
}
__device__ inline bool s_ok(float s) { return (s >= S_LO) && (s <= S_HI); }

// ---------------------------------------------------------------- prep
__global__ void prep_kernel(const float* __restrict__ anchor,
                            const float* __restrict__ weight,
                            const float* __restrict__ t0,
                            const int* __restrict__ len,
                            float* __restrict__ na, float* __restrict__ nt,
                            float* __restrict__ lw2) {
  int wid  = (blockIdx.x * blockDim.x + threadIdx.x) >> 6;
  int lane = threadIdx.x & 63;
  const int nA = NB * NL;
  const int total = nA + NK * NR;
  if (wid >= total) return;
  const float* src = (wid < nA) ? (anchor + (size_t)wid * ND)
                                : (t0 + (size_t)(wid - nA) * ND);
  float s = 0.f;
  for (int d = lane; d < ND; d += 64) { float v = src[d]; s += v * v; }
  #pragma unroll
  for (int off = 32; off; off >>= 1) s += __shfl_xor(s, off);
  if (lane == 0) { if (wid < nA) na[wid] = s; else nt[wid - nA] = s; }
  if (wid < nA && lane == 1) {
    int b = wid >> 7, l = wid & 127;
    float w = weight[wid];
    lw2[wid] = (l < len[b]) ? log2f(fmaxf(w, 1e-12f)) : NEGL2;
  }
}

// ---------------------------------------------------------------- staging helper
__device__ inline void stage8(const float* __restrict__ src, bool rowvalid,
                              int kg, short* __restrict__ Hs, short* __restrict__ Ls,
                              int lofs) {
  float xv[8];
  if (rowvalid && kg + 8 <= ND) {
    float4 u = *(const float4*)(src + kg);
    float4 v = *(const float4*)(src + kg + 4);
    xv[0]=u.x; xv[1]=u.y; xv[2]=u.z; xv[3]=u.w;
    xv[4]=v.x; xv[5]=v.y; xv[6]=v.z; xv[7]=v.w;
  } else {
    #pragma unroll
    for (int e = 0; e < 8; ++e)
      xv[e] = (rowvalid && kg + e < ND) ? src[kg + e] : 0.f;
  }
  bf16x8 hv, lv;
  #pragma unroll
  for (int e = 0; e < 8; ++e) {
    unsigned short h = f2bf_rn(xv[e]);
    float hf = bf2f(h);
    unsigned short l = f2bf_rn(xv[e] - hf);
    hv[e] = (short)h; lv[e] = (short)l;
  }
  *(bf16x8*)(Hs + lofs) = hv;
  *(bf16x8*)(Ls + lofs) = lv;
}

// ---------------------------------------------------------------- cost MFMA (ab / tt)
__global__ __launch_bounds__(512)
void cost_mfma(const float* __restrict__ X, const float* __restrict__ Y,
               const float* __restrict__ NX, const float* __restrict__ NY,
               float* __restrict__ C, int nX, int nY, int mode) {
  __shared__ __align__(16) short Ah[128 * PIT], Al[128 * PIT];
  __shared__ __align__(16) short Bh[128 * PIT], Bl[128 * PIT];

  const int t = threadIdx.x;
  const int i0 = blockIdx.x * 128, j0 = blockIdx.y * 128;
  const int srow = t >> 2, skq = t & 3, kloc = skq * 8;
  const int lofs = srow * PIT + kloc;
  const bool avalid = (i0 + srow) < nX;
  const bool bvalid = (j0 + srow) < nY;
  const float* aro = X + (size_t)(i0 + srow) * ND;
  const float* bro = Y + (size_t)(j0 + srow) * ND;

  const int lane = t & 63, w = t >> 6;
  const int fr = lane & 15, fo = (lane >> 4) * 8;
  const int aofs = (w * 16 + fr) * PIT + fo;

  f32x4 acc[8];
  #pragma unroll
  for (int cc = 0; cc < 8; ++cc) acc[cc] = (f32x4){0.f, 0.f, 0.f, 0.f};

  for (int c = 0; c < KCH; ++c) {
    int kg = c * 32 + kloc;
    stage8(aro, avalid, kg, Ah, Al, lofs);
    stage8(bro, bvalid, kg, Bh, Bl, lofs);
    __syncthreads();

    bf16x8 ah = *(const bf16x8*)(Ah + aofs);
    bf16x8 al = *(const bf16x8*)(Al + aofs);
    #pragma unroll
    for (int cc = 0; cc < 8; ++cc) {
      int bofs = (cc * 16 + fr) * PIT + fo;
      bf16x8 bh = *(const bf16x8*)(Bh + bofs);
      bf16x8 bl = *(const bf16x8*)(Bl + bofs);
      acc[cc] = __builtin_amdgcn_mfma_f32_16x16x32_bf16(ah, bh, acc[cc], 0, 0, 0);
      acc[cc] = __builtin_amdgcn_mfma_f32_16x16x32_bf16(ah, bl, acc[cc], 0, 0, 0);
      acc[cc] = __builtin_amdgcn_mfma_f32_16x16x32_bf16(al, bh, acc[cc], 0, 0, 0);
    }
    __syncthreads();
  }

  #pragma unroll
  for (int cc = 0; cc < 8; ++cc) {
    int gj = j0 + cc * 16 + fr;
    if (gj >= nY) continue;
    float ny = NY[gj];
    #pragma unroll
    for (int reg = 0; reg < 4; ++reg) {
      int gi = i0 + w * 16 + (lane >> 4) * 4 + reg;
      if (gi >= nX) continue;
      float sq = NX[gi] + ny - 2.f * acc[cc][reg];
      float cv = fmaxf(sq, 0.f) * CSCALE;
      if (mode == 0) {
        int k = gj / 50, jj = gj - k * 50;
        C[((size_t)((gi >> 7) * NK + k)) * (NL * NR) + (gi & 127) * NR + jj] = cv;
      } else {
        int ki = gi / 50, ii = gi - ki * 50;
        int kj = gj / 50, jj = gj - kj * 50;
        C[((size_t)(ki * NK + kj)) * (NR * NR) + ii * NR + jj] = cv;
      }
    }
  }
}

// ---------------------------------------------------------------- cost MFMA (aa)
__global__ __launch_bounds__(512)
void cost_mfma_aa(const float* __restrict__ X, const float* __restrict__ NX,
                  float* __restrict__ C) {
  __shared__ __align__(16) short Ah[128 * PIT], Al[128 * PIT];

  const int t = threadIdx.x, b = blockIdx.x;
  const int srow = t >> 2, skq = t & 3, kloc = skq * 8;
  const int lofs = srow * PIT + kloc;
  const float* aro = X + (size_t)(b * NL + srow) * ND;

  const int lane = t & 63, w = t >> 6;
  const int fr = lane & 15, fo = (lane >> 4) * 8;
  const int aofs = (w * 16 + fr) * PIT + fo;

  f32x4 acc[8];
  #pragma unroll
  for (int cc = 0; cc < 8; ++cc) acc[cc] = (f32x4){0.f, 0.f, 0.f, 0.f};

  for (int c = 0; c < KCH; ++c) {
    stage8(aro, true, c * 32 + kloc, Ah, Al, lofs);
    __syncthreads();

    bf16x8 ah = *(const bf16x8*)(Ah + aofs);
    bf16x8 al = *(const bf16x8*)(Al + aofs);
    #pragma unroll
    for (int cc = 0; cc < 8; ++cc) {
      int bofs = (cc * 16 + fr) * PIT + fo;
      bf16x8 bh = *(const bf16x8*)(Ah + bofs);
      bf16x8 bl = *(const bf16x8*)(Al + bofs);
      acc[cc] = __builtin_amdgcn_mfma_f32_16x16x32_bf16(ah, bh, acc[cc], 0, 0, 0);
      acc[cc] = __builtin_amdgcn_mfma_f32_16x16x32_bf16(ah, bl, acc[cc], 0, 0, 0);
      acc[cc] = __builtin_amdgcn_mfma_f32_16x16x32_bf16(al, bh, acc[cc], 0, 0, 0);
    }
    __syncthreads();
  }

  const float* nb = NX + b * NL;
  float* Cb = C + (size_t)b * (NL * NL);
  #pragma unroll
  for (int cc = 0; cc < 8; ++cc) {
    int gj = cc * 16 + fr;
    float ny = nb[gj];
    #pragma unroll
    for (int reg = 0; reg < 4; ++reg) {
      int gi = w * 16 + (lane >> 4) * 4 + reg;
      float sq = nb[gi] + ny - 2.f * acc[cc][reg];
      Cb[(size_t)gi * NL + gj] = fmaxf(sq, 0.f) * CSCALE;
    }
  }
}

// ---------------------------------------------------------------- sinkhorn ab + tt (fused launch)
// blocks [0, NB*NK): ab problems (128x50). blocks [NB*NK, +NK*NK): tt (50x50).
__global__ __launch_bounds__(256)
void sinkhorn_abtt(const float* __restrict__ Cab, const float* __restrict__ Ctt,
                   const float* __restrict__ lw2, const float* __restrict__ weight,
                   float* __restrict__ oab, float* __restrict__ ott) {
  __shared__ float smem[6966];
  const int t = threadIdx.x;

  if (blockIdx.x < NB * NK) {
    // ------------------------------ ab body
    float* Cs    = smem;                 // 128*51 = 6528
    float* g2    = smem + 6528;          // 50
    float* f2    = smem + 6578;          // 128
    float* potf2 = smem + 6706;          // 128
    float* la2s  = smem + 6834;          // 128
    float* red   = smem + 6962;          // 4
    int p = blockIdx.x, b = p / NK;
    const float* Cp = Cab + (size_t)p * (NL * NR);
    for (int i = t; i < NL * NR; i += 256) {
      int r = i / NR, c = i - r * NR;
      Cs[r * 51 + c] = Cp[i];
    }
    if (t < NL) la2s[t] = lw2[b * NL + t];
    if (t < NR) g2[t] = 0.f;
    __syncthreads();

    const int rf = t >> 1, sf = t & 1;
    float Crowb[25];                     // -C - Bf
    {
      const float* rp = &Cs[rf * 51 + sf * 25];
      #pragma unroll
      for (int j = 0; j < 25; ++j) Crowb[j] = -rp[j];
    }
    float Bf = 0.f;
    const int cc = t >> 2, sc = t & 3;
    float Ccolb[32];                     // -C - Bg
    float Bg = 0.f;
    if (t < 200) {
      #pragma unroll
      for (int i = 0; i < 32; ++i) Ccolb[i] = -Cs[(sc * 32 + i) * 51 + cc];
    }

    const float* gbase = g2 + sf * 25;
    const float* fbase = potf2 + sc * 32;

    for (int it = 0; it < NITER; ++it) {
      // ---- f update: steady path = add, exp2, add per element
      {
        float s = 0.f;
        #pragma unroll
        for (int j = 0; j < 25; ++j) s += exp2f(gbase[j] + Crowb[j]);
        s += __shfl_xor(s, 1);
        if (!s_ok(s)) {                  // redo with fresh max, re-bias
          float mx = -3.0e38f;
          #pragma unroll
          for (int j = 0; j < 25; ++j) mx = fmaxf(mx, gbase[j] + Crowb[j]);
          mx = fmaxf(mx, __shfl_xor(mx, 1));
          float s2 = 0.f;
          #pragma unroll
          for (int j = 0; j < 25; ++j) s2 += exp2f(gbase[j] + Crowb[j] - mx);
          s2 += __shfl_xor(s2, 1);
          float dB = mx + log2f(s2);
          #pragma unroll
          for (int j = 0; j < 25; ++j) Crowb[j] -= dB;
          Bf += dB;
          if (sf == 0) { float fv = LOG2_50 - Bf; f2[rf] = fv; potf2[rf] = la2s[rf] + fv; }
        } else {
          if (sf == 0) {
            float fv = LOG2_50 - (Bf + log2f(s));
            f2[rf] = fv; potf2[rf] = la2s[rf] + fv;
          }
        }
      }
      __syncthreads();
      // ---- g update
      if (t < 200) {
        float s = 0.f;
        #pragma unroll
        for (int i = 0; i < 32; ++i) s += exp2f(fbase[i] + Ccolb[i]);
        s += __shfl_xor(s, 1);
        s += __shfl_xor(s, 2);
        if (!s_ok(s)) {
          float mx = -3.0e38f;
          #pragma unroll
          for (int i = 0; i < 32; ++i) mx = fmaxf(mx, fbase[i] + Ccolb[i]);
          mx = fmaxf(mx, __shfl_xor(mx, 1));
          mx = fmaxf(mx, __shfl_xor(mx, 2));
          float s2 = 0.f;
          #pragma unroll
          for (int i = 0; i < 32; ++i) s2 += exp2f(fbase[i] + Ccolb[i] - mx);
          s2 += __shfl_xor(s2, 1);
          s2 += __shfl_xor(s2, 2);
          float dB = mx + log2f(s2);
          #pragma unroll
          for (int i = 0; i < 32; ++i) Ccolb[i] -= dB;
          Bg += dB;
          if (sc == 0) g2[cc] = -Bg;
        } else {
          if (sc == 0) g2[cc] = -(Bg + log2f(s));
        }
      }
      __syncthreads();
    }

    float acc = 0.f;
    if (t < NL) acc = weight[b * NL + t] * f2[t];
    else if (t < NL + NR) acc = g2[t - NL] * (1.0f / NR);
    #pragma unroll
    for (int off = 32; off; off >>= 1) acc += __shfl_xor(acc, off);
    if ((t & 63) == 0) red[t >> 6] = acc;
    __syncthreads();
    if (t == 0) oab[p] = VSCALE * (red[0] + red[1] + red[2] + red[3]);

  } else {
    // ------------------------------ tt body (50x50, both uniform)
    float* Cs = smem;                    // 50*51 = 2550
    float* f2 = smem + 2550;             // 50
    float* g2 = smem + 2600;             // 50
    float* red = smem + 2650;            // 4
    int p = blockIdx.x - NB * NK;
    const float* Cp = Ctt + (size_t)p * (NR * NR);
    for (int i = t; i < NR * NR; i += 256) {
      int r = i / NR, c = i - r * NR;
      Cs[r * 51 + c] = Cp[i];
    }
    if (t < NR) g2[t] = 0.f;
    __syncthreads();

    int r = t >> 2, sub = t & 3;
    for (int it = 0; it < NITER; ++it) {
      if (r < NR) {
        const float* row = &Cs[r * 51];
        float mx = -INFINITY;
        for (int mm = sub; mm < NR; mm += 4) mx = fmaxf(mx, g2[mm] - row[mm]);
        mx = fmaxf(mx, __shfl_xor(mx, 1));
        mx = fmaxf(mx, __shfl_xor(mx, 2));
        float s = 0.f;
        for (int mm = sub; mm < NR; mm += 4) s += exp2f(g2[mm] - row[mm] - mx);
        s += __shfl_xor(s, 1);
        s += __shfl_xor(s, 2);
        if (sub == 0) f2[r] = LOG2_50 - mx - log2f(s);
      }
      __syncthreads();
      if (r < NR) {
        float mx = -INFINITY;
        for (int nn = sub; nn < NR; nn += 4) mx = fmaxf(mx, f2[nn] - Cs[nn * 51 + r]);
        mx = fmaxf(mx, __shfl_xor(mx, 1));
        mx = fmaxf(mx, __shfl_xor(mx, 2));
        float s = 0.f;
        for (int nn = sub; nn < NR; nn += 4) s += exp2f(f2[nn] - Cs[nn * 51 + r] - mx);
        s += __shfl_xor(s, 1);
        s += __shfl_xor(s, 2);
        if (sub == 0) g2[r] = LOG2_50 - mx - log2f(s);
      }
      __syncthreads();
    }

    float acc = 0.f;
    if (t < NR) acc = f2[t] + g2[t];
    #pragma unroll
    for (int off = 32; off; off >>= 1) acc += __shfl_xor(acc, off);
    if ((t & 63) == 0) red[t >> 6] = acc;
    __syncthreads();
    if (t == 0) ott[p] = VSCALE * (1.0f / NR) * (red[0] + red[1] + red[2] + red[3]);
  }
}

// ---------------------------------------------------------------- sinkhorn aa
// Symmetric C, equal marginals. Biased reg costs CrF/CrG (la2 - C - B),
// static even/odd bodies (no runtime reg-array indexing, rule #20).
__global__ __launch_bounds__(512)
void sinkhorn_aa(const float* __restrict__ Cg, const float* __restrict__ lw2,
                 const float* __restrict__ weight, float* __restrict__ ot) {
  __shared__ float pF[NL];
  __shared__ float pG[NL];
  __shared__ float red[8];
  int b = blockIdx.x, t = threadIdx.x;
  int r = t >> 2, sub = t & 3;
  const float* Cp = Cg + (size_t)b * (NL * NL) + (size_t)r * NL + sub * 32;
  const float* lp = lw2 + b * NL + sub * 32;
  float CrF[32], CrG[32];
  #pragma unroll
  for (int i = 0; i < 32; i += 4) {
    float4 cv = *(const float4*)(Cp + i);
    float4 lv = *(const float4*)(lp + i);
    CrF[i]     = lv.x - cv.x; CrF[i + 1] = lv.y - cv.y;
    CrF[i + 2] = lv.z - cv.z; CrF[i + 3] = lv.w - cv.w;
  }
  #pragma unroll
  for (int i = 0; i < 32; ++i) CrG[i] = CrF[i];
  float BF = 0.f, BG = 0.f;
  if (t < NL) pG[t] = 0.f;
  __syncthreads();

  const float* spG = pG + sub * 32;
  const float* spF = pF + sub * 32;

  for (int it = 0; it < NITER; ++it) {
    // ---- f = T(g): read pG, write pF, bias BF in CrF
    {
      float s = 0.f;
      #pragma unroll
      for (int i = 0; i < 32; ++i) s += exp2f(spG[i] + CrF[i]);
      s += __shfl_xor(s, 1);
      s += __shfl_xor(s, 2);
      if (!s_ok(s)) {
        float mx = -3.0e38f;
        #pragma unroll
        for (int i = 0; i < 32; ++i) mx = fmaxf(mx, spG[i] + CrF[i]);
        mx = fmaxf(mx, __shfl_xor(mx, 1));
        mx = fmaxf(mx, __shfl_xor(mx, 2));
        float s2 = 0.f;
        #pragma unroll
        for (int i = 0; i < 32; ++i) s2 += exp2f(spG[i] + CrF[i] - mx);
        s2 += __shfl_xor(s2, 1);
        s2 += __shfl_xor(s2, 2);
        float dB = mx + log2f(s2);
        #pragma unroll
        for (int i = 0; i < 32; ++i) CrF[i] -= dB;
        BF += dB;
        if (sub == 0) pF[r] = -BF;
      } else {
        if (sub == 0) pF[r] = -(BF + log2f(s));
      }
    }
    __syncthreads();
    // ---- g = T(f): read pF, write pG, bias BG in CrG
    {
      float s = 0.f;
      #pragma unroll
      for (int i = 0; i < 32; ++i) s += exp2f(spF[i] + CrG[i]);
      s += __shfl_xor(s, 1);
      s += __shfl_xor(s, 2);
      if (!s_ok(s)) {
        float mx = -3.0e38f;
        #pragma unroll
        for (int i = 0; i < 32; ++i) mx = fmaxf(mx, spF[i] + CrG[i]);
        mx = fmaxf(mx, __shfl_xor(mx, 1));
        mx = fmaxf(mx, __shfl_xor(mx, 2));
        float s2 = 0.f;
        #pragma unroll
        for (int i = 0; i < 32; ++i) s2 += exp2f(spF[i] + CrG[i] - mx);
        s2 += __shfl_xor(s2, 1);
        s2 += __shfl_xor(s2, 2);
        float dB = mx + log2f(s2);
        #pragma unroll
        for (int i = 0; i < 32; ++i) CrG[i] -= dB;
        BG += dB;
        if (sub == 0) pG[r] = -BG;
      } else {
        if (sub == 0) pG[r] = -(BG + log2f(s));
      }
    }
    __syncthreads();
  }

  float acc = 0.f;
  if (t < NL) acc = weight[b * NL + t] * (pF[t] + pG[t]);
  #pragma unroll
  for (int off = 32; off; off >>= 1) acc += __shfl_xor(acc, off);
  if ((t & 63) == 0) red[t >> 6] = acc;
  __syncthreads();
  if (t == 0) {
    float v = 0.f;
    #pragma unroll
    for (int i = 0; i < 8; ++i) v += red[i];
    ot[b] = VSCALE * v;
  }
}

// ---------------------------------------------------------------- finalize
__global__ void finalize_kernel(const float* __restrict__ oab, const float* __restrict__ oaa,
                                const float* __restrict__ ott, const int* __restrict__ grade,
                                float* __restrict__ out) {
  __shared__ float selft[NK];
  __shared__ float redL[4], redD[4];
  int t = threadIdx.x;
  if (t < NK) selft[t] = ott[t * NK + t];
  __syncthreads();
  float dpart = (t < NK * NK) ? ott[t] : 0.f;
  float lpart = 0.f;
  if (t < NB) {
    int g = grade[t];
    float oa = oaa[t];
    float dpos = oab[t * NK + g] - 0.5f * (oa + selft[g]);
    float s = 0.f;
    #pragma unroll
    for (int k = 0; k < NK; ++k) {
      float dk = oab[t * NK + k] - 0.5f * (oa + selft[k]);
      s += fmaxf(dpos - dk + 10.0f, 0.0f);
    }
    lpart = s - 10.0f;
  }
  #pragma unroll
  for (int off = 32; off; off >>= 1) {
    dpart += __shfl_xor(dpart, off);
    lpart += __shfl_xor(lpart, off);
  }
  if ((t & 63) == 0) { redD[t >> 6] = dpart; redL[t >> 6] = lpart; }
  __syncthreads();
  if (t == 0) {
    float ds = 0.f, ls = 0.f;
    #pragma unroll
    for (int i = 0; i < 4; ++i) { ds += redD[i]; ls += redL[i]; }
    float ss = 0.f;
    #pragma unroll
    for (int k = 0; k < NK; ++k) ss += selft[k];
    float dis = ds - (float)NK * ss;
    out[0] = ls / (float)NB - dis * 0.01f;
  }
}

// ---------------------------------------------------------------- launch
extern "C" void kernel_launch(void* const* d_in, const int* in_sizes, int n_in,
                              void* d_out, int out_size, void* d_ws, size_t ws_size,
                              hipStream_t stream) {
  (void)in_sizes; (void)n_in; (void)out_size; (void)ws_size;
  const float* anchor = (const float*)d_in[0];
  const float* weight = (const float*)d_in[1];
  const float* t0     = (const float*)d_in[2];
  const int*   len    = (const int*)d_in[3];
  const int*   grade  = (const int*)d_in[4];
  float* out = (float*)d_out;

  float* ws  = (float*)d_ws;
  float* Cab = ws;                                    // 819200
  float* Caa = Cab + (size_t)NB * NK * NL * NR;       // 2097152
  float* Ctt = Caa + (size_t)NB * NL * NL;            // 250000
  float* na  = Ctt + (size_t)NK * NK * NR * NR;       // 16384
  float* nt  = na + NB * NL;                          // 500
  float* lw2 = nt + NK * NR;                          // 16384
  float* oab = lw2 + NB * NL;                         // 1280
  float* oaa = oab + NB * NK;                         // 128
  float* ott = oaa + NB;                              // 100

  prep_kernel<<<(NB * NL + NK * NR) / 4, 256, 0, stream>>>(anchor, weight, t0, len, na, nt, lw2);
  cost_mfma<<<dim3(128, 4), 512, 0, stream>>>(anchor, t0, na, nt, Cab,
                                              NB * NL, NK * NR, 0);
  cost_mfma<<<dim3(4, 4), 512, 0, stream>>>(t0, t0, nt, nt, Ctt,
                                            NK * NR, NK * NR, 2);
  cost_mfma_aa<<<NB, 512, 0, stream>>>(anchor, na, Caa);

  sinkhorn_abtt<<<NB * NK + NK * NK, 256, 0, stream>>>(Cab, Ctt, lw2, weight, oab, ott);
  sinkhorn_aa<<<NB, 512, 0, stream>>>(Caa, lw2, weight, oaa);
  finalize_kernel<<<1, 256, 0, stream>>>(oab, oaa, ott, grade, out);
}

// Round 9
// 249.906 us; speedup vs baseline: 12.1791x; 1.1759x over previous
//
#include <hip/hip_runtime.h>
#include <math.h>

// Sinkhorn-divergence triplet loss (geomloss-style), MI355X.
// R9: (a) native v_exp_f32 / v_log_f32 (__builtin_amdgcn_exp2f / _logf) in all
// Sinkhorn hot loops -- OCML exp2f/log2f libcalls were ~3x the native cost
// (R7: 54cy/elem @ 96% VALUBusy vs ~14cy floor). (b) folded defer-max with mx
// tracked IN the steady pass: guard mx in (-80,30], redo = rebias+re-exp only
// (R8's sum-guard redid a full max pass most iterations -> regression).
// Cost matrices via MFMA (R7, split-bf16 3-MFMA). Launch-bounds law: never
// pass arg2 (VGPR cap = 256/arg2, measured R3/R4).

namespace {
constexpr int NB = 128, NL = 128, ND = 300, NK = 10, NR = 50, NITER = 20;
constexpr float LOG2E   = 1.4426950408889634f;
constexpr float EPS     = 0.0025f;                  // blur^p = 0.05^2
constexpr float CSCALE  = 0.5f * LOG2E / EPS;       // squared-dist -> log2-domain cost
constexpr float VSCALE  = EPS * 0.6931471805599453f; // log2-potential -> nat (eps*ln2)
constexpr float LOG2_50 = 5.6438561897747395f;      // log2(50)
constexpr float NEGL2   = -1.442695e9f;             // -1e9 * log2e
constexpr float MX_HI   = 30.f, MX_LO = -80.f;      // bias window (exact: see R9 notes)
constexpr int KCH = 10;                              // K chunks of 32
constexpr int PIT = 40;                              // LDS pitch in shorts
}

typedef __attribute__((ext_vector_type(8))) short bf16x8;
typedef __attribute__((ext_vector_type(4))) float f32x4;

__device__ inline float ex2(float x) { return __builtin_amdgcn_exp2f(x); }
__device__ inline float lg2(float x) { return __builtin_amdgcn_logf(x); }

__device__ inline unsigned short f2bf_rn(float x) {
  unsigned int u = __float_as_uint(x);
  unsigned int r = (u + 0x7fffu + ((u >> 16) & 1u)) >> 16;
  return (unsigned short)r;
}
__device__ inline float bf2f(unsigned short h) {
  return __uint_as_float((unsigned int)h << 16);
}

// ---------------------------------------------------------------- prep
__global__ void prep_kernel(const float* __restrict__ anchor,
                            const float* __restrict__ weight,
                            const float* __restrict__ t0,
                            const int* __restrict__ len,
                            float* __restrict__ na, float* __restrict__ nt,
                            float* __restrict__ lw2) {
  int wid  = (blockIdx.x * blockDim.x + threadIdx.x) >> 6;
  int lane = threadIdx.x & 63;
  const int nA = NB * NL;
  const int total = nA + NK * NR;
  if (wid >= total) return;
  const float* src = (wid < nA) ? (anchor + (size_t)wid * ND)
                                : (t0 + (size_t)(wid - nA) * ND);
  float s = 0.f;
  for (int d = lane; d < ND; d += 64) { float v = src[d]; s += v * v; }
  #pragma unroll
  for (int off = 32; off; off >>= 1) s += __shfl_xor(s, off);
  if (lane == 0) { if (wid < nA) na[wid] = s; else nt[wid - nA] = s; }
  if (wid < nA && lane == 1) {
    int b = wid >> 7, l = wid & 127;
    float w = weight[wid];
    lw2[wid] = (l < len[b]) ? log2f(fmaxf(w, 1e-12f)) : NEGL2;
  }
}

// ---------------------------------------------------------------- staging helper
__device__ inline void stage8(const float* __restrict__ src, bool rowvalid,
                              int kg, short* __restrict__ Hs, short* __restrict__ Ls,
                              int lofs) {
  float xv[8];
  if (rowvalid && kg + 8 <= ND) {
    float4 u = *(const float4*)(src + kg);
    float4 v = *(const float4*)(src + kg + 4);
    xv[0]=u.x; xv[1]=u.y; xv[2]=u.z; xv[3]=u.w;
    xv[4]=v.x; xv[5]=v.y; xv[6]=v.z; xv[7]=v.w;
  } else {
    #pragma unroll
    for (int e = 0; e < 8; ++e)
      xv[e] = (rowvalid && kg + e < ND) ? src[kg + e] : 0.f;
  }
  bf16x8 hv, lv;
  #pragma unroll
  for (int e = 0; e < 8; ++e) {
    unsigned short h = f2bf_rn(xv[e]);
    float hf = bf2f(h);
    unsigned short l = f2bf_rn(xv[e] - hf);
    hv[e] = (short)h; lv[e] = (short)l;
  }
  *(bf16x8*)(Hs + lofs) = hv;
  *(bf16x8*)(Ls + lofs) = lv;
}

// ---------------------------------------------------------------- cost MFMA (ab / tt)
__global__ __launch_bounds__(512)
void cost_mfma(const float* __restrict__ X, const float* __restrict__ Y,
               const float* __restrict__ NX, const float* __restrict__ NY,
               float* __restrict__ C, int nX, int nY, int mode) {
  __shared__ __align__(16) short Ah[128 * PIT], Al[128 * PIT];
  __shared__ __align__(16) short Bh[128 * PIT], Bl[128 * PIT];

  const int t = threadIdx.x;
  const int i0 = blockIdx.x * 128, j0 = blockIdx.y * 128;
  const int srow = t >> 2, skq = t & 3, kloc = skq * 8;
  const int lofs = srow * PIT + kloc;
  const bool avalid = (i0 + srow) < nX;
  const bool bvalid = (j0 + srow) < nY;
  const float* aro = X + (size_t)(i0 + srow) * ND;
  const float* bro = Y + (size_t)(j0 + srow) * ND;

  const int lane = t & 63, w = t >> 6;
  const int fr = lane & 15, fo = (lane >> 4) * 8;
  const int aofs = (w * 16 + fr) * PIT + fo;

  f32x4 acc[8];
  #pragma unroll
  for (int cc = 0; cc < 8; ++cc) acc[cc] = (f32x4){0.f, 0.f, 0.f, 0.f};

  for (int c = 0; c < KCH; ++c) {
    int kg = c * 32 + kloc;
    stage8(aro, avalid, kg, Ah, Al, lofs);
    stage8(bro, bvalid, kg, Bh, Bl, lofs);
    __syncthreads();

    bf16x8 ah = *(const bf16x8*)(Ah + aofs);
    bf16x8 al = *(const bf16x8*)(Al + aofs);
    #pragma unroll
    for (int cc = 0; cc < 8; ++cc) {
      int bofs = (cc * 16 + fr) * PIT + fo;
      bf16x8 bh = *(const bf16x8*)(Bh + bofs);
      bf16x8 bl = *(const bf16x8*)(Bl + bofs);
      acc[cc] = __builtin_amdgcn_mfma_f32_16x16x32_bf16(ah, bh, acc[cc], 0, 0, 0);
      acc[cc] = __builtin_amdgcn_mfma_f32_16x16x32_bf16(ah, bl, acc[cc], 0, 0, 0);
      acc[cc] = __builtin_amdgcn_mfma_f32_16x16x32_bf16(al, bh, acc[cc], 0, 0, 0);
    }
    __syncthreads();
  }

  #pragma unroll
  for (int cc = 0; cc < 8; ++cc) {
    int gj = j0 + cc * 16 + fr;
    if (gj >= nY) continue;
    float ny = NY[gj];
    #pragma unroll
    for (int reg = 0; reg < 4; ++reg) {
      int gi = i0 + w * 16 + (lane >> 4) * 4 + reg;
      if (gi >= nX) continue;
      float sq = NX[gi] + ny - 2.f * acc[cc][reg];
      float cv = fmaxf(sq, 0.f) * CSCALE;
      if (mode == 0) {
        int k = gj / 50, jj = gj - k * 50;
        C[((size_t)((gi >> 7) * NK + k)) * (NL * NR) + (gi & 127) * NR + jj] = cv;
      } else {
        int ki = gi / 50, ii = gi - ki * 50;
        int kj = gj / 50, jj = gj - kj * 50;
        C[((size_t)(ki * NK + kj)) * (NR * NR) + ii * NR + jj] = cv;
      }
    }
  }
}

// ---------------------------------------------------------------- cost MFMA (aa)
__global__ __launch_bounds__(512)
void cost_mfma_aa(const float* __restrict__ X, const float* __restrict__ NX,
                  float* __restrict__ C) {
  __shared__ __align__(16) short Ah[128 * PIT], Al[128 * PIT];

  const int t = threadIdx.x, b = blockIdx.x;
  const int srow = t >> 2, skq = t & 3, kloc = skq * 8;
  const int lofs = srow * PIT + kloc;
  const float* aro = X + (size_t)(b * NL + srow) * ND;

  const int lane = t & 63, w = t >> 6;
  const int fr = lane & 15, fo = (lane >> 4) * 8;
  const int aofs = (w * 16 + fr) * PIT + fo;

  f32x4 acc[8];
  #pragma unroll
  for (int cc = 0; cc < 8; ++cc) acc[cc] = (f32x4){0.f, 0.f, 0.f, 0.f};

  for (int c = 0; c < KCH; ++c) {
    stage8(aro, true, c * 32 + kloc, Ah, Al, lofs);
    __syncthreads();

    bf16x8 ah = *(const bf16x8*)(Ah + aofs);
    bf16x8 al = *(const bf16x8*)(Al + aofs);
    #pragma unroll
    for (int cc = 0; cc < 8; ++cc) {
      int bofs = (cc * 16 + fr) * PIT + fo;
      bf16x8 bh = *(const bf16x8*)(Ah + bofs);
      bf16x8 bl = *(const bf16x8*)(Al + bofs);
      acc[cc] = __builtin_amdgcn_mfma_f32_16x16x32_bf16(ah, bh, acc[cc], 0, 0, 0);
      acc[cc] = __builtin_amdgcn_mfma_f32_16x16x32_bf16(ah, bl, acc[cc], 0, 0, 0);
      acc[cc] = __builtin_amdgcn_mfma_f32_16x16x32_bf16(al, bh, acc[cc], 0, 0, 0);
    }
    __syncthreads();
  }

  const float* nb = NX + b * NL;
  float* Cb = C + (size_t)b * (NL * NL);
  #pragma unroll
  for (int cc = 0; cc < 8; ++cc) {
    int gj = cc * 16 + fr;
    float ny = nb[gj];
    #pragma unroll
    for (int reg = 0; reg < 4; ++reg) {
      int gi = w * 16 + (lane >> 4) * 4 + reg;
      float sq = nb[gi] + ny - 2.f * acc[cc][reg];
      Cb[(size_t)gi * NL + gj] = fmaxf(sq, 0.f) * CSCALE;
    }
  }
}

// ---------------------------------------------------------------- sinkhorn ab + tt (fused launch)
__global__ __launch_bounds__(256)
void sinkhorn_abtt(const float* __restrict__ Cab, const float* __restrict__ Ctt,
                   const float* __restrict__ lw2, const float* __restrict__ weight,
                   float* __restrict__ oab, float* __restrict__ ott) {
  __shared__ float smem[6966];
  const int t = threadIdx.x;

  if (blockIdx.x < NB * NK) {
    // ------------------------------ ab body (128x50)
    float* Cs    = smem;                 // 128*51
    float* g2    = smem + 6528;          // 50
    float* f2    = smem + 6578;          // 128
    float* potf2 = smem + 6706;          // 128
    float* la2s  = smem + 6834;          // 128
    float* red   = smem + 6962;          // 4
    int p = blockIdx.x, b = p / NK;
    const float* Cp = Cab + (size_t)p * (NL * NR);
    for (int i = t; i < NL * NR; i += 256) {
      int r = i / NR, c = i - r * NR;
      Cs[r * 51 + c] = Cp[i];
    }
    if (t < NL) la2s[t] = lw2[b * NL + t];
    if (t < NR) g2[t] = 0.f;
    __syncthreads();

    const int rf = t >> 1, sf = t & 1;
    float Crowb[25];                     // -C - Bf (bias folded)
    {
      const float* rp = &Cs[rf * 51 + sf * 25];
      #pragma unroll
      for (int j = 0; j < 25; ++j) Crowb[j] = -rp[j];
    }
    float Bf = 0.f;
    const int cc = t >> 2, sc = t & 3;
    float Ccolb[32];                     // -C - Bg
    float Bg = 0.f;
    if (t < 200) {
      #pragma unroll
      for (int i = 0; i < 32; ++i) Ccolb[i] = -Cs[(sc * 32 + i) * 51 + cc];
    }

    const float* gbase = g2 + sf * 25;
    const float* fbase = potf2 + sc * 32;

    for (int it = 0; it < NITER; ++it) {
      // ---- f update: steady = {add, fmax, exp2, add}; redo = rebias + re-exp
      {
        float s = 0.f, mx = -3.0e38f;
        #pragma unroll
        for (int j = 0; j < 25; ++j) {
          float x = gbase[j] + Crowb[j];
          mx = fmaxf(mx, x);
          s += ex2(x);
        }
        mx = fmaxf(mx, __shfl_xor(mx, 1));
        s += __shfl_xor(s, 1);
        if (mx > MX_HI || mx < MX_LO) {  // wave-uniform within pair
          s = 0.f;
          #pragma unroll
          for (int j = 0; j < 25; ++j) {
            Crowb[j] -= mx;
            s += ex2(gbase[j] + Crowb[j]);
          }
          s += __shfl_xor(s, 1);
          Bf += mx;
        }
        if (sf == 0) {
          float fv = LOG2_50 - (Bf + lg2(s));
          f2[rf] = fv; potf2[rf] = la2s[rf] + fv;
        }
      }
      __syncthreads();
      // ---- g update
      if (t < 200) {
        float s = 0.f, mx = -3.0e38f;
        #pragma unroll
        for (int i = 0; i < 32; ++i) {
          float x = fbase[i] + Ccolb[i];
          mx = fmaxf(mx, x);
          s += ex2(x);
        }
        mx = fmaxf(mx, __shfl_xor(mx, 1));
        mx = fmaxf(mx, __shfl_xor(mx, 2));
        s += __shfl_xor(s, 1);
        s += __shfl_xor(s, 2);
        if (mx > MX_HI || mx < MX_LO) {
          s = 0.f;
          #pragma unroll
          for (int i = 0; i < 32; ++i) {
            Ccolb[i] -= mx;
            s += ex2(fbase[i] + Ccolb[i]);
          }
          s += __shfl_xor(s, 1);
          s += __shfl_xor(s, 2);
          Bg += mx;
        }
        if (sc == 0) g2[cc] = -(Bg + lg2(s));
      }
      __syncthreads();
    }

    float acc = 0.f;
    if (t < NL) acc = weight[b * NL + t] * f2[t];
    else if (t < NL + NR) acc = g2[t - NL] * (1.0f / NR);
    #pragma unroll
    for (int off = 32; off; off >>= 1) acc += __shfl_xor(acc, off);
    if ((t & 63) == 0) red[t >> 6] = acc;
    __syncthreads();
    if (t == 0) oab[p] = VSCALE * (red[0] + red[1] + red[2] + red[3]);

  } else {
    // ------------------------------ tt body (50x50, both uniform)
    float* Cs = smem;
    float* f2 = smem + 2550;
    float* g2 = smem + 2600;
    float* red = smem + 2650;
    int p = blockIdx.x - NB * NK;
    const float* Cp = Ctt + (size_t)p * (NR * NR);
    for (int i = t; i < NR * NR; i += 256) {
      int r = i / NR, c = i - r * NR;
      Cs[r * 51 + c] = Cp[i];
    }
    if (t < NR) g2[t] = 0.f;
    __syncthreads();

    int r = t >> 2, sub = t & 3;
    for (int it = 0; it < NITER; ++it) {
      if (r < NR) {
        const float* row = &Cs[r * 51];
        float mx = -INFINITY;
        for (int mm = sub; mm < NR; mm += 4) mx = fmaxf(mx, g2[mm] - row[mm]);
        mx = fmaxf(mx, __shfl_xor(mx, 1));
        mx = fmaxf(mx, __shfl_xor(mx, 2));
        float s = 0.f;
        for (int mm = sub; mm < NR; mm += 4) s += ex2(g2[mm] - row[mm] - mx);
        s += __shfl_xor(s, 1);
        s += __shfl_xor(s, 2);
        if (sub == 0) f2[r] = LOG2_50 - mx - lg2(s);
      }
      __syncthreads();
      if (r < NR) {
        float mx = -INFINITY;
        for (int nn = sub; nn < NR; nn += 4) mx = fmaxf(mx, f2[nn] - Cs[nn * 51 + r]);
        mx = fmaxf(mx, __shfl_xor(mx, 1));
        mx = fmaxf(mx, __shfl_xor(mx, 2));
        float s = 0.f;
        for (int nn = sub; nn < NR; nn += 4) s += ex2(f2[nn] - Cs[nn * 51 + r] - mx);
        s += __shfl_xor(s, 1);
        s += __shfl_xor(s, 2);
        if (sub == 0) g2[r] = LOG2_50 - mx - lg2(s);
      }
      __syncthreads();
    }

    float acc = 0.f;
    if (t < NR) acc = f2[t] + g2[t];
    #pragma unroll
    for (int off = 32; off; off >>= 1) acc += __shfl_xor(acc, off);
    if ((t & 63) == 0) red[t >> 6] = acc;
    __syncthreads();
    if (t == 0) ott[p] = VSCALE * (1.0f / NR) * (red[0] + red[1] + red[2] + red[3]);
  }
}

// ---------------------------------------------------------------- sinkhorn aa
// Symmetric C, equal marginals. Folded biases BF/BG in CrF/CrG; mx tracked in
// steady pass -> redo is rebias + re-exp only. Static even/odd bodies.
__global__ __launch_bounds__(512)
void sinkhorn_aa(const float* __restrict__ Cg, const float* __restrict__ lw2,
                 const float* __restrict__ weight, float* __restrict__ ot) {
  __shared__ float pF[NL];
  __shared__ float pG[NL];
  __shared__ float red[8];
  int b = blockIdx.x, t = threadIdx.x;
  int r = t >> 2, sub = t & 3;
  const float* Cp = Cg + (size_t)b * (NL * NL) + (size_t)r * NL + sub * 32;
  const float* lp = lw2 + b * NL + sub * 32;
  float CrF[32], CrG[32];
  #pragma unroll
  for (int i = 0; i < 32; i += 4) {
    float4 cv = *(const float4*)(Cp + i);
    float4 lv = *(const float4*)(lp + i);
    CrF[i]     = lv.x - cv.x; CrF[i + 1] = lv.y - cv.y;
    CrF[i + 2] = lv.z - cv.z; CrF[i + 3] = lv.w - cv.w;
  }
  #pragma unroll
  for (int i = 0; i < 32; ++i) CrG[i] = CrF[i];
  float BF = 0.f, BG = 0.f;
  if (t < NL) pG[t] = 0.f;
  __syncthreads();

  const float* spG = pG + sub * 32;
  const float* spF = pF + sub * 32;

  for (int it = 0; it < NITER; ++it) {
    // ---- f = T(g)
    {
      float s = 0.f, mx = -3.0e38f;
      #pragma unroll
      for (int i = 0; i < 32; ++i) {
        float x = spG[i] + CrF[i];
        mx = fmaxf(mx, x);
        s += ex2(x);
      }
      mx = fmaxf(mx, __shfl_xor(mx, 1));
      mx = fmaxf(mx, __shfl_xor(mx, 2));
      s += __shfl_xor(s, 1);
      s += __shfl_xor(s, 2);
      if (mx > MX_HI || mx < MX_LO) {
        s = 0.f;
        #pragma unroll
        for (int i = 0; i < 32; ++i) {
          CrF[i] -= mx;
          s += ex2(spG[i] + CrF[i]);
        }
        s += __shfl_xor(s, 1);
        s += __shfl_xor(s, 2);
        BF += mx;
      }
      if (sub == 0) pF[r] = -(BF + lg2(s));
    }
    __syncthreads();
    // ---- g = T(f)
    {
      float s = 0.f, mx = -3.0e38f;
      #pragma unroll
      for (int i = 0; i < 32; ++i) {
        float x = spF[i] + CrG[i];
        mx = fmaxf(mx, x);
        s += ex2(x);
      }
      mx = fmaxf(mx, __shfl_xor(mx, 1));
      mx = fmaxf(mx, __shfl_xor(mx, 2));
      s += __shfl_xor(s, 1);
      s += __shfl_xor(s, 2);
      if (mx > MX_HI || mx < MX_LO) {
        s = 0.f;
        #pragma unroll
        for (int i = 0; i < 32; ++i) {
          CrG[i] -= mx;
          s += ex2(spF[i] + CrG[i]);
        }
        s += __shfl_xor(s, 1);
        s += __shfl_xor(s, 2);
        BG += mx;
      }
      if (sub == 0) pG[r] = -(BG + lg2(s));
    }
    __syncthreads();
  }

  float acc = 0.f;
  if (t < NL) acc = weight[b * NL + t] * (pF[t] + pG[t]);
  #pragma unroll
  for (int off = 32; off; off >>= 1) acc += __shfl_xor(acc, off);
  if ((t & 63) == 0) red[t >> 6] = acc;
  __syncthreads();
  if (t == 0) {
    float v = 0.f;
    #pragma unroll
    for (int i = 0; i < 8; ++i) v += red[i];
    ot[b] = VSCALE * v;
  }
}

// ---------------------------------------------------------------- finalize
__global__ void finalize_kernel(const float* __restrict__ oab, const float* __restrict__ oaa,
                                const float* __restrict__ ott, const int* __restrict__ grade,
                                float* __restrict__ out) {
  __shared__ float selft[NK];
  __shared__ float redL[4], redD[4];
  int t = threadIdx.x;
  if (t < NK) selft[t] = ott[t * NK + t];
  __syncthreads();
  float dpart = (t < NK * NK) ? ott[t] : 0.f;
  float lpart = 0.f;
  if (t < NB) {
    int g = grade[t];
    float oa = oaa[t];
    float dpos = oab[t * NK + g] - 0.5f * (oa + selft[g]);
    float s = 0.f;
    #pragma unroll
    for (int k = 0; k < NK; ++k) {
      float dk = oab[t * NK + k] - 0.5f * (oa + selft[k]);
      s += fmaxf(dpos - dk + 10.0f, 0.0f);
    }
    lpart = s - 10.0f;
  }
  #pragma unroll
  for (int off = 32; off; off >>= 1) {
    dpart += __shfl_xor(dpart, off);
    lpart += __shfl_xor(lpart, off);
  }
  if ((t & 63) == 0) { redD[t >> 6] = dpart; redL[t >> 6] = lpart; }
  __syncthreads();
  if (t == 0) {
    float ds = 0.f, ls = 0.f;
    #pragma unroll
    for (int i = 0; i < 4; ++i) { ds += redD[i]; ls += redL[i]; }
    float ss = 0.f;
    #pragma unroll
    for (int k = 0; k < NK; ++k) ss += selft[k];
    float dis = ds - (float)NK * ss;
    out[0] = ls / (float)NB - dis * 0.01f;
  }
}

// ---------------------------------------------------------------- launch
extern "C" void kernel_launch(void* const* d_in, const int* in_sizes, int n_in,
                              void* d_out, int out_size, void* d_ws, size_t ws_size,
                              hipStream_t stream) {
  (void)in_sizes; (void)n_in; (void)out_size; (void)ws_size;
  const float* anchor = (const float*)d_in[0];
  const float* weight = (const float*)d_in[1];
  const float* t0     = (const float*)d_in[2];
  const int*   len    = (const int*)d_in[3];
  const int*   grade  = (const int*)d_in[4];
  float* out = (float*)d_out;

  float* ws  = (float*)d_ws;
  float* Cab = ws;                                    // 819200
  float* Caa = Cab + (size_t)NB * NK * NL * NR;       // 2097152
  float* Ctt = Caa + (size_t)NB * NL * NL;            // 250000
  float* na  = Ctt + (size_t)NK * NK * NR * NR;       // 16384
  float* nt  = na + NB * NL;                          // 500
  float* lw2 = nt + NK * NR;                          // 16384
  float* oab = lw2 + NB * NL;                         // 1280
  float* oaa = oab + NB * NK;                         // 128
  float* ott = oaa + NB;                              // 100

  prep_kernel<<<(NB * NL + NK * NR) / 4, 256, 0, stream>>>(anchor, weight, t0, len, na, nt, lw2);
  cost_mfma<<<dim3(128, 4), 512, 0, stream>>>(anchor, t0, na, nt, Cab,
                                              NB * NL, NK * NR, 0);
  cost_mfma<<<dim3(4, 4), 512, 0, stream>>>(t0, t0, nt, nt, Ctt,
                                            NK * NR, NK * NR, 2);
  cost_mfma_aa<<<NB, 512, 0, stream>>>(anchor, na, Caa);

  sinkhorn_abtt<<<NB * NK + NK * NK, 256, 0, stream>>>(Cab, Ctt, lw2, weight, oab, ott);
  sinkhorn_aa<<<NB, 512, 0, stream>>>(Caa, lw2, weight, oaa);
  finalize_kernel<<<1, 256, 0, stream>>>(oab, oaa, ott, grade, out);
}

// Round 10
// 203.490 us; speedup vs baseline: 14.9571x; 1.2281x over previous
//
#include <hip/hip_runtime.h>
#include <math.h>

// Sinkhorn-divergence triplet loss (geomloss-style), MI355X.
// R10: (a) dropped the 26KB LDS C-stage in sinkhorn_abtt -- C row/col fragments
// load straight from global (one-time, L2-hot); smem falls to ~2.4KB so
// occupancy goes LDS-bound(2 blk/CU) -> VGPR-bound(~5 blk/CU). (b) 4-way
// partial sums/maxes break the serial s+=exp2 dependency chains that pinned
// VALUBusy at 48% (R9: 2 waves/SIMD x 4cy dep = 50% issue). tt body also
// reg-resident (13 elem/thread, sentinel pad). aa gets the same ILP fix.
// Cost matrices via MFMA (R7, split-bf16 3-MFMA). Native v_exp/v_log (R9).
// Launch-bounds law: never pass arg2 (VGPR cap = 256/arg2, measured R3/R4).

namespace {
constexpr int NB = 128, NL = 128, ND = 300, NK = 10, NR = 50, NITER = 20;
constexpr float LOG2E   = 1.4426950408889634f;
constexpr float EPS     = 0.0025f;                  // blur^p = 0.05^2
constexpr float CSCALE  = 0.5f * LOG2E / EPS;       // squared-dist -> log2-domain cost
constexpr float VSCALE  = EPS * 0.6931471805599453f; // log2-potential -> nat (eps*ln2)
constexpr float LOG2_50 = 5.6438561897747395f;      // log2(50)
constexpr float NEGL2   = -1.442695e9f;             // -1e9 * log2e
constexpr float MX_HI   = 30.f, MX_LO = -80.f;      // bias window
constexpr int KCH = 10;                              // K chunks of 32
constexpr int PIT = 40;                              // LDS pitch in shorts
}

typedef __attribute__((ext_vector_type(8))) short bf16x8;
typedef __attribute__((ext_vector_type(4))) float f32x4;

__device__ inline float ex2(float x) { return __builtin_amdgcn_exp2f(x); }
__device__ inline float lg2(float x) { return __builtin_amdgcn_logf(x); }

__device__ inline unsigned short f2bf_rn(float x) {
  unsigned int u = __float_as_uint(x);
  unsigned int r = (u + 0x7fffu + ((u >> 16) & 1u)) >> 16;
  return (unsigned short)r;
}
__device__ inline float bf2f(unsigned short h) {
  return __uint_as_float((unsigned int)h << 16);
}

// ---------------------------------------------------------------- prep
__global__ void prep_kernel(const float* __restrict__ anchor,
                            const float* __restrict__ weight,
                            const float* __restrict__ t0,
                            const int* __restrict__ len,
                            float* __restrict__ na, float* __restrict__ nt,
                            float* __restrict__ lw2) {
  int wid  = (blockIdx.x * blockDim.x + threadIdx.x) >> 6;
  int lane = threadIdx.x & 63;
  const int nA = NB * NL;
  const int total = nA + NK * NR;
  if (wid >= total) return;
  const float* src = (wid < nA) ? (anchor + (size_t)wid * ND)
                                : (t0 + (size_t)(wid - nA) * ND);
  float s = 0.f;
  for (int d = lane; d < ND; d += 64) { float v = src[d]; s += v * v; }
  #pragma unroll
  for (int off = 32; off; off >>= 1) s += __shfl_xor(s, off);
  if (lane == 0) { if (wid < nA) na[wid] = s; else nt[wid - nA] = s; }
  if (wid < nA && lane == 1) {
    int b = wid >> 7, l = wid & 127;
    float w = weight[wid];
    lw2[wid] = (l < len[b]) ? log2f(fmaxf(w, 1e-12f)) : NEGL2;
  }
}

// ---------------------------------------------------------------- staging helper
__device__ inline void stage8(const float* __restrict__ src, bool rowvalid,
                              int kg, short* __restrict__ Hs, short* __restrict__ Ls,
                              int lofs) {
  float xv[8];
  if (rowvalid && kg + 8 <= ND) {
    float4 u = *(const float4*)(src + kg);
    float4 v = *(const float4*)(src + kg + 4);
    xv[0]=u.x; xv[1]=u.y; xv[2]=u.z; xv[3]=u.w;
    xv[4]=v.x; xv[5]=v.y; xv[6]=v.z; xv[7]=v.w;
  } else {
    #pragma unroll
    for (int e = 0; e < 8; ++e)
      xv[e] = (rowvalid && kg + e < ND) ? src[kg + e] : 0.f;
  }
  bf16x8 hv, lv;
  #pragma unroll
  for (int e = 0; e < 8; ++e) {
    unsigned short h = f2bf_rn(xv[e]);
    float hf = bf2f(h);
    unsigned short l = f2bf_rn(xv[e] - hf);
    hv[e] = (short)h; lv[e] = (short)l;
  }
  *(bf16x8*)(Hs + lofs) = hv;
  *(bf16x8*)(Ls + lofs) = lv;
}

// ---------------------------------------------------------------- cost MFMA (ab / tt)
__global__ __launch_bounds__(512)
void cost_mfma(const float* __restrict__ X, const float* __restrict__ Y,
               const float* __restrict__ NX, const float* __restrict__ NY,
               float* __restrict__ C, int nX, int nY, int mode) {
  __shared__ __align__(16) short Ah[128 * PIT], Al[128 * PIT];
  __shared__ __align__(16) short Bh[128 * PIT], Bl[128 * PIT];

  const int t = threadIdx.x;
  const int i0 = blockIdx.x * 128, j0 = blockIdx.y * 128;
  const int srow = t >> 2, skq = t & 3, kloc = skq * 8;
  const int lofs = srow * PIT + kloc;
  const bool avalid = (i0 + srow) < nX;
  const bool bvalid = (j0 + srow) < nY;
  const float* aro = X + (size_t)(i0 + srow) * ND;
  const float* bro = Y + (size_t)(j0 + srow) * ND;

  const int lane = t & 63, w = t >> 6;
  const int fr = lane & 15, fo = (lane >> 4) * 8;
  const int aofs = (w * 16 + fr) * PIT + fo;

  f32x4 acc[8];
  #pragma unroll
  for (int cc = 0; cc < 8; ++cc) acc[cc] = (f32x4){0.f, 0.f, 0.f, 0.f};

  for (int c = 0; c < KCH; ++c) {
    int kg = c * 32 + kloc;
    stage8(aro, avalid, kg, Ah, Al, lofs);
    stage8(bro, bvalid, kg, Bh, Bl, lofs);
    __syncthreads();

    bf16x8 ah = *(const bf16x8*)(Ah + aofs);
    bf16x8 al = *(const bf16x8*)(Al + aofs);
    #pragma unroll
    for (int cc = 0; cc < 8; ++cc) {
      int bofs = (cc * 16 + fr) * PIT + fo;
      bf16x8 bh = *(const bf16x8*)(Bh + bofs);
      bf16x8 bl = *(const bf16x8*)(Bl + bofs);
      acc[cc] = __builtin_amdgcn_mfma_f32_16x16x32_bf16(ah, bh, acc[cc], 0, 0, 0);
      acc[cc] = __builtin_amdgcn_mfma_f32_16x16x32_bf16(ah, bl, acc[cc], 0, 0, 0);
      acc[cc] = __builtin_amdgcn_mfma_f32_16x16x32_bf16(al, bh, acc[cc], 0, 0, 0);
    }
    __syncthreads();
  }

  #pragma unroll
  for (int cc = 0; cc < 8; ++cc) {
    int gj = j0 + cc * 16 + fr;
    if (gj >= nY) continue;
    float ny = NY[gj];
    #pragma unroll
    for (int reg = 0; reg < 4; ++reg) {
      int gi = i0 + w * 16 + (lane >> 4) * 4 + reg;
      if (gi >= nX) continue;
      float sq = NX[gi] + ny - 2.f * acc[cc][reg];
      float cv = fmaxf(sq, 0.f) * CSCALE;
      if (mode == 0) {
        int k = gj / 50, jj = gj - k * 50;
        C[((size_t)((gi >> 7) * NK + k)) * (NL * NR) + (gi & 127) * NR + jj] = cv;
      } else {
        int ki = gi / 50, ii = gi - ki * 50;
        int kj = gj / 50, jj = gj - kj * 50;
        C[((size_t)(ki * NK + kj)) * (NR * NR) + ii * NR + jj] = cv;
      }
    }
  }
}

// ---------------------------------------------------------------- cost MFMA (aa)
__global__ __launch_bounds__(512)
void cost_mfma_aa(const float* __restrict__ X, const float* __restrict__ NX,
                  float* __restrict__ C) {
  __shared__ __align__(16) short Ah[128 * PIT], Al[128 * PIT];

  const int t = threadIdx.x, b = blockIdx.x;
  const int srow = t >> 2, skq = t & 3, kloc = skq * 8;
  const int lofs = srow * PIT + kloc;
  const float* aro = X + (size_t)(b * NL + srow) * ND;

  const int lane = t & 63, w = t >> 6;
  const int fr = lane & 15, fo = (lane >> 4) * 8;
  const int aofs = (w * 16 + fr) * PIT + fo;

  f32x4 acc[8];
  #pragma unroll
  for (int cc = 0; cc < 8; ++cc) acc[cc] = (f32x4){0.f, 0.f, 0.f, 0.f};

  for (int c = 0; c < KCH; ++c) {
    stage8(aro, true, c * 32 + kloc, Ah, Al, lofs);
    __syncthreads();

    bf16x8 ah = *(const bf16x8*)(Ah + aofs);
    bf16x8 al = *(const bf16x8*)(Al + aofs);
    #pragma unroll
    for (int cc = 0; cc < 8; ++cc) {
      int bofs = (cc * 16 + fr) * PIT + fo;
      bf16x8 bh = *(const bf16x8*)(Ah + bofs);
      bf16x8 bl = *(const bf16x8*)(Al + bofs);
      acc[cc] = __builtin_amdgcn_mfma_f32_16x16x32_bf16(ah, bh, acc[cc], 0, 0, 0);
      acc[cc] = __builtin_amdgcn_mfma_f32_16x16x32_bf16(ah, bl, acc[cc], 0, 0, 0);
      acc[cc] = __builtin_amdgcn_mfma_f32_16x16x32_bf16(al, bh, acc[cc], 0, 0, 0);
    }
    __syncthreads();
  }

  const float* nb = NX + b * NL;
  float* Cb = C + (size_t)b * (NL * NL);
  #pragma unroll
  for (int cc = 0; cc < 8; ++cc) {
    int gj = cc * 16 + fr;
    float ny = nb[gj];
    #pragma unroll
    for (int reg = 0; reg < 4; ++reg) {
      int gi = w * 16 + (lane >> 4) * 4 + reg;
      float sq = nb[gi] + ny - 2.f * acc[cc][reg];
      Cb[(size_t)gi * NL + gj] = fmaxf(sq, 0.f) * CSCALE;
    }
  }
}

// ---------------------------------------------------------------- sinkhorn ab + tt (fused launch)
// smem ~2.4KB only: C fragments load straight from global into registers.
__global__ __launch_bounds__(256)
void sinkhorn_abtt(const float* __restrict__ Cab, const float* __restrict__ Ctt,
                   const float* __restrict__ lw2, const float* __restrict__ weight,
                   float* __restrict__ oab, float* __restrict__ ott) {
  __shared__ float smem[440];
  const int t = threadIdx.x;

  if (blockIdx.x < NB * NK) {
    // ------------------------------ ab body (128x50)
    float* g2    = smem;                 // 50
    float* f2    = smem + 52;            // 128
    float* potf2 = smem + 180;           // 128
    float* la2s  = smem + 308;           // 128
    float* red   = smem + 436;           // 4
    int p = blockIdx.x, b = p / NK;
    const float* Cp = Cab + (size_t)p * (NL * NR);
    if (t < NL) la2s[t] = lw2[b * NL + t];
    if (t < NR) g2[t] = 0.f;

    const int rf = t >> 1, sf = t & 1;
    float Crowb[25];                     // -C - Bf (bias folded)
    {
      const float* rp = Cp + rf * NR + sf * 25;
      #pragma unroll
      for (int j = 0; j < 25; ++j) Crowb[j] = -rp[j];
    }
    float Bf = 0.f;
    const int cc = t >> 2, sc = t & 3;
    float Ccolb[32];                     // -C - Bg
    float Bg = 0.f;
    if (t < 200) {
      #pragma unroll
      for (int i = 0; i < 32; ++i) Ccolb[i] = -Cp[(sc * 32 + i) * NR + cc];
    }
    __syncthreads();

    const float* gbase = g2 + sf * 25;
    const float* fbase = potf2 + sc * 32;

    for (int it = 0; it < NITER; ++it) {
      // ---- f update: 4-way partial chains
      {
        float s0 = 0.f, s1 = 0.f, s2 = 0.f, s3 = 0.f;
        float m0 = -3.0e38f, m1 = -3.0e38f, m2 = -3.0e38f, m3 = -3.0e38f;
        #pragma unroll
        for (int j = 0; j < 24; j += 4) {
          float x0 = gbase[j]     + Crowb[j];
          float x1 = gbase[j + 1] + Crowb[j + 1];
          float x2 = gbase[j + 2] + Crowb[j + 2];
          float x3 = gbase[j + 3] + Crowb[j + 3];
          m0 = fmaxf(m0, x0); s0 += ex2(x0);
          m1 = fmaxf(m1, x1); s1 += ex2(x1);
          m2 = fmaxf(m2, x2); s2 += ex2(x2);
          m3 = fmaxf(m3, x3); s3 += ex2(x3);
        }
        { float x = gbase[24] + Crowb[24]; m0 = fmaxf(m0, x); s0 += ex2(x); }
        float mx = fmaxf(fmaxf(m0, m1), fmaxf(m2, m3));
        float s  = (s0 + s1) + (s2 + s3);
        mx = fmaxf(mx, __shfl_xor(mx, 1));
        s += __shfl_xor(s, 1);
        if (mx > MX_HI || mx < MX_LO) {   // redo: rebias + re-exp only
          s0 = s1 = s2 = s3 = 0.f;
          #pragma unroll
          for (int j = 0; j < 25; ++j) Crowb[j] -= mx;
          #pragma unroll
          for (int j = 0; j < 24; j += 4) {
            s0 += ex2(gbase[j]     + Crowb[j]);
            s1 += ex2(gbase[j + 1] + Crowb[j + 1]);
            s2 += ex2(gbase[j + 2] + Crowb[j + 2]);
            s3 += ex2(gbase[j + 3] + Crowb[j + 3]);
          }
          s0 += ex2(gbase[24] + Crowb[24]);
          s = (s0 + s1) + (s2 + s3);
          s += __shfl_xor(s, 1);
          Bf += mx;
        }
        if (sf == 0) {
          float fv = LOG2_50 - (Bf + lg2(s));
          f2[rf] = fv; potf2[rf] = la2s[rf] + fv;
        }
      }
      __syncthreads();
      // ---- g update
      if (t < 200) {
        float s0 = 0.f, s1 = 0.f, s2 = 0.f, s3 = 0.f;
        float m0 = -3.0e38f, m1 = -3.0e38f, m2 = -3.0e38f, m3 = -3.0e38f;
        #pragma unroll
        for (int i = 0; i < 32; i += 4) {
          float x0 = fbase[i]     + Ccolb[i];
          float x1 = fbase[i + 1] + Ccolb[i + 1];
          float x2 = fbase[i + 2] + Ccolb[i + 2];
          float x3 = fbase[i + 3] + Ccolb[i + 3];
          m0 = fmaxf(m0, x0); s0 += ex2(x0);
          m1 = fmaxf(m1, x1); s1 += ex2(x1);
          m2 = fmaxf(m2, x2); s2 += ex2(x2);
          m3 = fmaxf(m3, x3); s3 += ex2(x3);
        }
        float mx = fmaxf(fmaxf(m0, m1), fmaxf(m2, m3));
        float s  = (s0 + s1) + (s2 + s3);
        mx = fmaxf(mx, __shfl_xor(mx, 1));
        mx = fmaxf(mx, __shfl_xor(mx, 2));
        s += __shfl_xor(s, 1);
        s += __shfl_xor(s, 2);
        if (mx > MX_HI || mx < MX_LO) {
          s0 = s1 = s2 = s3 = 0.f;
          #pragma unroll
          for (int i = 0; i < 32; ++i) Ccolb[i] -= mx;
          #pragma unroll
          for (int i = 0; i < 32; i += 4) {
            s0 += ex2(fbase[i]     + Ccolb[i]);
            s1 += ex2(fbase[i + 1] + Ccolb[i + 1]);
            s2 += ex2(fbase[i + 2] + Ccolb[i + 2]);
            s3 += ex2(fbase[i + 3] + Ccolb[i + 3]);
          }
          s = (s0 + s1) + (s2 + s3);
          s += __shfl_xor(s, 1);
          s += __shfl_xor(s, 2);
          Bg += mx;
        }
        if (sc == 0) g2[cc] = -(Bg + lg2(s));
      }
      __syncthreads();
    }

    float acc = 0.f;
    if (t < NL) acc = weight[b * NL + t] * f2[t];
    else if (t < NL + NR) acc = g2[t - NL] * (1.0f / NR);
    #pragma unroll
    for (int off = 32; off; off >>= 1) acc += __shfl_xor(acc, off);
    if ((t & 63) == 0) red[t >> 6] = acc;
    __syncthreads();
    if (t == 0) oab[p] = VSCALE * (red[0] + red[1] + red[2] + red[3]);

  } else {
    // ------------------------------ tt body (50x50, both uniform 1/50)
    // reg-resident: thread (r=t>>2, sub=t&3) handles elements idx = sub+4j.
    float* f2 = smem;                    // 50
    float* g2 = smem + 52;               // 50
    float* red = smem + 104;             // 4
    int p = blockIdx.x - NB * NK;
    const float* Cp = Ctt + (size_t)p * (NR * NR);
    if (t < NR) g2[t] = 0.f;

    const int r = t >> 2, sub = t & 3;
    const bool act = (t < 200);
    float Crowb[13], Ccolb[13];
    float Bf = 0.f, Bg = 0.f;
    if (act) {
      #pragma unroll
      for (int j = 0; j < 13; ++j) {
        int idx = sub + 4 * j;
        Crowb[j] = (idx < NR) ? -Cp[r * NR + idx] : -3.0e38f;
        Ccolb[j] = (idx < NR) ? -Cp[idx * NR + r] : -3.0e38f;
      }
    }
    __syncthreads();

    for (int it = 0; it < NITER; ++it) {
      if (act) {
        float s0 = 0.f, s1 = 0.f, m0 = -3.0e38f, m1 = -3.0e38f;
        #pragma unroll
        for (int j = 0; j < 12; j += 2) {
          int i0 = sub + 4 * j, i1 = sub + 4 * (j + 1);
          float x0 = g2[i0] + Crowb[j];
          float x1 = g2[i1] + Crowb[j + 1];
          m0 = fmaxf(m0, x0); s0 += ex2(x0);
          m1 = fmaxf(m1, x1); s1 += ex2(x1);
        }
        { int i0 = sub + 48; float x = ((i0 < NR) ? g2[i0] : 0.f) + Crowb[12];
          m0 = fmaxf(m0, x); s0 += ex2(x); }
        float mx = fmaxf(m0, m1);
        float s  = s0 + s1;
        mx = fmaxf(mx, __shfl_xor(mx, 1));
        mx = fmaxf(mx, __shfl_xor(mx, 2));
        s += __shfl_xor(s, 1);
        s += __shfl_xor(s, 2);
        if (mx > MX_HI || mx < MX_LO) {
          #pragma unroll
          for (int j = 0; j < 13; ++j) Crowb[j] -= mx;
          s0 = s1 = 0.f;
          #pragma unroll
          for (int j = 0; j < 12; j += 2) {
            int i0 = sub + 4 * j, i1 = sub + 4 * (j + 1);
            s0 += ex2(g2[i0] + Crowb[j]);
            s1 += ex2(g2[i1] + Crowb[j + 1]);
          }
          { int i0 = sub + 48; s0 += ex2(((i0 < NR) ? g2[i0] : 0.f) + Crowb[12]); }
          s = s0 + s1;
          s += __shfl_xor(s, 1);
          s += __shfl_xor(s, 2);
          Bf += mx;
        }
        if (sub == 0) f2[r] = LOG2_50 - (Bf + lg2(s));
      }
      __syncthreads();
      if (act) {
        float s0 = 0.f, s1 = 0.f, m0 = -3.0e38f, m1 = -3.0e38f;
        #pragma unroll
        for (int j = 0; j < 12; j += 2) {
          int i0 = sub + 4 * j, i1 = sub + 4 * (j + 1);
          float x0 = f2[i0] + Ccolb[j];
          float x1 = f2[i1] + Ccolb[j + 1];
          m0 = fmaxf(m0, x0); s0 += ex2(x0);
          m1 = fmaxf(m1, x1); s1 += ex2(x1);
        }
        { int i0 = sub + 48; float x = ((i0 < NR) ? f2[i0] : 0.f) + Ccolb[12];
          m0 = fmaxf(m0, x); s0 += ex2(x); }
        float mx = fmaxf(m0, m1);
        float s  = s0 + s1;
        mx = fmaxf(mx, __shfl_xor(mx, 1));
        mx = fmaxf(mx, __shfl_xor(mx, 2));
        s += __shfl_xor(s, 1);
        s += __shfl_xor(s, 2);
        if (mx > MX_HI || mx < MX_LO) {
          #pragma unroll
          for (int j = 0; j < 13; ++j) Ccolb[j] -= mx;
          s0 = s1 = 0.f;
          #pragma unroll
          for (int j = 0; j < 12; j += 2) {
            int i0 = sub + 4 * j, i1 = sub + 4 * (j + 1);
            s0 += ex2(f2[i0] + Ccolb[j]);
            s1 += ex2(f2[i1] + Ccolb[j + 1]);
          }
          { int i0 = sub + 48; s0 += ex2(((i0 < NR) ? f2[i0] : 0.f) + Ccolb[12]); }
          s = s0 + s1;
          s += __shfl_xor(s, 1);
          s += __shfl_xor(s, 2);
          Bg += mx;
        }
        if (sub == 0) g2[r] = LOG2_50 - (Bg + lg2(s));
      }
      __syncthreads();
    }

    float acc = 0.f;
    if (t < NR) acc = f2[t] + g2[t];
    #pragma unroll
    for (int off = 32; off; off >>= 1) acc += __shfl_xor(acc, off);
    if ((t & 63) == 0) red[t >> 6] = acc;
    __syncthreads();
    if (t == 0) ott[p] = VSCALE * (1.0f / NR) * (red[0] + red[1] + red[2] + red[3]);
  }
}

// ---------------------------------------------------------------- sinkhorn aa
__global__ __launch_bounds__(512)
void sinkhorn_aa(const float* __restrict__ Cg, const float* __restrict__ lw2,
                 const float* __restrict__ weight, float* __restrict__ ot) {
  __shared__ float pF[NL];
  __shared__ float pG[NL];
  __shared__ float red[8];
  int b = blockIdx.x, t = threadIdx.x;
  int r = t >> 2, sub = t & 3;
  const float* Cp = Cg + (size_t)b * (NL * NL) + (size_t)r * NL + sub * 32;
  const float* lp = lw2 + b * NL + sub * 32;
  float CrF[32], CrG[32];
  #pragma unroll
  for (int i = 0; i < 32; i += 4) {
    float4 cv = *(const float4*)(Cp + i);
    float4 lv = *(const float4*)(lp + i);
    CrF[i]     = lv.x - cv.x; CrF[i + 1] = lv.y - cv.y;
    CrF[i + 2] = lv.z - cv.z; CrF[i + 3] = lv.w - cv.w;
  }
  #pragma unroll
  for (int i = 0; i < 32; ++i) CrG[i] = CrF[i];
  float BF = 0.f, BG = 0.f;
  if (t < NL) pG[t] = 0.f;
  __syncthreads();

  const float* spG = pG + sub * 32;
  const float* spF = pF + sub * 32;

  for (int it = 0; it < NITER; ++it) {
    // ---- f = T(g)
    {
      float s0 = 0.f, s1 = 0.f, s2 = 0.f, s3 = 0.f;
      float m0 = -3.0e38f, m1 = -3.0e38f, m2 = -3.0e38f, m3 = -3.0e38f;
      #pragma unroll
      for (int i = 0; i < 32; i += 4) {
        float x0 = spG[i]     + CrF[i];
        float x1 = spG[i + 1] + CrF[i + 1];
        float x2 = spG[i + 2] + CrF[i + 2];
        float x3 = spG[i + 3] + CrF[i + 3];
        m0 = fmaxf(m0, x0); s0 += ex2(x0);
        m1 = fmaxf(m1, x1); s1 += ex2(x1);
        m2 = fmaxf(m2, x2); s2 += ex2(x2);
        m3 = fmaxf(m3, x3); s3 += ex2(x3);
      }
      float mx = fmaxf(fmaxf(m0, m1), fmaxf(m2, m3));
      float s  = (s0 + s1) + (s2 + s3);
      mx = fmaxf(mx, __shfl_xor(mx, 1));
      mx = fmaxf(mx, __shfl_xor(mx, 2));
      s += __shfl_xor(s, 1);
      s += __shfl_xor(s, 2);
      if (mx > MX_HI || mx < MX_LO) {
        #pragma unroll
        for (int i = 0; i < 32; ++i) CrF[i] -= mx;
        s0 = s1 = s2 = s3 = 0.f;
        #pragma unroll
        for (int i = 0; i < 32; i += 4) {
          s0 += ex2(spG[i]     + CrF[i]);
          s1 += ex2(spG[i + 1] + CrF[i + 1]);
          s2 += ex2(spG[i + 2] + CrF[i + 2]);
          s3 += ex2(spG[i + 3] + CrF[i + 3]);
        }
        s = (s0 + s1) + (s2 + s3);
        s += __shfl_xor(s, 1);
        s += __shfl_xor(s, 2);
        BF += mx;
      }
      if (sub == 0) pF[r] = -(BF + lg2(s));
    }
    __syncthreads();
    // ---- g = T(f)
    {
      float s0 = 0.f, s1 = 0.f, s2 = 0.f, s3 = 0.f;
      float m0 = -3.0e38f, m1 = -3.0e38f, m2 = -3.0e38f, m3 = -3.0e38f;
      #pragma unroll
      for (int i = 0; i < 32; i += 4) {
        float x0 = spF[i]     + CrG[i];
        float x1 = spF[i + 1] + CrG[i + 1];
        float x2 = spF[i + 2] + CrG[i + 2];
        float x3 = spF[i + 3] + CrG[i + 3];
        m0 = fmaxf(m0, x0); s0 += ex2(x0);
        m1 = fmaxf(m1, x1); s1 += ex2(x1);
        m2 = fmaxf(m2, x2); s2 += ex2(x2);
        m3 = fmaxf(m3, x3); s3 += ex2(x3);
      }
      float mx = fmaxf(fmaxf(m0, m1), fmaxf(m2, m3));
      float s  = (s0 + s1) + (s2 + s3);
      mx = fmaxf(mx, __shfl_xor(mx, 1));
      mx = fmaxf(mx, __shfl_xor(mx, 2));
      s += __shfl_xor(s, 1);
      s += __shfl_xor(s, 2);
      if (mx > MX_HI || mx < MX_LO) {
        #pragma unroll
        for (int i = 0; i < 32; ++i) CrG[i] -= mx;
        s0 = s1 = s2 = s3 = 0.f;
        #pragma unroll
        for (int i = 0; i < 32; i += 4) {
          s0 += ex2(spF[i]     + CrG[i]);
          s1 += ex2(spF[i + 1] + CrG[i + 1]);
          s2 += ex2(spF[i + 2] + CrG[i + 2]);
          s3 += ex2(spF[i + 3] + CrG[i + 3]);
        }
        s = (s0 + s1) + (s2 + s3);
        s += __shfl_xor(s, 1);
        s += __shfl_xor(s, 2);
        BG += mx;
      }
      if (sub == 0) pG[r] = -(BG + lg2(s));
    }
    __syncthreads();
  }

  float acc = 0.f;
  if (t < NL) acc = weight[b * NL + t] * (pF[t] + pG[t]);
  #pragma unroll
  for (int off = 32; off; off >>= 1) acc += __shfl_xor(acc, off);
  if ((t & 63) == 0) red[t >> 6] = acc;
  __syncthreads();
  if (t == 0) {
    float v = 0.f;
    #pragma unroll
    for (int i = 0; i < 8; ++i) v += red[i];
    ot[b] = VSCALE * v;
  }
}

// ---------------------------------------------------------------- finalize
__global__ void finalize_kernel(const float* __restrict__ oab, const float* __restrict__ oaa,
                                const float* __restrict__ ott, const int* __restrict__ grade,
                                float* __restrict__ out) {
  __shared__ float selft[NK];
  __shared__ float redL[4], redD[4];
  int t = threadIdx.x;
  if (t < NK) selft[t] = ott[t * NK + t];
  __syncthreads();
  float dpart = (t < NK * NK) ? ott[t] : 0.f;
  float lpart = 0.f;
  if (t < NB) {
    int g = grade[t];
    float oa = oaa[t];
    float dpos = oab[t * NK + g] - 0.5f * (oa + selft[g]);
    float s = 0.f;
    #pragma unroll
    for (int k = 0; k < NK; ++k) {
      float dk = oab[t * NK + k] - 0.5f * (oa + selft[k]);
      s += fmaxf(dpos - dk + 10.0f, 0.0f);
    }
    lpart = s - 10.0f;
  }
  #pragma unroll
  for (int off = 32; off; off >>= 1) {
    dpart += __shfl_xor(dpart, off);
    lpart += __shfl_xor(lpart, off);
  }
  if ((t & 63) == 0) { redD[t >> 6] = dpart; redL[t >> 6] = lpart; }
  __syncthreads();
  if (t == 0) {
    float ds = 0.f, ls = 0.f;
    #pragma unroll
    for (int i = 0; i < 4; ++i) { ds += redD[i]; ls += redL[i]; }
    float ss = 0.f;
    #pragma unroll
    for (int k = 0; k < NK; ++k) ss += selft[k];
    float dis = ds - (float)NK * ss;
    out[0] = ls / (float)NB - dis * 0.01f;
  }
}

// ---------------------------------------------------------------- launch
extern "C" void kernel_launch(void* const* d_in, const int* in_sizes, int n_in,
                              void* d_out, int out_size, void* d_ws, size_t ws_size,
                              hipStream_t stream) {
  (void)in_sizes; (void)n_in; (void)out_size; (void)ws_size;
  const float* anchor = (const float*)d_in[0];
  const float* weight = (const float*)d_in[1];
  const float* t0     = (const float*)d_in[2];
  const int*   len    = (const int*)d_in[3];
  const int*   grade  = (const int*)d_in[4];
  float* out = (float*)d_out;

  float* ws  = (float*)d_ws;
  float* Cab = ws;                                    // 819200
  float* Caa = Cab + (size_t)NB * NK * NL * NR;       // 2097152
  float* Ctt = Caa + (size_t)NB * NL * NL;            // 250000
  float* na  = Ctt + (size_t)NK * NK * NR * NR;       // 16384
  float* nt  = na + NB * NL;                          // 500
  float* lw2 = nt + NK * NR;                          // 16384
  float* oab = lw2 + NB * NL;                         // 1280
  float* oaa = oab + NB * NK;                         // 128
  float* ott = oaa + NB;                              // 100

  prep_kernel<<<(NB * NL + NK * NR) / 4, 256, 0, stream>>>(anchor, weight, t0, len, na, nt, lw2);
  cost_mfma<<<dim3(128, 4), 512, 0, stream>>>(anchor, t0, na, nt, Cab,
                                              NB * NL, NK * NR, 0);
  cost_mfma<<<dim3(4, 4), 512, 0, stream>>>(t0, t0, nt, nt, Ctt,
                                            NK * NR, NK * NR, 2);
  cost_mfma_aa<<<NB, 512, 0, stream>>>(anchor, na, Caa);

  sinkhorn_abtt<<<NB * NK + NK * NK, 256, 0, stream>>>(Cab, Ctt, lw2, weight, oab, ott);
  sinkhorn_aa<<<NB, 512, 0, stream>>>(Caa, lw2, weight, oaa);
  finalize_kernel<<<1, 256, 0, stream>>>(oab, oaa, ott, grade, out);
}

// Round 11
// 200.731 us; speedup vs baseline: 15.1627x; 1.0137x over previous
//
#include <hip/hip_runtime.h>
#include <math.h>

// Sinkhorn-divergence triplet loss (geomloss-style), MI355X.
// R11: exact 2-pass LSE with register-CACHED x (pass1: x=pot+(-C), fmax;
// pass2: exp2(x-mx)) -- R7..R10 evidence shows the defer-max guard redid the
// exp pass nearly every iteration (potential drift ~577*dF/iter >> any window),
// so the cheapest correct structure is two minimal passes with x held in VGPRs:
// no bias state, no redo, LDS read once (as float4; g2 padded to 56 with
// -3e38 sentinels). aa bonus: costs now immutable -> ONE Cr array serves both
// update directions (-32 VGPR). Cost matrices via MFMA (R7 split-bf16).
// Native v_exp/v_log (R9). Launch-bounds law: never pass arg2 (R3/R4).

namespace {
constexpr int NB = 128, NL = 128, ND = 300, NK = 10, NR = 50, NITER = 20;
constexpr float LOG2E   = 1.4426950408889634f;
constexpr float EPS     = 0.0025f;                  // blur^p = 0.05^2
constexpr float CSCALE  = 0.5f * LOG2E / EPS;       // squared-dist -> log2-domain cost
constexpr float VSCALE  = EPS * 0.6931471805599453f; // log2-potential -> nat (eps*ln2)
constexpr float LOG2_50 = 5.6438561897747395f;      // log2(50)
constexpr float NEGL2   = -1.442695e9f;             // -1e9 * log2e
constexpr float SENT    = -3.0e38f;                 // sentinel (exp2 -> 0)
constexpr int KCH = 10;                              // K chunks of 32
constexpr int PIT = 40;                              // LDS pitch in shorts
}

typedef __attribute__((ext_vector_type(8))) short bf16x8;
typedef __attribute__((ext_vector_type(4))) float f32x4;

__device__ inline float ex2(float x) { return __builtin_amdgcn_exp2f(x); }
__device__ inline float lg2(float x) { return __builtin_amdgcn_logf(x); }
__device__ inline f32x4 vmax4(f32x4 a, f32x4 b) {
  f32x4 r;
  r[0] = fmaxf(a[0], b[0]); r[1] = fmaxf(a[1], b[1]);
  r[2] = fmaxf(a[2], b[2]); r[3] = fmaxf(a[3], b[3]);
  return r;
}
__device__ inline f32x4 vexp4(f32x4 x) {
  f32x4 r;
  r[0] = ex2(x[0]); r[1] = ex2(x[1]); r[2] = ex2(x[2]); r[3] = ex2(x[3]);
  return r;
}

__device__ inline unsigned short f2bf_rn(float x) {
  unsigned int u = __float_as_uint(x);
  unsigned int r = (u + 0x7fffu + ((u >> 16) & 1u)) >> 16;
  return (unsigned short)r;
}
__device__ inline float bf2f(unsigned short h) {
  return __uint_as_float((unsigned int)h << 16);
}

// ---------------------------------------------------------------- prep
__global__ void prep_kernel(const float* __restrict__ anchor,
                            const float* __restrict__ weight,
                            const float* __restrict__ t0,
                            const int* __restrict__ len,
                            float* __restrict__ na, float* __restrict__ nt,
                            float* __restrict__ lw2) {
  int wid  = (blockIdx.x * blockDim.x + threadIdx.x) >> 6;
  int lane = threadIdx.x & 63;
  const int nA = NB * NL;
  const int total = nA + NK * NR;
  if (wid >= total) return;
  const float* src = (wid < nA) ? (anchor + (size_t)wid * ND)
                                : (t0 + (size_t)(wid - nA) * ND);
  float s = 0.f;
  for (int d = lane; d < ND; d += 64) { float v = src[d]; s += v * v; }
  #pragma unroll
  for (int off = 32; off; off >>= 1) s += __shfl_xor(s, off);
  if (lane == 0) { if (wid < nA) na[wid] = s; else nt[wid - nA] = s; }
  if (wid < nA && lane == 1) {
    int b = wid >> 7, l = wid & 127;
    float w = weight[wid];
    lw2[wid] = (l < len[b]) ? log2f(fmaxf(w, 1e-12f)) : NEGL2;
  }
}

// ---------------------------------------------------------------- staging helper
__device__ inline void stage8(const float* __restrict__ src, bool rowvalid,
                              int kg, short* __restrict__ Hs, short* __restrict__ Ls,
                              int lofs) {
  float xv[8];
  if (rowvalid && kg + 8 <= ND) {
    float4 u = *(const float4*)(src + kg);
    float4 v = *(const float4*)(src + kg + 4);
    xv[0]=u.x; xv[1]=u.y; xv[2]=u.z; xv[3]=u.w;
    xv[4]=v.x; xv[5]=v.y; xv[6]=v.z; xv[7]=v.w;
  } else {
    #pragma unroll
    for (int e = 0; e < 8; ++e)
      xv[e] = (rowvalid && kg + e < ND) ? src[kg + e] : 0.f;
  }
  bf16x8 hv, lv;
  #pragma unroll
  for (int e = 0; e < 8; ++e) {
    unsigned short h = f2bf_rn(xv[e]);
    float hf = bf2f(h);
    unsigned short l = f2bf_rn(xv[e] - hf);
    hv[e] = (short)h; lv[e] = (short)l;
  }
  *(bf16x8*)(Hs + lofs) = hv;
  *(bf16x8*)(Ls + lofs) = lv;
}

// ---------------------------------------------------------------- cost MFMA (ab / tt)
__global__ __launch_bounds__(512)
void cost_mfma(const float* __restrict__ X, const float* __restrict__ Y,
               const float* __restrict__ NX, const float* __restrict__ NY,
               float* __restrict__ C, int nX, int nY, int mode) {
  __shared__ __align__(16) short Ah[128 * PIT], Al[128 * PIT];
  __shared__ __align__(16) short Bh[128 * PIT], Bl[128 * PIT];

  const int t = threadIdx.x;
  const int i0 = blockIdx.x * 128, j0 = blockIdx.y * 128;
  const int srow = t >> 2, skq = t & 3, kloc = skq * 8;
  const int lofs = srow * PIT + kloc;
  const bool avalid = (i0 + srow) < nX;
  const bool bvalid = (j0 + srow) < nY;
  const float* aro = X + (size_t)(i0 + srow) * ND;
  const float* bro = Y + (size_t)(j0 + srow) * ND;

  const int lane = t & 63, w = t >> 6;
  const int fr = lane & 15, fo = (lane >> 4) * 8;
  const int aofs = (w * 16 + fr) * PIT + fo;

  f32x4 acc[8];
  #pragma unroll
  for (int cc = 0; cc < 8; ++cc) acc[cc] = (f32x4){0.f, 0.f, 0.f, 0.f};

  for (int c = 0; c < KCH; ++c) {
    int kg = c * 32 + kloc;
    stage8(aro, avalid, kg, Ah, Al, lofs);
    stage8(bro, bvalid, kg, Bh, Bl, lofs);
    __syncthreads();

    bf16x8 ah = *(const bf16x8*)(Ah + aofs);
    bf16x8 al = *(const bf16x8*)(Al + aofs);
    #pragma unroll
    for (int cc = 0; cc < 8; ++cc) {
      int bofs = (cc * 16 + fr) * PIT + fo;
      bf16x8 bh = *(const bf16x8*)(Bh + bofs);
      bf16x8 bl = *(const bf16x8*)(Bl + bofs);
      acc[cc] = __builtin_amdgcn_mfma_f32_16x16x32_bf16(ah, bh, acc[cc], 0, 0, 0);
      acc[cc] = __builtin_amdgcn_mfma_f32_16x16x32_bf16(ah, bl, acc[cc], 0, 0, 0);
      acc[cc] = __builtin_amdgcn_mfma_f32_16x16x32_bf16(al, bh, acc[cc], 0, 0, 0);
    }
    __syncthreads();
  }

  #pragma unroll
  for (int cc = 0; cc < 8; ++cc) {
    int gj = j0 + cc * 16 + fr;
    if (gj >= nY) continue;
    float ny = NY[gj];
    #pragma unroll
    for (int reg = 0; reg < 4; ++reg) {
      int gi = i0 + w * 16 + (lane >> 4) * 4 + reg;
      if (gi >= nX) continue;
      float sq = NX[gi] + ny - 2.f * acc[cc][reg];
      float cv = fmaxf(sq, 0.f) * CSCALE;
      if (mode == 0) {
        int k = gj / 50, jj = gj - k * 50;
        C[((size_t)((gi >> 7) * NK + k)) * (NL * NR) + (gi & 127) * NR + jj] = cv;
      } else {
        int ki = gi / 50, ii = gi - ki * 50;
        int kj = gj / 50, jj = gj - kj * 50;
        C[((size_t)(ki * NK + kj)) * (NR * NR) + ii * NR + jj] = cv;
      }
    }
  }
}

// ---------------------------------------------------------------- cost MFMA (aa)
__global__ __launch_bounds__(512)
void cost_mfma_aa(const float* __restrict__ X, const float* __restrict__ NX,
                  float* __restrict__ C) {
  __shared__ __align__(16) short Ah[128 * PIT], Al[128 * PIT];

  const int t = threadIdx.x, b = blockIdx.x;
  const int srow = t >> 2, skq = t & 3, kloc = skq * 8;
  const int lofs = srow * PIT + kloc;
  const float* aro = X + (size_t)(b * NL + srow) * ND;

  const int lane = t & 63, w = t >> 6;
  const int fr = lane & 15, fo = (lane >> 4) * 8;
  const int aofs = (w * 16 + fr) * PIT + fo;

  f32x4 acc[8];
  #pragma unroll
  for (int cc = 0; cc < 8; ++cc) acc[cc] = (f32x4){0.f, 0.f, 0.f, 0.f};

  for (int c = 0; c < KCH; ++c) {
    stage8(aro, true, c * 32 + kloc, Ah, Al, lofs);
    __syncthreads();

    bf16x8 ah = *(const bf16x8*)(Ah + aofs);
    bf16x8 al = *(const bf16x8*)(Al + aofs);
    #pragma unroll
    for (int cc = 0; cc < 8; ++cc) {
      int bofs = (cc * 16 + fr) * PIT + fo;
      bf16x8 bh = *(const bf16x8*)(Ah + bofs);
      bf16x8 bl = *(const bf16x8*)(Al + bofs);
      acc[cc] = __builtin_amdgcn_mfma_f32_16x16x32_bf16(ah, bh, acc[cc], 0, 0, 0);
      acc[cc] = __builtin_amdgcn_mfma_f32_16x16x32_bf16(ah, bl, acc[cc], 0, 0, 0);
      acc[cc] = __builtin_amdgcn_mfma_f32_16x16x32_bf16(al, bh, acc[cc], 0, 0, 0);
    }
    __syncthreads();
  }

  const float* nb = NX + b * NL;
  float* Cb = C + (size_t)b * (NL * NL);
  #pragma unroll
  for (int cc = 0; cc < 8; ++cc) {
    int gj = cc * 16 + fr;
    float ny = nb[gj];
    #pragma unroll
    for (int reg = 0; reg < 4; ++reg) {
      int gi = w * 16 + (lane >> 4) * 4 + reg;
      float sq = nb[gi] + ny - 2.f * acc[cc][reg];
      Cb[(size_t)gi * NL + gj] = fmaxf(sq, 0.f) * CSCALE;
    }
  }
}

// ---------------------------------------------------------------- sinkhorn ab + tt (fused launch)
// ab: f-update rf=t>>1, sf=t&1 over 28 cols (g2 padded to 56, SENT pads);
//     g-update cc=t>>2, sc=t&3 over 32 rows. Exact 2-pass LSE, x cached in regs.
__global__ __launch_bounds__(256)
void sinkhorn_abtt(const float* __restrict__ Cab, const float* __restrict__ Ctt,
                   const float* __restrict__ lw2, const float* __restrict__ weight,
                   float* __restrict__ oab, float* __restrict__ ott) {
  __shared__ __align__(16) float smem[444];
  const int t = threadIdx.x;

  if (blockIdx.x < NB * NK) {
    // ------------------------------ ab body (128x50)
    float* g2    = smem;                 // 56 (50 real + 6 SENT pads)
    float* f2    = smem + 56;            // 128
    float* potf2 = smem + 184;           // 128 (16B-aligned: 184*4=736)
    float* la2s  = smem + 312;           // 128
    float* red   = smem + 440;           // 4
    int p = blockIdx.x, b = p / NK;
    const float* Cp = Cab + (size_t)p * (NL * NR);
    if (t < NL) la2s[t] = lw2[b * NL + t];
    if (t < NR) g2[t] = 0.f;
    else if (t < 56) g2[t] = SENT;

    const int rf = t >> 1, sf = t & 1;
    f32x4 Crow4[7];                      // -C row fragment (immutable), pads 0
    {
      const float* rp = Cp + rf * NR;
      #pragma unroll
      for (int q = 0; q < 7; ++q)
        #pragma unroll
        for (int e = 0; e < 4; ++e) {
          int col = sf * 28 + q * 4 + e;
          Crow4[q][e] = (col < NR) ? -rp[col] : 0.f;
        }
    }
    const int cc = t >> 2, sc = t & 3;
    f32x4 Ccol4[8];                      // -C col fragment (immutable)
    if (t < 200) {
      #pragma unroll
      for (int q = 0; q < 8; ++q)
        #pragma unroll
        for (int e = 0; e < 4; ++e)
          Ccol4[q][e] = -Cp[(sc * 32 + q * 4 + e) * NR + cc];
    }
    __syncthreads();

    const f32x4* g4base = (const f32x4*)(g2 + sf * 28);
    const f32x4* f4base = (const f32x4*)(potf2 + sc * 32);

    for (int it = 0; it < NITER; ++it) {
      // ---- f update: pass1 x+max, pass2 exp(x-mx)
      {
        f32x4 x[7];
        f32x4 m4 = {SENT, SENT, SENT, SENT};
        #pragma unroll
        for (int q = 0; q < 7; ++q) {
          x[q] = g4base[q] + Crow4[q];
          m4 = vmax4(m4, x[q]);
        }
        float mx = fmaxf(fmaxf(m4[0], m4[1]), fmaxf(m4[2], m4[3]));
        mx = fmaxf(mx, __shfl_xor(mx, 1));
        f32x4 s4 = {0.f, 0.f, 0.f, 0.f};
        #pragma unroll
        for (int q = 0; q < 7; ++q) s4 += vexp4(x[q] - mx);
        float s = (s4[0] + s4[1]) + (s4[2] + s4[3]);
        s += __shfl_xor(s, 1);
        if (sf == 0) {
          float fv = LOG2_50 - mx - lg2(s);
          f2[rf] = fv; potf2[rf] = la2s[rf] + fv;
        }
      }
      __syncthreads();
      // ---- g update
      if (t < 200) {
        f32x4 x[8];
        f32x4 m4 = {SENT, SENT, SENT, SENT};
        #pragma unroll
        for (int q = 0; q < 8; ++q) {
          x[q] = f4base[q] + Ccol4[q];
          m4 = vmax4(m4, x[q]);
        }
        float mx = fmaxf(fmaxf(m4[0], m4[1]), fmaxf(m4[2], m4[3]));
        mx = fmaxf(mx, __shfl_xor(mx, 1));
        mx = fmaxf(mx, __shfl_xor(mx, 2));
        f32x4 s4 = {0.f, 0.f, 0.f, 0.f};
        #pragma unroll
        for (int q = 0; q < 8; ++q) s4 += vexp4(x[q] - mx);
        float s = (s4[0] + s4[1]) + (s4[2] + s4[3]);
        s += __shfl_xor(s, 1);
        s += __shfl_xor(s, 2);
        if (sc == 0) g2[cc] = -(mx + lg2(s));
      }
      __syncthreads();
    }

    float acc = 0.f;
    if (t < NL) acc = weight[b * NL + t] * f2[t];
    else if (t < NL + NR) acc = g2[t - NL] * (1.0f / NR);
    #pragma unroll
    for (int off = 32; off; off >>= 1) acc += __shfl_xor(acc, off);
    if ((t & 63) == 0) red[t >> 6] = acc;
    __syncthreads();
    if (t == 0) oab[p] = VSCALE * (red[0] + red[1] + red[2] + red[3]);

  } else {
    // ------------------------------ tt body (50x50, both uniform 1/50)
    // reg-resident, exact 2-pass LSE with cached x (13 interleaved elems).
    float* f2 = smem;                    // 50
    float* g2 = smem + 56;               // 50
    float* red = smem + 112;             // 4
    int p = blockIdx.x - NB * NK;
    const float* Cp = Ctt + (size_t)p * (NR * NR);
    if (t < NR) g2[t] = 0.f;

    const int r = t >> 2, sub = t & 3;
    const bool act = (t < 200);
    float Crowb[13], Ccolb[13];
    if (act) {
      #pragma unroll
      for (int j = 0; j < 13; ++j) {
        int idx = sub + 4 * j;
        Crowb[j] = (idx < NR) ? -Cp[r * NR + idx] : SENT;
        Ccolb[j] = (idx < NR) ? -Cp[idx * NR + r] : SENT;
      }
    }
    __syncthreads();

    for (int it = 0; it < NITER; ++it) {
      if (act) {
        float x[13];
        float m0 = SENT, m1 = SENT;
        #pragma unroll
        for (int j = 0; j < 12; j += 2) {
          x[j]     = g2[sub + 4 * j]       + Crowb[j];
          x[j + 1] = g2[sub + 4 * (j + 1)] + Crowb[j + 1];
          m0 = fmaxf(m0, x[j]); m1 = fmaxf(m1, x[j + 1]);
        }
        { int i0 = sub + 48; x[12] = ((i0 < NR) ? g2[i0] : 0.f) + Crowb[12];
          m0 = fmaxf(m0, x[12]); }
        float mx = fmaxf(m0, m1);
        mx = fmaxf(mx, __shfl_xor(mx, 1));
        mx = fmaxf(mx, __shfl_xor(mx, 2));
        float s0 = 0.f, s1 = 0.f;
        #pragma unroll
        for (int j = 0; j < 12; j += 2) {
          s0 += ex2(x[j] - mx); s1 += ex2(x[j + 1] - mx);
        }
        s0 += ex2(x[12] - mx);
        float s = s0 + s1;
        s += __shfl_xor(s, 1);
        s += __shfl_xor(s, 2);
        if (sub == 0) f2[r] = LOG2_50 - mx - lg2(s);
      }
      __syncthreads();
      if (act) {
        float x[13];
        float m0 = SENT, m1 = SENT;
        #pragma unroll
        for (int j = 0; j < 12; j += 2) {
          x[j]     = f2[sub + 4 * j]       + Ccolb[j];
          x[j + 1] = f2[sub + 4 * (j + 1)] + Ccolb[j + 1];
          m0 = fmaxf(m0, x[j]); m1 = fmaxf(m1, x[j + 1]);
        }
        { int i0 = sub + 48; x[12] = ((i0 < NR) ? f2[i0] : 0.f) + Ccolb[12];
          m0 = fmaxf(m0, x[12]); }
        float mx = fmaxf(m0, m1);
        mx = fmaxf(mx, __shfl_xor(mx, 1));
        mx = fmaxf(mx, __shfl_xor(mx, 2));
        float s0 = 0.f, s1 = 0.f;
        #pragma unroll
        for (int j = 0; j < 12; j += 2) {
          s0 += ex2(x[j] - mx); s1 += ex2(x[j + 1] - mx);
        }
        s0 += ex2(x[12] - mx);
        float s = s0 + s1;
        s += __shfl_xor(s, 1);
        s += __shfl_xor(s, 2);
        if (sub == 0) g2[r] = LOG2_50 - mx - lg2(s);
      }
      __syncthreads();
    }

    float acc = 0.f;
    if (t < NR) acc = f2[t] + g2[t];
    #pragma unroll
    for (int off = 32; off; off >>= 1) acc += __shfl_xor(acc, off);
    if ((t & 63) == 0) red[t >> 6] = acc;
    __syncthreads();
    if (t == 0) ott[p] = VSCALE * (1.0f / NR) * (red[0] + red[1] + red[2] + red[3]);
  }
}

// ---------------------------------------------------------------- sinkhorn aa
// Symmetric C, equal marginals, IMMUTABLE folded cost (la2 - C) -> one Cr
// array serves both update directions. Exact 2-pass LSE with cached x.
__global__ __launch_bounds__(512)
void sinkhorn_aa(const float* __restrict__ Cg, const float* __restrict__ lw2,
                 const float* __restrict__ weight, float* __restrict__ ot) {
  __shared__ __align__(16) float pF[NL];
  __shared__ __align__(16) float pG[NL];
  __shared__ float red[8];
  int b = blockIdx.x, t = threadIdx.x;
  int r = t >> 2, sub = t & 3;
  const float* Cp = Cg + (size_t)b * (NL * NL) + (size_t)r * NL + sub * 32;
  const float* lp = lw2 + b * NL + sub * 32;
  f32x4 Cr4[8];                          // la2[col] - C[r][col], immutable
  #pragma unroll
  for (int q = 0; q < 8; ++q) {
    float4 cv = *(const float4*)(Cp + q * 4);
    float4 lv = *(const float4*)(lp + q * 4);
    Cr4[q] = (f32x4){lv.x - cv.x, lv.y - cv.y, lv.z - cv.z, lv.w - cv.w};
  }
  if (t < NL) pG[t] = 0.f;
  __syncthreads();

  const f32x4* spG = (const f32x4*)(pG + sub * 32);
  const f32x4* spF = (const f32x4*)(pF + sub * 32);

  for (int it = 0; it < NITER; ++it) {
    // ---- f = T(g)
    {
      f32x4 x[8];
      f32x4 m4 = {SENT, SENT, SENT, SENT};
      #pragma unroll
      for (int q = 0; q < 8; ++q) {
        x[q] = spG[q] + Cr4[q];
        m4 = vmax4(m4, x[q]);
      }
      float mx = fmaxf(fmaxf(m4[0], m4[1]), fmaxf(m4[2], m4[3]));
      mx = fmaxf(mx, __shfl_xor(mx, 1));
      mx = fmaxf(mx, __shfl_xor(mx, 2));
      f32x4 s4 = {0.f, 0.f, 0.f, 0.f};
      #pragma unroll
      for (int q = 0; q < 8; ++q) s4 += vexp4(x[q] - mx);
      float s = (s4[0] + s4[1]) + (s4[2] + s4[3]);
      s += __shfl_xor(s, 1);
      s += __shfl_xor(s, 2);
      if (sub == 0) pF[r] = -(mx + lg2(s));
    }
    __syncthreads();
    // ---- g = T(f)
    {
      f32x4 x[8];
      f32x4 m4 = {SENT, SENT, SENT, SENT};
      #pragma unroll
      for (int q = 0; q < 8; ++q) {
        x[q] = spF[q] + Cr4[q];
        m4 = vmax4(m4, x[q]);
      }
      float mx = fmaxf(fmaxf(m4[0], m4[1]), fmaxf(m4[2], m4[3]));
      mx = fmaxf(mx, __shfl_xor(mx, 1));
      mx = fmaxf(mx, __shfl_xor(mx, 2));
      f32x4 s4 = {0.f, 0.f, 0.f, 0.f};
      #pragma unroll
      for (int q = 0; q < 8; ++q) s4 += vexp4(x[q] - mx);
      float s = (s4[0] + s4[1]) + (s4[2] + s4[3]);
      s += __shfl_xor(s, 1);
      s += __shfl_xor(s, 2);
      if (sub == 0) pG[r] = -(mx + lg2(s));
    }
    __syncthreads();
  }

  float acc = 0.f;
  if (t < NL) acc = weight[b * NL + t] * (pF[t] + pG[t]);
  #pragma unroll
  for (int off = 32; off; off >>= 1) acc += __shfl_xor(acc, off);
  if ((t & 63) == 0) red[t >> 6] = acc;
  __syncthreads();
  if (t == 0) {
    float v = 0.f;
    #pragma unroll
    for (int i = 0; i < 8; ++i) v += red[i];
    ot[b] = VSCALE * v;
  }
}

// ---------------------------------------------------------------- finalize
__global__ void finalize_kernel(const float* __restrict__ oab, const float* __restrict__ oaa,
                                const float* __restrict__ ott, const int* __restrict__ grade,
                                float* __restrict__ out) {
  __shared__ float selft[NK];
  __shared__ float redL[4], redD[4];
  int t = threadIdx.x;
  if (t < NK) selft[t] = ott[t * NK + t];
  __syncthreads();
  float dpart = (t < NK * NK) ? ott[t] : 0.f;
  float lpart = 0.f;
  if (t < NB) {
    int g = grade[t];
    float oa = oaa[t];
    float dpos = oab[t * NK + g] - 0.5f * (oa + selft[g]);
    float s = 0.f;
    #pragma unroll
    for (int k = 0; k < NK; ++k) {
      float dk = oab[t * NK + k] - 0.5f * (oa + selft[k]);
      s += fmaxf(dpos - dk + 10.0f, 0.0f);
    }
    lpart = s - 10.0f;
  }
  #pragma unroll
  for (int off = 32; off; off >>= 1) {
    dpart += __shfl_xor(dpart, off);
    lpart += __shfl_xor(lpart, off);
  }
  if ((t & 63) == 0) { redD[t >> 6] = dpart; redL[t >> 6] = lpart; }
  __syncthreads();
  if (t == 0) {
    float ds = 0.f, ls = 0.f;
    #pragma unroll
    for (int i = 0; i < 4; ++i) { ds += redD[i]; ls += redL[i]; }
    float ss = 0.f;
    #pragma unroll
    for (int k = 0; k < NK; ++k) ss += selft[k];
    float dis = ds - (float)NK * ss;
    out[0] = ls / (float)NB - dis * 0.01f;
  }
}

// ---------------------------------------------------------------- launch
extern "C" void kernel_launch(void* const* d_in, const int* in_sizes, int n_in,
                              void* d_out, int out_size, void* d_ws, size_t ws_size,
                              hipStream_t stream) {
  (void)in_sizes; (void)n_in; (void)out_size; (void)ws_size;
  const float* anchor = (const float*)d_in[0];
  const float* weight = (const float*)d_in[1];
  const float* t0     = (const float*)d_in[2];
  const int*   len    = (const int*)d_in[3];
  const int*   grade  = (const int*)d_in[4];
  float* out = (float*)d_out;

  float* ws  = (float*)d_ws;
  float* Cab = ws;                                    // 819200
  float* Caa = Cab + (size_t)NB * NK * NL * NR;       // 2097152
  float* Ctt = Caa + (size_t)NB * NL * NL;            // 250000
  float* na  = Ctt + (size_t)NK * NK * NR * NR;       // 16384
  float* nt  = na + NB * NL;                          // 500
  float* lw2 = nt + NK * NR;                          // 16384
  float* oab = lw2 + NB * NL;                         // 1280
  float* oaa = oab + NB * NK;                         // 128
  float* ott = oaa + NB;                              // 100

  prep_kernel<<<(NB * NL + NK * NR) / 4, 256, 0, stream>>>(anchor, weight, t0, len, na, nt, lw2);
  cost_mfma<<<dim3(128, 4), 512, 0, stream>>>(anchor, t0, na, nt, Cab,
                                              NB * NL, NK * NR, 0);
  cost_mfma<<<dim3(4, 4), 512, 0, stream>>>(t0, t0, nt, nt, Ctt,
                                            NK * NR, NK * NR, 2);
  cost_mfma_aa<<<NB, 512, 0, stream>>>(anchor, na, Caa);

  sinkhorn_abtt<<<NB * NK + NK * NK, 256, 0, stream>>>(Cab, Ctt, lw2, weight, oab, ott);
  sinkhorn_aa<<<NB, 512, 0, stream>>>(Caa, lw2, weight, oaa);
  finalize_kernel<<<1, 256, 0, stream>>>(oab, oaa, ott, grade, out);
}